// Round 2
// baseline (3363.976 us; speedup 1.0000x reference)
//
#include <hip/hip_runtime.h>

// ---------------------------------------------------------------- types/helpers
typedef __bf16 bf16x8 __attribute__((ext_vector_type(8)));
typedef float  f32x4  __attribute__((ext_vector_type(4)));

#define DEV __device__ __forceinline__

DEV ushort f2bf(float f) {                       // fp32 -> bf16 RNE
  unsigned u = __builtin_bit_cast(unsigned, f);
  u += 0x7FFFu + ((u >> 16) & 1u);
  return (ushort)(u >> 16);
}
DEV float bf2f(ushort u) { return __builtin_bit_cast(float, ((unsigned)u) << 16); }
DEV unsigned pk2(ushort a, ushort b) { return (unsigned)a | ((unsigned)b << 16); }

DEV f32x4 mfma16(bf16x8 a, bf16x8 b, f32x4 c) {
  return __builtin_amdgcn_mfma_f32_16x16x32_bf16(a, b, c, 0, 0, 0);
}

// jax.nn.gelu approximate=True: 0.5x(1+tanh(u)) == x*sigmoid(2u), one v_exp + rcp
DEV float gelu_f(float x) {
  float u = 0.7978845608028654f * (x + 0.044715f * x * x * x);
  return x / (1.f + __expf(-2.f * u));
}

#define SEQ  1024
#define NBAT 4
#define CDIM 256
#define EDIM 512
#define NLAY 6
#define NHEAD 8
#define HDIM 32
#define IDIM 1024
#define NVOC 50304
#define NROWS (NBAT * SEQ)   // 4096

// ---------------------------------------------------------------- fp32 -> bf16 convert
__global__ __launch_bounds__(256) void cvt_k(const float* __restrict__ src,
                                             ushort* __restrict__ dst, int n4) {
  int i = blockIdx.x * blockDim.x + threadIdx.x;
  int stride = gridDim.x * blockDim.x;
  for (; i < n4; i += stride) {
    float4 f = ((const float4*)src)[i];
    ushort4 u; u.x = f2bf(f.x); u.y = f2bf(f.y); u.z = f2bf(f.z); u.w = f2bf(f.w);
    ((ushort4*)dst)[i] = u;
  }
}

// ---------------------------------------------------------------- embed gather + LN (E=512)
__global__ __launch_bounds__(64) void embed_ln_k(const int* __restrict__ ids,
                                                 const float* __restrict__ ew,
                                                 const float* __restrict__ w,
                                                 const float* __restrict__ b,
                                                 ushort* __restrict__ tok) {
  int m = blockIdx.x, t = threadIdx.x;
  const float* row = ew + (size_t)ids[m] * EDIM;
  float4 v0 = *(const float4*)(row + t * 8);
  float4 v1 = *(const float4*)(row + t * 8 + 4);
  float sm = v0.x + v0.y + v0.z + v0.w + v1.x + v1.y + v1.z + v1.w;
  float sq = v0.x*v0.x + v0.y*v0.y + v0.z*v0.z + v0.w*v0.w
           + v1.x*v1.x + v1.y*v1.y + v1.z*v1.z + v1.w*v1.w;
#pragma unroll
  for (int msk = 1; msk <= 32; msk <<= 1) { sm += __shfl_xor(sm, msk); sq += __shfl_xor(sq, msk); }
  float mean = sm * (1.f / EDIM);
  float var  = sq * (1.f / EDIM) - mean * mean;
  float inv  = rsqrtf(var + 1e-5f);
  float4 w0 = *(const float4*)(w + t * 8), w1 = *(const float4*)(w + t * 8 + 4);
  float4 b0 = *(const float4*)(b + t * 8), b1 = *(const float4*)(b + t * 8 + 4);
  ushort4 u0, u1;
  u0.x = f2bf((v0.x - mean) * inv * w0.x + b0.x);
  u0.y = f2bf((v0.y - mean) * inv * w0.y + b0.y);
  u0.z = f2bf((v0.z - mean) * inv * w0.z + b0.z);
  u0.w = f2bf((v0.w - mean) * inv * w0.w + b0.w);
  u1.x = f2bf((v1.x - mean) * inv * w1.x + b1.x);
  u1.y = f2bf((v1.y - mean) * inv * w1.y + b1.y);
  u1.z = f2bf((v1.z - mean) * inv * w1.z + b1.z);
  u1.w = f2bf((v1.w - mean) * inv * w1.w + b1.w);
  *(ushort4*)(tok + (size_t)m * EDIM + t * 8)     = u0;
  *(ushort4*)(tok + (size_t)m * EDIM + t * 8 + 4) = u1;
}

// ---------------------------------------------------------------- LayerNorm (C=256) -> bf16, 1 or 2 outputs
template <bool DUAL>
__global__ __launch_bounds__(64) void ln_k(const float* __restrict__ x,
                                           const float* __restrict__ w1, const float* __restrict__ b1,
                                           const float* __restrict__ w2, const float* __restrict__ b2,
                                           ushort* __restrict__ o1, ushort* __restrict__ o2) {
  int m = blockIdx.x, t = threadIdx.x;
  const float* row = x + (size_t)m * CDIM;
  float4 v = *(const float4*)(row + t * 4);
  float sm = v.x + v.y + v.z + v.w;
  float sq = v.x*v.x + v.y*v.y + v.z*v.z + v.w*v.w;
#pragma unroll
  for (int msk = 1; msk <= 32; msk <<= 1) { sm += __shfl_xor(sm, msk); sq += __shfl_xor(sq, msk); }
  float mean = sm * (1.f / CDIM);
  float var  = sq * (1.f / CDIM) - mean * mean;
  float inv  = rsqrtf(var + 1e-5f);
  float n0 = (v.x - mean) * inv, n1 = (v.y - mean) * inv, n2 = (v.z - mean) * inv, n3 = (v.w - mean) * inv;
  {
    float4 wv = *(const float4*)(w1 + t * 4), bv = *(const float4*)(b1 + t * 4);
    ushort4 u; u.x = f2bf(n0*wv.x+bv.x); u.y = f2bf(n1*wv.y+bv.y); u.z = f2bf(n2*wv.z+bv.z); u.w = f2bf(n3*wv.w+bv.w);
    *(ushort4*)(o1 + (size_t)m * CDIM + t * 4) = u;
  }
  if constexpr (DUAL) {
    float4 wv = *(const float4*)(w2 + t * 4), bv = *(const float4*)(b2 + t * 4);
    ushort4 u; u.x = f2bf(n0*wv.x+bv.x); u.y = f2bf(n1*wv.y+bv.y); u.z = f2bf(n2*wv.z+bv.z); u.w = f2bf(n3*wv.w+bv.w);
    *(ushort4*)(o2 + (size_t)m * CDIM + t * 4) = u;
  }
}

// ---------------------------------------------------------------- generic 128x128 MFMA GEMM
// C[M,N] = A[M,K](bf16) * W[N,K]^T (+bias) (+gelu) (+accumulate) ; W fp32 or bf16
enum { GF_BIAS = 1, GF_GELU = 2, GF_ACC = 4, GF_BF16O = 8, GF_WF32 = 16 };

template <int FLAGS>
__global__ __launch_bounds__(256) void gemm_k(const ushort* __restrict__ A, int lda,
                                              const void* __restrict__ Wv, int ldw,
                                              const float* __restrict__ bias,
                                              void* __restrict__ C, int ldc, int K) {
  __shared__ __attribute__((aligned(16))) ushort lsA[128 * 32];
  __shared__ __attribute__((aligned(16))) ushort lsB[128 * 32];
  const int tid = threadIdx.x, lane = tid & 63, wave = tid >> 6;
  const int wm = wave >> 1, wn = wave & 1;
  const int row0 = blockIdx.x * 128, col0 = blockIdx.y * 128;
  const int l15 = lane & 15, koff = (lane >> 4) * 8;

  f32x4 acc[4][4] = {};
  for (int k0 = 0; k0 < K; k0 += 32) {
    __syncthreads();
#pragma unroll
    for (int p = 0; p < 2; ++p) {
      int c = tid + p * 256;          // 512 chunks of 8 bf16
      int r = c >> 2, k8 = (c & 3) * 8;
      *(uint4*)(&lsA[c * 8]) = *(const uint4*)(A + (size_t)(row0 + r) * lda + k0 + k8);
      if constexpr (FLAGS & GF_WF32) {
        const float* gw = (const float*)Wv + (size_t)(col0 + r) * ldw + k0 + k8;
        float4 f0 = *(const float4*)gw, f1 = *(const float4*)(gw + 4);
        uint4 vw;
        vw.x = pk2(f2bf(f0.x), f2bf(f0.y)); vw.y = pk2(f2bf(f0.z), f2bf(f0.w));
        vw.z = pk2(f2bf(f1.x), f2bf(f1.y)); vw.w = pk2(f2bf(f1.z), f2bf(f1.w));
        *(uint4*)(&lsB[c * 8]) = vw;
      } else {
        *(uint4*)(&lsB[c * 8]) = *(const uint4*)((const ushort*)Wv + (size_t)(col0 + r) * ldw + k0 + k8);
      }
    }
    __syncthreads();
    bf16x8 af[4], bfr[4];
#pragma unroll
    for (int mt = 0; mt < 4; ++mt)
      af[mt] = __builtin_bit_cast(bf16x8, *(const uint4*)(&lsA[(wm * 64 + mt * 16 + l15) * 32 + koff]));
#pragma unroll
    for (int nt = 0; nt < 4; ++nt)
      bfr[nt] = __builtin_bit_cast(bf16x8, *(const uint4*)(&lsB[(wn * 64 + nt * 16 + l15) * 32 + koff]));
#pragma unroll
    for (int mt = 0; mt < 4; ++mt)
#pragma unroll
      for (int nt = 0; nt < 4; ++nt)
        acc[mt][nt] = mfma16(af[mt], bfr[nt], acc[mt][nt]);
  }
#pragma unroll
  for (int mt = 0; mt < 4; ++mt) {
#pragma unroll
    for (int nt = 0; nt < 4; ++nt) {
      int col = col0 + wn * 64 + nt * 16 + l15;
      float bv = (FLAGS & GF_BIAS) ? bias[col] : 0.f;
      int rowb = row0 + wm * 64 + mt * 16 + (lane >> 4) * 4;
#pragma unroll
      for (int r = 0; r < 4; ++r) {
        float v = acc[mt][nt][r] + bv;
        if constexpr (FLAGS & GF_GELU) v = gelu_f(v);
        size_t off = (size_t)(rowb + r) * ldc + col;
        if constexpr (FLAGS & GF_ACC)        ((float*)C)[off] += v;
        else if constexpr (FLAGS & GF_BF16O) ((ushort*)C)[off] = f2bf(v);
        else                                 ((float*)C)[off] = v;
      }
    }
  }
}

// ---------------------------------------------------------------- sequential context scan (1 block)
// ctx_{t+1} = LN(gelu(W_c ctx_t + P[t])),  P[t] precomputed = W_e emb_t + ctx_b
// Raw barriers (lgkmcnt-only, never drain vmcnt of the y-store).
__global__ __launch_bounds__(256, 1) void scan_k(const float* __restrict__ ctx_w,
                                                 const float* __restrict__ prev_ctx,
                                                 const float* __restrict__ P,
                                                 const float* __restrict__ cn_w,
                                                 const float* __restrict__ cn_b,
                                                 float* __restrict__ x) {
  __shared__ __attribute__((aligned(16))) ushort ctx_lds[4 * 288];   // [b][o], stride 288
  __shared__ __attribute__((aligned(16))) float  g_lds[4 * 256];     // gelu'd h
  __shared__ __attribute__((aligned(16))) float  p_lds[2][4 * 256];  // P[t] double-buffer
  __shared__ __attribute__((aligned(16))) float  part_lds[4 * 8];    // per-wave (s,q) x 4 batches
  const int tid = threadIdx.x, lane = tid & 63, wave = tid >> 6;
  const int l15 = lane & 15, lhi = lane >> 4;

  // static weight B-fragments: wave owns outputs [wave*64, wave*64+64)
  bf16x8 wf[4][8];
#pragma unroll
  for (int nt = 0; nt < 4; ++nt)
#pragma unroll
    for (int kt = 0; kt < 8; ++kt) {
      int n = wave * 64 + nt * 16 + l15;
      int k = kt * 32 + lhi * 8;
      const float* s = ctx_w + (size_t)n * 768 + k;   // W_c = ctx_w[:, :256]
      float4 f0 = *(const float4*)s, f1 = *(const float4*)(s + 4);
      uint4 vw;
      vw.x = pk2(f2bf(f0.x), f2bf(f0.y)); vw.y = pk2(f2bf(f0.z), f2bf(f0.w));
      vw.z = pk2(f2bf(f1.x), f2bf(f1.y)); vw.w = pk2(f2bf(f1.z), f2bf(f1.w));
      wf[nt][kt] = __builtin_bit_cast(bf16x8, vw);
    }
  const int b2 = tid >> 6, o2 = (tid & 63) * 4;
  {
    float4 c4 = *(const float4*)(prev_ctx + b2 * CDIM + o2);
    ushort4 u; u.x = f2bf(c4.x); u.y = f2bf(c4.y); u.z = f2bf(c4.z); u.w = f2bf(c4.w);
    *(ushort4*)&ctx_lds[b2 * 288 + o2] = u;
    float4 p0 = *(const float4*)(P + (size_t)b2 * SEQ * CDIM + o2);
    *(float4*)&p_lds[0][b2 * 256 + o2] = p0;
  }
  float4 cw = *(const float4*)(cn_w + o2);
  float4 cb = *(const float4*)(cn_b + o2);
  bf16x8 af[8] = {};                       // rows 4..15 of A stay zero
  __syncthreads();

  for (int t = 0; t < SEQ; ++t) {
    const int cur = t & 1, nxt = cur ^ 1;
    // prefetch P[t+1] (consumed in phase 3; latency hidden under MFMA+phase2)
    float4 pf = {};
    if (t + 1 < SEQ) pf = *(const float4*)(P + ((size_t)b2 * SEQ + t + 1) * CDIM + o2);

    // phase 1: ctx fragment + MFMA
    if (l15 < 4) {
#pragma unroll
      for (int kt = 0; kt < 8; ++kt)
        af[kt] = __builtin_bit_cast(bf16x8, *(const uint4*)(&ctx_lds[l15 * 288 + kt * 32 + lhi * 8]));
    }
    f32x4 acc[4] = {};
#pragma unroll
    for (int nt = 0; nt < 4; ++nt)
#pragma unroll
      for (int kt = 0; kt < 8; ++kt)
        acc[nt] = mfma16(af[kt], wf[nt][kt], acc[nt]);

    // phase 2 (lanes 0-15): gelu + per-wave partial LN sums
    if (lhi == 0) {
      float s[4] = {}, q[4] = {};
#pragma unroll
      for (int nt = 0; nt < 4; ++nt)
#pragma unroll
        for (int r = 0; r < 4; ++r) {
          int col = wave * 64 + nt * 16 + l15;
          float g = gelu_f(acc[nt][r] + p_lds[cur][r * 256 + col]);
          g_lds[r * 256 + col] = g;
          s[r] += g; q[r] += g * g;
        }
#pragma unroll
      for (int msk = 1; msk <= 8; msk <<= 1)
#pragma unroll
        for (int r = 0; r < 4; ++r) { s[r] += __shfl_xor(s[r], msk); q[r] += __shfl_xor(q[r], msk); }
      if (l15 < 8) part_lds[wave * 8 + l15] = (l15 & 1) ? q[l15 >> 1] : s[l15 >> 1];
    }
    asm volatile("s_waitcnt lgkmcnt(0)" ::: "memory");
    __builtin_amdgcn_s_barrier();

    // phase 3: combine partials, normalize, write y + new ctx + next P
    float4 g4 = *(const float4*)&g_lds[b2 * 256 + o2];
    float sm = 0.f, sq = 0.f;
#pragma unroll
    for (int w = 0; w < 4; ++w) { sm += part_lds[w * 8 + b2 * 2]; sq += part_lds[w * 8 + b2 * 2 + 1]; }
    float mean = sm * (1.f / CDIM);
    float var  = sq * (1.f / CDIM) - mean * mean;
    float inv  = rsqrtf(var + 1e-5f);
    float y0 = (g4.x - mean) * inv * cw.x + cb.x;
    float y1 = (g4.y - mean) * inv * cw.y + cb.y;
    float y2 = (g4.z - mean) * inv * cw.z + cb.z;
    float y3 = (g4.w - mean) * inv * cw.w + cb.w;
    float4 y; y.x = y0; y.y = y1; y.z = y2; y.w = y3;
    *(float4*)(x + ((size_t)b2 * SEQ + t) * CDIM + o2) = y;   // no vmcnt drain before barrier
    ushort4 u; u.x = f2bf(y0); u.y = f2bf(y1); u.z = f2bf(y2); u.w = f2bf(y3);
    *(ushort4*)&ctx_lds[b2 * 288 + o2] = u;
    *(float4*)&p_lds[nxt][b2 * 256 + o2] = pf;
    asm volatile("s_waitcnt lgkmcnt(0)" ::: "memory");
    __builtin_amdgcn_s_barrier();
  }
}

// ---------------------------------------------------------------- qkv rearrange + RoPE (ROT=8)
__global__ __launch_bounds__(256) void rope_k(const ushort* __restrict__ qkv,
                                              ushort* __restrict__ Qo,
                                              ushort* __restrict__ Ko,
                                              ushort* __restrict__ Vt) {
  int m = blockIdx.x;                      // b*S + s
  int b = m >> 10, s = m & 1023;
  int t = threadIdx.x;
  int h = t >> 5, d = t & 31;
  const ushort* row = qkv + (size_t)m * 768;
  float q = bf2f(row[h * 32 + d]);
  float k = bf2f(row[256 + h * 32 + d]);
  float v = bf2f(row[512 + h * 32 + d]);
  if (d < 8) {
    int prt = (d < 4) ? d + 4 : d - 4;
    float sgn = (d < 4) ? -1.f : 1.f;
    float qp = sgn * bf2f(row[h * 32 + prt]);
    float kp = sgn * bf2f(row[256 + h * 32 + prt]);
    int j = d & 3;
    // 10000^(-j/4) = 10^-j exactly
    const float invs[4] = {1.f, 0.1f, 0.01f, 0.001f};
    float ang = (float)s * invs[j];
    float c, sn;
    __sincosf(ang, &sn, &c);
    q = q * c + qp * sn;
    k = k * c + kp * sn;
  }
  size_t bh = (size_t)(b * NHEAD + h);
  Qo[(bh * SEQ + s) * HDIM + d] = f2bf(q);
  Ko[(bh * SEQ + s) * HDIM + d] = f2bf(k);
  Vt[bh * HDIM * SEQ + (size_t)d * SEQ + s] = f2bf(v);   // V transposed: [bh][d][s]
}

// ---------------------------------------------------------------- causal flash attention, D=32, MFMA
__global__ __launch_bounds__(256) void attn_k(const ushort* __restrict__ Q,
                                              const ushort* __restrict__ K,
                                              const ushort* __restrict__ VT,
                                              ushort* __restrict__ O) {
  __shared__ __attribute__((aligned(16))) ushort Plds[4 * 16 * 32];  // per-wave 16x32 P tile
  const int tid = threadIdx.x, lane = tid & 63, wave = tid >> 6;
  const int bh = blockIdx.y;
  const int qtile = blockIdx.x * 4 + wave;
  const int q0 = qtile * 16;
  const int l15 = lane & 15, lhi = lane >> 4;
  const float scale = 0.17677669529663689f;   // 1/sqrt(32)

  bf16x8 qa = __builtin_bit_cast(bf16x8,
      *(const uint4*)(Q + ((size_t)bh * SEQ + q0 + l15) * HDIM + lhi * 8));
  const ushort* Kb = K + (size_t)bh * SEQ * HDIM;
  const ushort* Vb = VT + (size_t)bh * HDIM * SEQ;
  ushort* Pw = &Plds[wave * 512];

  f32x4 o0 = {}, o1 = {};
  float mrow[4] = {-1e30f, -1e30f, -1e30f, -1e30f};
  float lrow[4] = {};

  for (int kt = 0; kt <= qtile; kt += 2) {
    const bool t2 = (kt + 1 <= qtile);
    f32x4 z = {};
    bf16x8 kf0 = __builtin_bit_cast(bf16x8, *(const uint4*)(Kb + (size_t)(kt * 16 + l15) * HDIM + lhi * 8));
    f32x4 s0 = mfma16(qa, kf0, z);
    f32x4 s1 = {};
    if (t2) {
      bf16x8 kf1 = __builtin_bit_cast(bf16x8, *(const uint4*)(Kb + (size_t)((kt + 1) * 16 + l15) * HDIM + lhi * 8));
      s1 = mfma16(qa, kf1, z);
    }
    float p0[4], p1[4], mx[4];
#pragma unroll
    for (int r = 0; r < 4; ++r) {
      int qr = q0 + lhi * 4 + r;
      int kc0 = kt * 16 + l15;
      p0[r] = (kc0 <= qr) ? s0[r] * scale : -1e30f;
      p1[r] = (t2 && kc0 + 16 <= qr) ? s1[r] * scale : -1e30f;
      mx[r] = fmaxf(p0[r], p1[r]);
    }
#pragma unroll
    for (int msk = 1; msk <= 8; msk <<= 1)
#pragma unroll
      for (int r = 0; r < 4; ++r) mx[r] = fmaxf(mx[r], __shfl_xor(mx[r], msk));
    float rs[4];
#pragma unroll
    for (int r = 0; r < 4; ++r) {
      float mn = fmaxf(mrow[r], mx[r]);
      float alpha = __expf(mrow[r] - mn);
      mrow[r] = mn;
      p0[r] = __expf(p0[r] - mn);
      p1[r] = __expf(p1[r] - mn);
      rs[r] = p0[r] + p1[r];
      lrow[r] = lrow[r] * alpha;
      o0[r] *= alpha; o1[r] *= alpha;
    }
#pragma unroll
    for (int msk = 1; msk <= 8; msk <<= 1)
#pragma unroll
      for (int r = 0; r < 4; ++r) rs[r] += __shfl_xor(rs[r], msk);
#pragma unroll
    for (int r = 0; r < 4; ++r) lrow[r] += rs[r];
#pragma unroll
    for (int r = 0; r < 4; ++r) {
      Pw[(lhi * 4 + r) * 32 + l15]      = f2bf(p0[r]);
      Pw[(lhi * 4 + r) * 32 + 16 + l15] = f2bf(p1[r]);
    }
    bf16x8 pa  = __builtin_bit_cast(bf16x8, *(const uint4*)(&Pw[l15 * 32 + lhi * 8]));
    bf16x8 v0f = __builtin_bit_cast(bf16x8, *(const uint4*)(Vb + (size_t)l15 * SEQ + kt * 16 + lhi * 8));
    bf16x8 v1f = __builtin_bit_cast(bf16x8, *(const uint4*)(Vb + (size_t)(16 + l15) * SEQ + kt * 16 + lhi * 8));
    o0 = mfma16(pa, v0f, o0);
    o1 = mfma16(pa, v1f, o1);
  }
  const int b = bh >> 3, h = bh & 7;
#pragma unroll
  for (int r = 0; r < 4; ++r) {
    float inv = 1.f / lrow[r];
    int qr = q0 + lhi * 4 + r;
    size_t base = ((size_t)(b * SEQ + qr)) * CDIM + h * HDIM;
    O[base + l15]      = f2bf(o0[r] * inv);
    O[base + 16 + l15] = f2bf(o1[r] * inv);
  }
}

// ---------------------------------------------------------------- launcher
static size_t ws_take(size_t& o, size_t bytes) {
  size_t r = o;
  o += (bytes + 255) & ~(size_t)255;
  return r;
}

extern "C" void kernel_launch(void* const* d_in, const int* in_sizes, int n_in,
                              void* d_out, int out_size, void* d_ws, size_t ws_size,
                              hipStream_t stream) {
  (void)in_sizes; (void)n_in; (void)out_size; (void)ws_size;
  const int*   input_ids = (const int*)  d_in[0];
  const float* prev_ctx  = (const float*)d_in[1];
  const float* embed_w   = (const float*)d_in[2];
  const float* en_w      = (const float*)d_in[3];
  const float* en_b      = (const float*)d_in[4];
  const float* ctx_w     = (const float*)d_in[5];
  const float* ctx_b     = (const float*)d_in[6];
  const float* cn_w      = (const float*)d_in[7];
  const float* cn_b      = (const float*)d_in[8];
  const float* ln1_w     = (const float*)d_in[9];
  const float* ln1_b     = (const float*)d_in[10];
  const float* ln2_w     = (const float*)d_in[11];
  const float* ln2_b     = (const float*)d_in[12];
  const float* qkv_w     = (const float*)d_in[13];
  const float* qkv_b     = (const float*)d_in[14];
  const float* ao_w      = (const float*)d_in[15];
  const float* ao_b      = (const float*)d_in[16];
  const float* fc1_w     = (const float*)d_in[17];
  const float* fc1_b     = (const float*)d_in[18];
  const float* fc2_w     = (const float*)d_in[19];
  const float* fc2_b     = (const float*)d_in[20];
  const float* fln_w     = (const float*)d_in[21];
  const float* fln_b     = (const float*)d_in[22];
  const float* out_w     = (const float*)d_in[23];
  float* logits = (float*)d_out;

  char* ws = (char*)d_ws;
  size_t o = 0;
  ushort* WB_OUT = (ushort*)(ws + ws_take(o, (size_t)NVOC * CDIM * 2));
  ushort* TOK    = (ushort*)(ws + ws_take(o, (size_t)NROWS * EDIM * 2));
  float*  PBUF   = (float*) (ws + ws_take(o, (size_t)NROWS * CDIM * 4));
  float*  XBUF   = (float*) (ws + ws_take(o, (size_t)NROWS * CDIM * 4));
  ushort* AIN    = (ushort*)(ws + ws_take(o, (size_t)NROWS * CDIM * 2));
  ushort* MIN    = (ushort*)(ws + ws_take(o, (size_t)NROWS * CDIM * 2));
  ushort* QKVB   = (ushort*)(ws + ws_take(o, (size_t)NROWS * 768 * 2));
  ushort* QB     = (ushort*)(ws + ws_take(o, (size_t)NROWS * CDIM * 2));
  ushort* KB     = (ushort*)(ws + ws_take(o, (size_t)NROWS * CDIM * 2));
  ushort* VTB    = (ushort*)(ws + ws_take(o, (size_t)NROWS * CDIM * 2));
  ushort* OB     = (ushort*)(ws + ws_take(o, (size_t)NROWS * CDIM * 2));
  ushort* TBUF   = (ushort*)(ws + ws_take(o, (size_t)NROWS * IDIM * 2));
  ushort* XLN    = (ushort*)(ws + ws_take(o, (size_t)NROWS * CDIM * 2));

  cvt_k<<<dim3(2048), dim3(256), 0, stream>>>(out_w, WB_OUT, NVOC * CDIM / 4);
  embed_ln_k<<<dim3(NROWS), dim3(64), 0, stream>>>(input_ids, embed_w, en_w, en_b, TOK);
  gemm_k<GF_BIAS | GF_WF32><<<dim3(32, 2), dim3(256), 0, stream>>>(
      TOK, EDIM, (const void*)(ctx_w + 256), 768, ctx_b, (void*)PBUF, CDIM, EDIM);
  scan_k<<<dim3(1), dim3(256), 0, stream>>>(ctx_w, prev_ctx, PBUF, cn_w, cn_b, XBUF);

  for (int l = 0; l < NLAY; ++l) {
    ln_k<true><<<dim3(NROWS), dim3(64), 0, stream>>>(
        XBUF, ln1_w + l * CDIM, ln1_b + l * CDIM, ln2_w + l * CDIM, ln2_b + l * CDIM, AIN, MIN);
    gemm_k<GF_BIAS | GF_BF16O | GF_WF32><<<dim3(32, 6), dim3(256), 0, stream>>>(
        AIN, CDIM, (const void*)(qkv_w + (size_t)l * 768 * CDIM), CDIM,
        qkv_b + l * 768, (void*)QKVB, 768, CDIM);
    rope_k<<<dim3(NROWS), dim3(256), 0, stream>>>(QKVB, QB, KB, VTB);
    attn_k<<<dim3(16, 32), dim3(256), 0, stream>>>(QB, KB, VTB, OB);
    gemm_k<GF_BIAS | GF_ACC | GF_WF32><<<dim3(32, 2), dim3(256), 0, stream>>>(
        OB, CDIM, (const void*)(ao_w + (size_t)l * CDIM * CDIM), CDIM,
        ao_b + l * CDIM, (void*)XBUF, CDIM, CDIM);
    gemm_k<GF_BIAS | GF_GELU | GF_BF16O | GF_WF32><<<dim3(32, 8), dim3(256), 0, stream>>>(
        MIN, CDIM, (const void*)(fc1_w + (size_t)l * IDIM * CDIM), CDIM,
        fc1_b + l * IDIM, (void*)TBUF, IDIM, CDIM);
    gemm_k<GF_BIAS | GF_ACC | GF_WF32><<<dim3(32, 2), dim3(256), 0, stream>>>(
        TBUF, IDIM, (const void*)(fc2_w + (size_t)l * CDIM * IDIM), IDIM,
        fc2_b + l * CDIM, (void*)XBUF, CDIM, IDIM);
  }

  ln_k<false><<<dim3(NROWS), dim3(64), 0, stream>>>(
      XBUF, fln_w, fln_b, nullptr, nullptr, XLN, nullptr);
  gemm_k<0><<<dim3(32, 393), dim3(256), 0, stream>>>(
      XLN, CDIM, (const void*)WB_OUT, CDIM, nullptr, (void*)logits, NVOC, CDIM);
}

// Round 3
// 2370.356 us; speedup vs baseline: 1.4192x; 1.4192x over previous
//
#include <hip/hip_runtime.h>

// ---------------------------------------------------------------- types/helpers
typedef __bf16 bf16x8 __attribute__((ext_vector_type(8)));
typedef float  f32x4  __attribute__((ext_vector_type(4)));
typedef unsigned uint32x4 __attribute__((ext_vector_type(4)));

#define DEV __device__ __forceinline__

DEV ushort f2bf(float f) {                       // fp32 -> bf16 RNE
  unsigned u = __builtin_bit_cast(unsigned, f);
  u += 0x7FFFu + ((u >> 16) & 1u);
  return (ushort)(u >> 16);
}
DEV float bf2f(ushort u) { return __builtin_bit_cast(float, ((unsigned)u) << 16); }
DEV unsigned pk2(ushort a, ushort b) { return (unsigned)a | ((unsigned)b << 16); }

DEV f32x4 mfma16(bf16x8 a, bf16x8 b, f32x4 c) {
  return __builtin_amdgcn_mfma_f32_16x16x32_bf16(a, b, c, 0, 0, 0);
}

// jax.nn.gelu approximate=True: 0.5x(1+tanh(u)) == x*sigmoid(2u), one v_exp + rcp
DEV float gelu_f(float x) {
  float u = 0.7978845608028654f * (x + 0.044715f * x * x * x);
  return x / (1.f + __expf(-2.f * u));
}

#define SEQ  1024
#define NBAT 4
#define CDIM 256
#define EDIM 512
#define NLAY 6
#define NHEAD 8
#define HDIM 32
#define IDIM 1024
#define NVOC 50304
#define NROWS (NBAT * SEQ)   // 4096

// ---------------------------------------------------------------- fp32 -> bf16 convert
__global__ __launch_bounds__(256) void cvt_k(const float* __restrict__ src,
                                             ushort* __restrict__ dst, int n4) {
  int i = blockIdx.x * blockDim.x + threadIdx.x;
  int stride = gridDim.x * blockDim.x;
  for (; i < n4; i += stride) {
    float4 f = ((const float4*)src)[i];
    ushort4 u; u.x = f2bf(f.x); u.y = f2bf(f.y); u.z = f2bf(f.z); u.w = f2bf(f.w);
    ((ushort4*)dst)[i] = u;
  }
}

// ---------------------------------------------------------------- embed gather + LN (E=512)
__global__ __launch_bounds__(64) void embed_ln_k(const int* __restrict__ ids,
                                                 const float* __restrict__ ew,
                                                 const float* __restrict__ w,
                                                 const float* __restrict__ b,
                                                 ushort* __restrict__ tok) {
  int m = blockIdx.x, t = threadIdx.x;
  const float* row = ew + (size_t)ids[m] * EDIM;
  float4 v0 = *(const float4*)(row + t * 8);
  float4 v1 = *(const float4*)(row + t * 8 + 4);
  float sm = v0.x + v0.y + v0.z + v0.w + v1.x + v1.y + v1.z + v1.w;
  float sq = v0.x*v0.x + v0.y*v0.y + v0.z*v0.z + v0.w*v0.w
           + v1.x*v1.x + v1.y*v1.y + v1.z*v1.z + v1.w*v1.w;
#pragma unroll
  for (int msk = 1; msk <= 32; msk <<= 1) { sm += __shfl_xor(sm, msk); sq += __shfl_xor(sq, msk); }
  float mean = sm * (1.f / EDIM);
  float var  = sq * (1.f / EDIM) - mean * mean;
  float inv  = rsqrtf(var + 1e-5f);
  float4 w0 = *(const float4*)(w + t * 8), w1 = *(const float4*)(w + t * 8 + 4);
  float4 b0 = *(const float4*)(b + t * 8), b1 = *(const float4*)(b + t * 8 + 4);
  ushort4 u0, u1;
  u0.x = f2bf((v0.x - mean) * inv * w0.x + b0.x);
  u0.y = f2bf((v0.y - mean) * inv * w0.y + b0.y);
  u0.z = f2bf((v0.z - mean) * inv * w0.z + b0.z);
  u0.w = f2bf((v0.w - mean) * inv * w0.w + b0.w);
  u1.x = f2bf((v1.x - mean) * inv * w1.x + b1.x);
  u1.y = f2bf((v1.y - mean) * inv * w1.y + b1.y);
  u1.z = f2bf((v1.z - mean) * inv * w1.z + b1.z);
  u1.w = f2bf((v1.w - mean) * inv * w1.w + b1.w);
  *(ushort4*)(tok + (size_t)m * EDIM + t * 8)     = u0;
  *(ushort4*)(tok + (size_t)m * EDIM + t * 8 + 4) = u1;
}

// ---------------------------------------------------------------- LayerNorm (C=256) -> bf16, wave-per-row
template <bool DUAL>
__global__ __launch_bounds__(256) void ln_k(const float* __restrict__ x,
                                            const float* __restrict__ w1, const float* __restrict__ b1,
                                            const float* __restrict__ w2, const float* __restrict__ b2,
                                            ushort* __restrict__ o1, ushort* __restrict__ o2) {
  int wave = threadIdx.x >> 6, t = threadIdx.x & 63;
  int m = blockIdx.x * 4 + wave;
  const float* row = x + (size_t)m * CDIM;
  float4 v = *(const float4*)(row + t * 4);
  float sm = v.x + v.y + v.z + v.w;
  float sq = v.x*v.x + v.y*v.y + v.z*v.z + v.w*v.w;
#pragma unroll
  for (int msk = 1; msk <= 32; msk <<= 1) { sm += __shfl_xor(sm, msk); sq += __shfl_xor(sq, msk); }
  float mean = sm * (1.f / CDIM);
  float var  = sq * (1.f / CDIM) - mean * mean;
  float inv  = rsqrtf(var + 1e-5f);
  float n0 = (v.x - mean) * inv, n1 = (v.y - mean) * inv, n2 = (v.z - mean) * inv, n3 = (v.w - mean) * inv;
  {
    float4 wv = *(const float4*)(w1 + t * 4), bv = *(const float4*)(b1 + t * 4);
    ushort4 u; u.x = f2bf(n0*wv.x+bv.x); u.y = f2bf(n1*wv.y+bv.y); u.z = f2bf(n2*wv.z+bv.z); u.w = f2bf(n3*wv.w+bv.w);
    *(ushort4*)(o1 + (size_t)m * CDIM + t * 4) = u;
  }
  if constexpr (DUAL) {
    float4 wv = *(const float4*)(w2 + t * 4), bv = *(const float4*)(b2 + t * 4);
    ushort4 u; u.x = f2bf(n0*wv.x+bv.x); u.y = f2bf(n1*wv.y+bv.y); u.z = f2bf(n2*wv.z+bv.z); u.w = f2bf(n3*wv.w+bv.w);
    *(ushort4*)(o2 + (size_t)m * CDIM + t * 4) = u;
  }
}

// ---------------------------------------------------------------- generic 128x128 MFMA GEMM
enum { GF_BIAS = 1, GF_GELU = 2, GF_ACC = 4, GF_BF16O = 8, GF_WF32 = 16 };

template <int FLAGS>
__global__ __launch_bounds__(256) void gemm_k(const ushort* __restrict__ A, int lda,
                                              const void* __restrict__ Wv, int ldw,
                                              const float* __restrict__ bias,
                                              void* __restrict__ C, int ldc, int K) {
  __shared__ __attribute__((aligned(16))) ushort lsA[128 * 32];
  __shared__ __attribute__((aligned(16))) ushort lsB[128 * 32];
  const int tid = threadIdx.x, lane = tid & 63, wave = tid >> 6;
  const int wm = wave >> 1, wn = wave & 1;
  const int row0 = blockIdx.x * 128, col0 = blockIdx.y * 128;
  const int l15 = lane & 15, koff = (lane >> 4) * 8;

  f32x4 acc[4][4] = {};
  for (int k0 = 0; k0 < K; k0 += 32) {
    __syncthreads();
#pragma unroll
    for (int p = 0; p < 2; ++p) {
      int c = tid + p * 256;          // 512 chunks of 8 bf16
      int r = c >> 2, k8 = (c & 3) * 8;
      *(uint4*)(&lsA[c * 8]) = *(const uint4*)(A + (size_t)(row0 + r) * lda + k0 + k8);
      if constexpr (FLAGS & GF_WF32) {
        const float* gw = (const float*)Wv + (size_t)(col0 + r) * ldw + k0 + k8;
        float4 f0 = *(const float4*)gw, f1 = *(const float4*)(gw + 4);
        uint4 vw;
        vw.x = pk2(f2bf(f0.x), f2bf(f0.y)); vw.y = pk2(f2bf(f0.z), f2bf(f0.w));
        vw.z = pk2(f2bf(f1.x), f2bf(f1.y)); vw.w = pk2(f2bf(f1.z), f2bf(f1.w));
        *(uint4*)(&lsB[c * 8]) = vw;
      } else {
        *(uint4*)(&lsB[c * 8]) = *(const uint4*)((const ushort*)Wv + (size_t)(col0 + r) * ldw + k0 + k8);
      }
    }
    __syncthreads();
    bf16x8 af[4], bfr[4];
#pragma unroll
    for (int mt = 0; mt < 4; ++mt)
      af[mt] = __builtin_bit_cast(bf16x8, *(const uint4*)(&lsA[(wm * 64 + mt * 16 + l15) * 32 + koff]));
#pragma unroll
    for (int nt = 0; nt < 4; ++nt)
      bfr[nt] = __builtin_bit_cast(bf16x8, *(const uint4*)(&lsB[(wn * 64 + nt * 16 + l15) * 32 + koff]));
#pragma unroll
    for (int mt = 0; mt < 4; ++mt)
#pragma unroll
      for (int nt = 0; nt < 4; ++nt)
        acc[mt][nt] = mfma16(af[mt], bfr[nt], acc[mt][nt]);
  }
#pragma unroll
  for (int mt = 0; mt < 4; ++mt) {
#pragma unroll
    for (int nt = 0; nt < 4; ++nt) {
      int col = col0 + wn * 64 + nt * 16 + l15;
      float bv = (FLAGS & GF_BIAS) ? bias[col] : 0.f;
      int rowb = row0 + wm * 64 + mt * 16 + (lane >> 4) * 4;
#pragma unroll
      for (int r = 0; r < 4; ++r) {
        float v = acc[mt][nt][r] + bv;
        if constexpr (FLAGS & GF_GELU) v = gelu_f(v);
        size_t off = (size_t)(rowb + r) * ldc + col;
        if constexpr (FLAGS & GF_ACC)        ((float*)C)[off] += v;
        else if constexpr (FLAGS & GF_BF16O) ((ushort*)C)[off] = f2bf(v);
        else                                 ((float*)C)[off] = v;
      }
    }
  }
}

// ---------------------------------------------------------------- sequential context scan (1 block)
// ctx_{t+1} = LN(gelu(W_c ctx_t + P[t])),  P[t] precomputed = W_e emb_t + ctx_b
// Round-1 dataflow (all-thread phase 2) + raw barriers (no vmcnt drain) +
// P software-pipelined across iterations (counted vmcnt skips the y-store).
__global__ __launch_bounds__(256, 1) void scan_k(const float* __restrict__ ctx_w,
                                                 const float* __restrict__ prev_ctx,
                                                 const float* __restrict__ P,
                                                 const float* __restrict__ cn_w,
                                                 const float* __restrict__ cn_b,
                                                 float* __restrict__ x) {
  __shared__ __attribute__((aligned(16))) ushort ctx_lds[4 * 288];   // [b][o], stride 288
  __shared__ __attribute__((aligned(16))) float  h_lds[4 * 256];
  const int tid = threadIdx.x, lane = tid & 63, wave = tid >> 6;
  const int l15 = lane & 15, lhi = lane >> 4;

  // static weight B-fragments: wave owns outputs [wave*64, wave*64+64)
  uint32x4 wfu[4][8];
#pragma unroll
  for (int nt = 0; nt < 4; ++nt)
#pragma unroll
    for (int kt = 0; kt < 8; ++kt) {
      int n = wave * 64 + nt * 16 + l15;
      int k = kt * 32 + lhi * 8;
      const float* s = ctx_w + (size_t)n * 768 + k;   // W_c = ctx_w[:, :256]
      float4 f0 = *(const float4*)s, f1 = *(const float4*)(s + 4);
      uint32x4 vw;
      vw.x = pk2(f2bf(f0.x), f2bf(f0.y)); vw.y = pk2(f2bf(f0.z), f2bf(f0.w));
      vw.z = pk2(f2bf(f1.x), f2bf(f1.y)); vw.w = pk2(f2bf(f1.z), f2bf(f1.w));
      wfu[nt][kt] = vw;
    }
  // pin fragments live in VGPRs (prevent rematerialization inside the loop)
#pragma unroll
  for (int nt = 0; nt < 4; ++nt)
#pragma unroll
    for (int kt = 0; kt < 8; ++kt)
      asm volatile("" : "+v"(wfu[nt][kt]));

  const int b2 = tid >> 6, o2 = (tid & 63) * 4;
  {
    float4 c4 = *(const float4*)(prev_ctx + b2 * CDIM + o2);
    ushort4 u; u.x = f2bf(c4.x); u.y = f2bf(c4.y); u.z = f2bf(c4.z); u.w = f2bf(c4.w);
    *(ushort4*)&ctx_lds[b2 * 288 + o2] = u;
  }
  float4 cw = *(const float4*)(cn_w + o2);
  float4 cb = *(const float4*)(cn_b + o2);
  float4 pf = *(const float4*)(P + (size_t)b2 * SEQ * CDIM + o2);  // P[0]
  uint32x4 afu[8];
#pragma unroll
  for (int kt = 0; kt < 8; ++kt) afu[kt] = (uint32x4){0, 0, 0, 0};
  __syncthreads();

  for (int t = 0; t < SEQ; ++t) {
    // prefetch P[t+1] early (older than this step's y-store -> counted vmcnt)
    float4 pn = {};
    if (t + 1 < SEQ) pn = *(const float4*)(P + ((size_t)b2 * SEQ + t + 1) * CDIM + o2);

    // phase 1: ctx fragment + MFMA (A rows 4..15 are don't-care: row m of D
    // depends only on row m of A)
    if (l15 < 4) {
#pragma unroll
      for (int kt = 0; kt < 8; ++kt)
        afu[kt] = *(const uint32x4*)(&ctx_lds[l15 * 288 + kt * 32 + lhi * 8]);
    }
    f32x4 acc[4] = {};
#pragma unroll
    for (int nt = 0; nt < 4; ++nt)
#pragma unroll
      for (int kt = 0; kt < 8; ++kt)
        acc[nt] = mfma16(__builtin_bit_cast(bf16x8, afu[kt]),
                         __builtin_bit_cast(bf16x8, wfu[nt][kt]), acc[nt]);
    if (lane < 16) {                       // batches live in lanes 0..15, reg r
#pragma unroll
      for (int nt = 0; nt < 4; ++nt)
#pragma unroll
        for (int r = 0; r < 4; ++r)
          h_lds[r * 256 + wave * 64 + nt * 16 + lane] = acc[nt][r];
    }
    asm volatile("s_waitcnt lgkmcnt(0)" ::: "memory");
    __builtin_amdgcn_s_barrier();
    __builtin_amdgcn_sched_barrier(0);

    // phase 2: all 256 threads; wave == batch
    float4 h4 = *(const float4*)&h_lds[b2 * 256 + o2];
    float g0 = gelu_f(h4.x + pf.x), g1 = gelu_f(h4.y + pf.y);
    float g2 = gelu_f(h4.z + pf.z), g3 = gelu_f(h4.w + pf.w);
    float sm = g0 + g1 + g2 + g3;
    float sq = g0*g0 + g1*g1 + g2*g2 + g3*g3;
#pragma unroll
    for (int msk = 1; msk <= 32; msk <<= 1) { sm += __shfl_xor(sm, msk); sq += __shfl_xor(sq, msk); }
    float mean = sm * (1.f / CDIM);
    float var  = sq * (1.f / CDIM) - mean * mean;
    float inv  = rsqrtf(var + 1e-5f);
    float y0 = (g0 - mean) * inv * cw.x + cb.x;
    float y1 = (g1 - mean) * inv * cw.y + cb.y;
    float y2 = (g2 - mean) * inv * cw.z + cb.z;
    float y3 = (g3 - mean) * inv * cw.w + cb.w;
    ushort4 u; u.x = f2bf(y0); u.y = f2bf(y1); u.z = f2bf(y2); u.w = f2bf(y3);
    *(ushort4*)&ctx_lds[b2 * 288 + o2] = u;
    float4 y; y.x = y0; y.y = y1; y.z = y2; y.w = y3;
    *(float4*)(x + ((size_t)b2 * SEQ + t) * CDIM + o2) = y;   // never drained in-loop
    pf = pn;
    asm volatile("s_waitcnt lgkmcnt(0)" ::: "memory");
    __builtin_amdgcn_s_barrier();
    __builtin_amdgcn_sched_barrier(0);
  }
}

// ---------------------------------------------------------------- qkv rearrange + RoPE (ROT=8)
__global__ __launch_bounds__(256) void rope_k(const ushort* __restrict__ qkv,
                                              ushort* __restrict__ Qo,
                                              ushort* __restrict__ Ko,
                                              ushort* __restrict__ Vt) {
  int m = blockIdx.x;                      // b*S + s
  int b = m >> 10, s = m & 1023;
  int t = threadIdx.x;
  int h = t >> 5, d = t & 31;
  const ushort* row = qkv + (size_t)m * 768;
  float q = bf2f(row[h * 32 + d]);
  float k = bf2f(row[256 + h * 32 + d]);
  float v = bf2f(row[512 + h * 32 + d]);
  if (d < 8) {
    int prt = (d < 4) ? d + 4 : d - 4;
    float sgn = (d < 4) ? -1.f : 1.f;
    float qp = sgn * bf2f(row[h * 32 + prt]);
    float kp = sgn * bf2f(row[256 + h * 32 + prt]);
    int j = d & 3;
    const float invs[4] = {1.f, 0.1f, 0.01f, 0.001f};   // 10000^(-j/4) = 10^-j
    float ang = (float)s * invs[j];
    float c, sn;
    __sincosf(ang, &sn, &c);
    q = q * c + qp * sn;
    k = k * c + kp * sn;
  }
  size_t bh = (size_t)(b * NHEAD + h);
  Qo[(bh * SEQ + s) * HDIM + d] = f2bf(q);
  Ko[(bh * SEQ + s) * HDIM + d] = f2bf(k);
  Vt[bh * HDIM * SEQ + (size_t)d * SEQ + s] = f2bf(v);   // V transposed: [bh][d][s]
}

// ---------------------------------------------------------------- causal flash attention, D=32, MFMA
__global__ __launch_bounds__(256) void attn_k(const ushort* __restrict__ Q,
                                              const ushort* __restrict__ K,
                                              const ushort* __restrict__ VT,
                                              ushort* __restrict__ O) {
  __shared__ __attribute__((aligned(16))) ushort Plds[4 * 16 * 32];  // per-wave 16x32 P tile
  const int tid = threadIdx.x, lane = tid & 63, wave = tid >> 6;
  const int bh = blockIdx.y;
  const int qtile = blockIdx.x * 4 + wave;
  const int q0 = qtile * 16;
  const int l15 = lane & 15, lhi = lane >> 4;
  const float scale = 0.17677669529663689f;   // 1/sqrt(32)

  bf16x8 qa = __builtin_bit_cast(bf16x8,
      *(const uint4*)(Q + ((size_t)bh * SEQ + q0 + l15) * HDIM + lhi * 8));
  const ushort* Kb = K + (size_t)bh * SEQ * HDIM;
  const ushort* Vb = VT + (size_t)bh * HDIM * SEQ;
  ushort* Pw = &Plds[wave * 512];

  f32x4 o0 = {}, o1 = {};
  float mrow[4] = {-1e30f, -1e30f, -1e30f, -1e30f};
  float lrow[4] = {};

  for (int kt = 0; kt <= qtile; kt += 2) {
    const bool t2 = (kt + 1 <= qtile);
    f32x4 z = {};
    bf16x8 kf0 = __builtin_bit_cast(bf16x8, *(const uint4*)(Kb + (size_t)(kt * 16 + l15) * HDIM + lhi * 8));
    f32x4 s0 = mfma16(qa, kf0, z);
    f32x4 s1 = {};
    if (t2) {
      bf16x8 kf1 = __builtin_bit_cast(bf16x8, *(const uint4*)(Kb + (size_t)((kt + 1) * 16 + l15) * HDIM + lhi * 8));
      s1 = mfma16(qa, kf1, z);
    }
    float p0[4], p1[4], mx[4];
#pragma unroll
    for (int r = 0; r < 4; ++r) {
      int qr = q0 + lhi * 4 + r;
      int kc0 = kt * 16 + l15;
      p0[r] = (kc0 <= qr) ? s0[r] * scale : -1e30f;
      p1[r] = (t2 && kc0 + 16 <= qr) ? s1[r] * scale : -1e30f;
      mx[r] = fmaxf(p0[r], p1[r]);
    }
#pragma unroll
    for (int msk = 1; msk <= 8; msk <<= 1)
#pragma unroll
      for (int r = 0; r < 4; ++r) mx[r] = fmaxf(mx[r], __shfl_xor(mx[r], msk));
    float rs[4];
#pragma unroll
    for (int r = 0; r < 4; ++r) {
      float mn = fmaxf(mrow[r], mx[r]);
      float alpha = __expf(mrow[r] - mn);
      mrow[r] = mn;
      p0[r] = __expf(p0[r] - mn);
      p1[r] = __expf(p1[r] - mn);
      rs[r] = p0[r] + p1[r];
      lrow[r] = lrow[r] * alpha;
      o0[r] *= alpha; o1[r] *= alpha;
    }
#pragma unroll
    for (int msk = 1; msk <= 8; msk <<= 1)
#pragma unroll
      for (int r = 0; r < 4; ++r) rs[r] += __shfl_xor(rs[r], msk);
#pragma unroll
    for (int r = 0; r < 4; ++r) lrow[r] += rs[r];
#pragma unroll
    for (int r = 0; r < 4; ++r) {
      Pw[(lhi * 4 + r) * 32 + l15]      = f2bf(p0[r]);
      Pw[(lhi * 4 + r) * 32 + 16 + l15] = f2bf(p1[r]);
    }
    bf16x8 pa  = __builtin_bit_cast(bf16x8, *(const uint4*)(&Pw[l15 * 32 + lhi * 8]));
    bf16x8 v0f = __builtin_bit_cast(bf16x8, *(const uint4*)(Vb + (size_t)l15 * SEQ + kt * 16 + lhi * 8));
    bf16x8 v1f = __builtin_bit_cast(bf16x8, *(const uint4*)(Vb + (size_t)(16 + l15) * SEQ + kt * 16 + lhi * 8));
    o0 = mfma16(pa, v0f, o0);
    o1 = mfma16(pa, v1f, o1);
  }
  const int b = bh >> 3, h = bh & 7;
#pragma unroll
  for (int r = 0; r < 4; ++r) {
    float inv = 1.f / lrow[r];
    int qr = q0 + lhi * 4 + r;
    size_t base = ((size_t)(b * SEQ + qr)) * CDIM + h * HDIM;
    O[base + l15]      = f2bf(o0[r] * inv);
    O[base + 16 + l15] = f2bf(o1[r] * inv);
  }
}

// ---------------------------------------------------------------- launcher
static size_t ws_take(size_t& o, size_t bytes) {
  size_t r = o;
  o += (bytes + 255) & ~(size_t)255;
  return r;
}

extern "C" void kernel_launch(void* const* d_in, const int* in_sizes, int n_in,
                              void* d_out, int out_size, void* d_ws, size_t ws_size,
                              hipStream_t stream) {
  (void)in_sizes; (void)n_in; (void)out_size; (void)ws_size;
  const int*   input_ids = (const int*)  d_in[0];
  const float* prev_ctx  = (const float*)d_in[1];
  const float* embed_w   = (const float*)d_in[2];
  const float* en_w      = (const float*)d_in[3];
  const float* en_b      = (const float*)d_in[4];
  const float* ctx_w     = (const float*)d_in[5];
  const float* ctx_b     = (const float*)d_in[6];
  const float* cn_w      = (const float*)d_in[7];
  const float* cn_b      = (const float*)d_in[8];
  const float* ln1_w     = (const float*)d_in[9];
  const float* ln1_b     = (const float*)d_in[10];
  const float* ln2_w     = (const float*)d_in[11];
  const float* ln2_b     = (const float*)d_in[12];
  const float* qkv_w     = (const float*)d_in[13];
  const float* qkv_b     = (const float*)d_in[14];
  const float* ao_w      = (const float*)d_in[15];
  const float* ao_b      = (const float*)d_in[16];
  const float* fc1_w     = (const float*)d_in[17];
  const float* fc1_b     = (const float*)d_in[18];
  const float* fc2_w     = (const float*)d_in[19];
  const float* fc2_b     = (const float*)d_in[20];
  const float* fln_w     = (const float*)d_in[21];
  const float* fln_b     = (const float*)d_in[22];
  const float* out_w     = (const float*)d_in[23];
  float* logits = (float*)d_out;

  char* ws = (char*)d_ws;
  size_t o = 0;
  ushort* WB_OUT = (ushort*)(ws + ws_take(o, (size_t)NVOC * CDIM * 2));
  ushort* TOK    = (ushort*)(ws + ws_take(o, (size_t)NROWS * EDIM * 2));
  float*  PBUF   = (float*) (ws + ws_take(o, (size_t)NROWS * CDIM * 4));
  float*  XBUF   = (float*) (ws + ws_take(o, (size_t)NROWS * CDIM * 4));
  ushort* AIN    = (ushort*)(ws + ws_take(o, (size_t)NROWS * CDIM * 2));
  ushort* MIN    = (ushort*)(ws + ws_take(o, (size_t)NROWS * CDIM * 2));
  ushort* QKVB   = (ushort*)(ws + ws_take(o, (size_t)NROWS * 768 * 2));
  ushort* QB     = (ushort*)(ws + ws_take(o, (size_t)NROWS * CDIM * 2));
  ushort* KB     = (ushort*)(ws + ws_take(o, (size_t)NROWS * CDIM * 2));
  ushort* VTB    = (ushort*)(ws + ws_take(o, (size_t)NROWS * CDIM * 2));
  ushort* OB     = (ushort*)(ws + ws_take(o, (size_t)NROWS * CDIM * 2));
  ushort* TBUF   = (ushort*)(ws + ws_take(o, (size_t)NROWS * IDIM * 2));
  ushort* XLN    = (ushort*)(ws + ws_take(o, (size_t)NROWS * CDIM * 2));

  cvt_k<<<dim3(2048), dim3(256), 0, stream>>>(out_w, WB_OUT, NVOC * CDIM / 4);
  embed_ln_k<<<dim3(NROWS), dim3(64), 0, stream>>>(input_ids, embed_w, en_w, en_b, TOK);
  gemm_k<GF_BIAS | GF_WF32><<<dim3(32, 2), dim3(256), 0, stream>>>(
      TOK, EDIM, (const void*)(ctx_w + 256), 768, ctx_b, (void*)PBUF, CDIM, EDIM);
  scan_k<<<dim3(1), dim3(256), 0, stream>>>(ctx_w, prev_ctx, PBUF, cn_w, cn_b, XBUF);

  for (int l = 0; l < NLAY; ++l) {
    ln_k<true><<<dim3(NROWS / 4), dim3(256), 0, stream>>>(
        XBUF, ln1_w + l * CDIM, ln1_b + l * CDIM, ln2_w + l * CDIM, ln2_b + l * CDIM, AIN, MIN);
    gemm_k<GF_BIAS | GF_BF16O | GF_WF32><<<dim3(32, 6), dim3(256), 0, stream>>>(
        AIN, CDIM, (const void*)(qkv_w + (size_t)l * 768 * CDIM), CDIM,
        qkv_b + l * 768, (void*)QKVB, 768, CDIM);
    rope_k<<<dim3(NROWS), dim3(256), 0, stream>>>(QKVB, QB, KB, VTB);
    attn_k<<<dim3(16, 32), dim3(256), 0, stream>>>(QB, KB, VTB, OB);
    gemm_k<GF_BIAS | GF_ACC | GF_WF32><<<dim3(32, 2), dim3(256), 0, stream>>>(
        OB, CDIM, (const void*)(ao_w + (size_t)l * CDIM * CDIM), CDIM,
        ao_b + l * CDIM, (void*)XBUF, CDIM, CDIM);
    gemm_k<GF_BIAS | GF_GELU | GF_BF16O | GF_WF32><<<dim3(32, 8), dim3(256), 0, stream>>>(
        MIN, CDIM, (const void*)(fc1_w + (size_t)l * IDIM * CDIM), CDIM,
        fc1_b + l * IDIM, (void*)TBUF, IDIM, CDIM);
    gemm_k<GF_BIAS | GF_ACC | GF_WF32><<<dim3(32, 2), dim3(256), 0, stream>>>(
        TBUF, IDIM, (const void*)(fc2_w + (size_t)l * CDIM * IDIM), IDIM,
        fc2_b + l * CDIM, (void*)XBUF, CDIM, IDIM);
  }

  ln_k<false><<<dim3(NROWS / 4), dim3(256), 0, stream>>>(
      XBUF, fln_w, fln_b, nullptr, nullptr, XLN, nullptr);
  gemm_k<0><<<dim3(32, 393), dim3(256), 0, stream>>>(
      XLN, CDIM, (const void*)WB_OUT, CDIM, nullptr, (void*)logits, NVOC, CDIM);
}

// Round 4
// 2330.140 us; speedup vs baseline: 1.4437x; 1.0173x over previous
//
#include <hip/hip_runtime.h>

// ---------------------------------------------------------------- types/helpers
typedef __bf16 bf16x8 __attribute__((ext_vector_type(8)));
typedef float  f32x4  __attribute__((ext_vector_type(4)));
typedef unsigned uint32x4 __attribute__((ext_vector_type(4)));

#define DEV __device__ __forceinline__

DEV ushort f2bf(float f) {                       // fp32 -> bf16 RNE
  unsigned u = __builtin_bit_cast(unsigned, f);
  u += 0x7FFFu + ((u >> 16) & 1u);
  return (ushort)(u >> 16);
}
DEV float bf2f(ushort u) { return __builtin_bit_cast(float, ((unsigned)u) << 16); }
DEV unsigned pk2(ushort a, ushort b) { return (unsigned)a | ((unsigned)b << 16); }

DEV f32x4 mfma16(bf16x8 a, bf16x8 b, f32x4 c) {
  return __builtin_amdgcn_mfma_f32_16x16x32_bf16(a, b, c, 0, 0, 0);
}

// jax.nn.gelu approximate=True: 0.5x(1+tanh(u)) == x*sigmoid(2u), one v_exp + rcp
DEV float gelu_f(float x) {
  float u = 0.7978845608028654f * (x + 0.044715f * x * x * x);
  return x / (1.f + __expf(-2.f * u));
}

#define SEQ  1024
#define NBAT 4
#define CDIM 256
#define EDIM 512
#define NLAY 6
#define NHEAD 8
#define HDIM 32
#define IDIM 1024
#define NVOC 50304
#define NROWS (NBAT * SEQ)   // 4096

// ---------------------------------------------------------------- fp32 -> bf16 convert
__global__ __launch_bounds__(256) void cvt_k(const float* __restrict__ src,
                                             ushort* __restrict__ dst, int n4) {
  int i = blockIdx.x * blockDim.x + threadIdx.x;
  int stride = gridDim.x * blockDim.x;
  for (; i < n4; i += stride) {
    float4 f = ((const float4*)src)[i];
    ushort4 u; u.x = f2bf(f.x); u.y = f2bf(f.y); u.z = f2bf(f.z); u.w = f2bf(f.w);
    ((ushort4*)dst)[i] = u;
  }
}

// ---------------------------------------------------------------- embed gather + LN (E=512)
__global__ __launch_bounds__(64) void embed_ln_k(const int* __restrict__ ids,
                                                 const float* __restrict__ ew,
                                                 const float* __restrict__ w,
                                                 const float* __restrict__ b,
                                                 ushort* __restrict__ tok) {
  int m = blockIdx.x, t = threadIdx.x;
  const float* row = ew + (size_t)ids[m] * EDIM;
  float4 v0 = *(const float4*)(row + t * 8);
  float4 v1 = *(const float4*)(row + t * 8 + 4);
  float sm = v0.x + v0.y + v0.z + v0.w + v1.x + v1.y + v1.z + v1.w;
  float sq = v0.x*v0.x + v0.y*v0.y + v0.z*v0.z + v0.w*v0.w
           + v1.x*v1.x + v1.y*v1.y + v1.z*v1.z + v1.w*v1.w;
#pragma unroll
  for (int msk = 1; msk <= 32; msk <<= 1) { sm += __shfl_xor(sm, msk); sq += __shfl_xor(sq, msk); }
  float mean = sm * (1.f / EDIM);
  float var  = sq * (1.f / EDIM) - mean * mean;
  float inv  = rsqrtf(var + 1e-5f);
  float4 w0 = *(const float4*)(w + t * 8), w1 = *(const float4*)(w + t * 8 + 4);
  float4 b0 = *(const float4*)(b + t * 8), b1 = *(const float4*)(b + t * 8 + 4);
  ushort4 u0, u1;
  u0.x = f2bf((v0.x - mean) * inv * w0.x + b0.x);
  u0.y = f2bf((v0.y - mean) * inv * w0.y + b0.y);
  u0.z = f2bf((v0.z - mean) * inv * w0.z + b0.z);
  u0.w = f2bf((v0.w - mean) * inv * w0.w + b0.w);
  u1.x = f2bf((v1.x - mean) * inv * w1.x + b1.x);
  u1.y = f2bf((v1.y - mean) * inv * w1.y + b1.y);
  u1.z = f2bf((v1.z - mean) * inv * w1.z + b1.z);
  u1.w = f2bf((v1.w - mean) * inv * w1.w + b1.w);
  *(ushort4*)(tok + (size_t)m * EDIM + t * 8)     = u0;
  *(ushort4*)(tok + (size_t)m * EDIM + t * 8 + 4) = u1;
}

// ---------------------------------------------------------------- LayerNorm (C=256) -> bf16, wave-per-row
template <bool DUAL>
__global__ __launch_bounds__(256) void ln_k(const float* __restrict__ x,
                                            const float* __restrict__ w1, const float* __restrict__ b1,
                                            const float* __restrict__ w2, const float* __restrict__ b2,
                                            ushort* __restrict__ o1, ushort* __restrict__ o2) {
  int wave = threadIdx.x >> 6, t = threadIdx.x & 63;
  int m = blockIdx.x * 4 + wave;
  const float* row = x + (size_t)m * CDIM;
  float4 v = *(const float4*)(row + t * 4);
  float sm = v.x + v.y + v.z + v.w;
  float sq = v.x*v.x + v.y*v.y + v.z*v.z + v.w*v.w;
#pragma unroll
  for (int msk = 1; msk <= 32; msk <<= 1) { sm += __shfl_xor(sm, msk); sq += __shfl_xor(sq, msk); }
  float mean = sm * (1.f / CDIM);
  float var  = sq * (1.f / CDIM) - mean * mean;
  float inv  = rsqrtf(var + 1e-5f);
  float n0 = (v.x - mean) * inv, n1 = (v.y - mean) * inv, n2 = (v.z - mean) * inv, n3 = (v.w - mean) * inv;
  {
    float4 wv = *(const float4*)(w1 + t * 4), bv = *(const float4*)(b1 + t * 4);
    ushort4 u; u.x = f2bf(n0*wv.x+bv.x); u.y = f2bf(n1*wv.y+bv.y); u.z = f2bf(n2*wv.z+bv.z); u.w = f2bf(n3*wv.w+bv.w);
    *(ushort4*)(o1 + (size_t)m * CDIM + t * 4) = u;
  }
  if constexpr (DUAL) {
    float4 wv = *(const float4*)(w2 + t * 4), bv = *(const float4*)(b2 + t * 4);
    ushort4 u; u.x = f2bf(n0*wv.x+bv.x); u.y = f2bf(n1*wv.y+bv.y); u.z = f2bf(n2*wv.z+bv.z); u.w = f2bf(n3*wv.w+bv.w);
    *(ushort4*)(o2 + (size_t)m * CDIM + t * 4) = u;
  }
}

// ---------------------------------------------------------------- generic 128x128 MFMA GEMM
enum { GF_BIAS = 1, GF_GELU = 2, GF_ACC = 4, GF_BF16O = 8, GF_WF32 = 16 };

template <int FLAGS>
__global__ __launch_bounds__(256) void gemm_k(const ushort* __restrict__ A, int lda,
                                              const void* __restrict__ Wv, int ldw,
                                              const float* __restrict__ bias,
                                              void* __restrict__ C, int ldc, int K) {
  __shared__ __attribute__((aligned(16))) ushort lsA[128 * 32];
  __shared__ __attribute__((aligned(16))) ushort lsB[128 * 32];
  const int tid = threadIdx.x, lane = tid & 63, wave = tid >> 6;
  const int wm = wave >> 1, wn = wave & 1;
  const int row0 = blockIdx.x * 128, col0 = blockIdx.y * 128;
  const int l15 = lane & 15, koff = (lane >> 4) * 8;

  f32x4 acc[4][4] = {};
  for (int k0 = 0; k0 < K; k0 += 32) {
    __syncthreads();
#pragma unroll
    for (int p = 0; p < 2; ++p) {
      int c = tid + p * 256;          // 512 chunks of 8 bf16
      int r = c >> 2, k8 = (c & 3) * 8;
      *(uint4*)(&lsA[c * 8]) = *(const uint4*)(A + (size_t)(row0 + r) * lda + k0 + k8);
      if constexpr (FLAGS & GF_WF32) {
        const float* gw = (const float*)Wv + (size_t)(col0 + r) * ldw + k0 + k8;
        float4 f0 = *(const float4*)gw, f1 = *(const float4*)(gw + 4);
        uint4 vw;
        vw.x = pk2(f2bf(f0.x), f2bf(f0.y)); vw.y = pk2(f2bf(f0.z), f2bf(f0.w));
        vw.z = pk2(f2bf(f1.x), f2bf(f1.y)); vw.w = pk2(f2bf(f1.z), f2bf(f1.w));
        *(uint4*)(&lsB[c * 8]) = vw;
      } else {
        *(uint4*)(&lsB[c * 8]) = *(const uint4*)((const ushort*)Wv + (size_t)(col0 + r) * ldw + k0 + k8);
      }
    }
    __syncthreads();
    bf16x8 af[4], bfr[4];
#pragma unroll
    for (int mt = 0; mt < 4; ++mt)
      af[mt] = __builtin_bit_cast(bf16x8, *(const uint4*)(&lsA[(wm * 64 + mt * 16 + l15) * 32 + koff]));
#pragma unroll
    for (int nt = 0; nt < 4; ++nt)
      bfr[nt] = __builtin_bit_cast(bf16x8, *(const uint4*)(&lsB[(wn * 64 + nt * 16 + l15) * 32 + koff]));
#pragma unroll
    for (int mt = 0; mt < 4; ++mt)
#pragma unroll
      for (int nt = 0; nt < 4; ++nt)
        acc[mt][nt] = mfma16(af[mt], bfr[nt], acc[mt][nt]);
  }
#pragma unroll
  for (int mt = 0; mt < 4; ++mt) {
#pragma unroll
    for (int nt = 0; nt < 4; ++nt) {
      int col = col0 + wn * 64 + nt * 16 + l15;
      float bv = (FLAGS & GF_BIAS) ? bias[col] : 0.f;
      int rowb = row0 + wm * 64 + mt * 16 + (lane >> 4) * 4;
#pragma unroll
      for (int r = 0; r < 4; ++r) {
        float v = acc[mt][nt][r] + bv;
        if constexpr (FLAGS & GF_GELU) v = gelu_f(v);
        size_t off = (size_t)(rowb + r) * ldc + col;
        if constexpr (FLAGS & GF_ACC)        ((float*)C)[off] += v;
        else if constexpr (FLAGS & GF_BF16O) ((ushort*)C)[off] = f2bf(v);
        else                                 ((float*)C)[off] = v;
      }
    }
  }
}

// ---------------------------------------------------------------- sequential context scan (1 block)
// LN folded into weights:  W_c @ LN(g) = inv*(W'@g) - inv*mu*s1 + c1,
//   W' = W_c * diag(cn_w), s1 = W'@1, c1 = W_c@cn_b.
// Loop iteration t:  phase B: raw = W'@g_t (MFMA) with stats(g_t) reduce hidden under it;
//                    phase C: y[t] = LN(g_t) from regs;  g_{t+1} = gelu(inv*raw - inv*mu*s1 + c1 + P[t+1]).
__global__ __launch_bounds__(256, 1) void scan_k(const float* __restrict__ ctx_w,
                                                 const float* __restrict__ prev_ctx,
                                                 const float* __restrict__ P,
                                                 const float* __restrict__ cn_w,
                                                 const float* __restrict__ cn_b,
                                                 float* __restrict__ x) {
  __shared__ __attribute__((aligned(16))) ushort g_lds[4 * 288];   // [batch][col], stride 288
  __shared__ __attribute__((aligned(16))) float  h_lds[4 * 256];   // raw matmul out [batch][col]
  const int tid = threadIdx.x, lane = tid & 63, wave = tid >> 6;
  const int l15 = lane & 15, lhi = lane >> 4;
  const int b2 = wave, o2 = (tid & 63) * 4;

  // ---- per-thread epilogue constants for own 4 output cols
  float4 wv = *(const float4*)(cn_w + o2);
  float4 bv = *(const float4*)(cn_b + o2);
  float s1v[4] = {}, c1v[4] = {};
#pragma unroll 1
  for (int kk = 0; kk < CDIM; kk += 4) {
    float4 wk = *(const float4*)(cn_w + kk);
    float4 bk = *(const float4*)(cn_b + kk);
#pragma unroll
    for (int j = 0; j < 4; ++j) {
      float4 Wr = *(const float4*)(ctx_w + (size_t)(o2 + j) * 768 + kk);
      s1v[j] += Wr.x * wk.x + Wr.y * wk.y + Wr.z * wk.z + Wr.w * wk.w;
      c1v[j] += Wr.x * bk.x + Wr.y * bk.y + Wr.z * bk.z + Wr.w * bk.w;
    }
  }

  // ---- prologue step 0: plain-W fragments, A = bf16(prev_ctx)
  uint32x4 wfu[4][8];
#pragma unroll
  for (int nt = 0; nt < 4; ++nt)
#pragma unroll
    for (int kt = 0; kt < 8; ++kt) {
      int n = wave * 64 + nt * 16 + l15;
      int k = kt * 32 + lhi * 8;
      const float* s = ctx_w + (size_t)n * 768 + k;
      float4 f0 = *(const float4*)s, f1 = *(const float4*)(s + 4);
      uint32x4 vw;
      vw.x = pk2(f2bf(f0.x), f2bf(f0.y)); vw.y = pk2(f2bf(f0.z), f2bf(f0.w));
      vw.z = pk2(f2bf(f1.x), f2bf(f1.y)); vw.w = pk2(f2bf(f1.z), f2bf(f1.w));
      wfu[nt][kt] = vw;
    }
  {
    float4 c4 = *(const float4*)(prev_ctx + b2 * CDIM + o2);
    ushort4 u; u.x = f2bf(c4.x); u.y = f2bf(c4.y); u.z = f2bf(c4.z); u.w = f2bf(c4.w);
    *(ushort4*)&g_lds[b2 * 288 + o2] = u;
  }
  float4 pf = *(const float4*)(P + (size_t)b2 * SEQ * CDIM + o2);   // P[0]
  uint32x4 afu[8];
#pragma unroll
  for (int kt = 0; kt < 8; ++kt) afu[kt] = (uint32x4){0, 0, 0, 0};
  __syncthreads();

  // step-0 matmul: raw0 = W @ bf16(prev_ctx)
  if (l15 < 4) {
#pragma unroll
    for (int kt = 0; kt < 8; ++kt)
      afu[kt] = *(const uint32x4*)(&g_lds[l15 * 288 + kt * 32 + lhi * 8]);
  }
  {
    f32x4 acc[4] = {};
#pragma unroll
    for (int nt = 0; nt < 4; ++nt)
#pragma unroll
      for (int kt = 0; kt < 8; ++kt)
        acc[nt] = mfma16(__builtin_bit_cast(bf16x8, afu[kt]),
                         __builtin_bit_cast(bf16x8, wfu[nt][kt]), acc[nt]);
    if (lane < 16) {
#pragma unroll
      for (int nt = 0; nt < 4; ++nt)
#pragma unroll
        for (int r = 0; r < 4; ++r)
          h_lds[r * 256 + wave * 64 + nt * 16 + lane] = acc[nt][r];
    }
  }
  asm volatile("s_waitcnt lgkmcnt(0)" ::: "memory");
  __builtin_amdgcn_s_barrier();

  // g_0 = gelu(raw0 + P[0]); seed local stats; write g_0 to LDS
  float gr[4];
  float lsm, lsq;
  {
    float4 h4 = *(const float4*)&h_lds[b2 * 256 + o2];
    gr[0] = gelu_f(h4.x + pf.x); gr[1] = gelu_f(h4.y + pf.y);
    gr[2] = gelu_f(h4.z + pf.z); gr[3] = gelu_f(h4.w + pf.w);
    ushort4 u; u.x = f2bf(gr[0]); u.y = f2bf(gr[1]); u.z = f2bf(gr[2]); u.w = f2bf(gr[3]);
    *(ushort4*)&g_lds[b2 * 288 + o2] = u;
    lsm = gr[0] + gr[1] + gr[2] + gr[3];
    lsq = gr[0]*gr[0] + gr[1]*gr[1] + gr[2]*gr[2] + gr[3]*gr[3];
  }
  // swap fragments to W' = W_c * diag(cn_w)
#pragma unroll
  for (int nt = 0; nt < 4; ++nt)
#pragma unroll
    for (int kt = 0; kt < 8; ++kt) {
      int n = wave * 64 + nt * 16 + l15;
      int k = kt * 32 + lhi * 8;
      const float* s = ctx_w + (size_t)n * 768 + k;
      float4 f0 = *(const float4*)s, f1 = *(const float4*)(s + 4);
      float4 w0 = *(const float4*)(cn_w + k), w1 = *(const float4*)(cn_w + k + 4);
      uint32x4 vw;
      vw.x = pk2(f2bf(f0.x * w0.x), f2bf(f0.y * w0.y));
      vw.y = pk2(f2bf(f0.z * w0.z), f2bf(f0.w * w0.w));
      vw.z = pk2(f2bf(f1.x * w1.x), f2bf(f1.y * w1.y));
      vw.w = pk2(f2bf(f1.z * w1.z), f2bf(f1.w * w1.w));
      wfu[nt][kt] = vw;
    }
  pf = *(const float4*)(P + ((size_t)b2 * SEQ + 1) * CDIM + o2);   // P[1]
  asm volatile("s_waitcnt lgkmcnt(0)" ::: "memory");
  __builtin_amdgcn_s_barrier();

  for (int t = 0; t < SEQ; ++t) {
    // ---- phase B: prefetch P[t+2]; MFMA raw = W'@g_t; stats(g_t) reduce hidden under MFMA
    int tp = (t + 2 < SEQ) ? t + 2 : SEQ - 1;
    float4 pn = *(const float4*)(P + ((size_t)b2 * SEQ + tp) * CDIM + o2);

    if (l15 < 4) {
#pragma unroll
      for (int kt = 0; kt < 8; ++kt)
        afu[kt] = *(const uint32x4*)(&g_lds[l15 * 288 + kt * 32 + lhi * 8]);
    }
    float sm = lsm, sq = lsq;
#pragma unroll
    for (int msk = 1; msk <= 32; msk <<= 1) { sm += __shfl_xor(sm, msk); sq += __shfl_xor(sq, msk); }
    f32x4 acc[4] = {};
#pragma unroll
    for (int nt = 0; nt < 4; ++nt)
#pragma unroll
      for (int kt = 0; kt < 8; ++kt)
        acc[nt] = mfma16(__builtin_bit_cast(bf16x8, afu[kt]),
                         __builtin_bit_cast(bf16x8, wfu[nt][kt]), acc[nt]);
    float mu  = sm * (1.f / CDIM);
    float inv = rsqrtf(sq * (1.f / CDIM) - mu * mu + 1e-5f);
    float invmu = inv * mu;
    if (lane < 16) {
#pragma unroll
      for (int nt = 0; nt < 4; ++nt)
#pragma unroll
        for (int r = 0; r < 4; ++r)
          h_lds[r * 256 + wave * 64 + nt * 16 + lane] = acc[nt][r];
    }
    asm volatile("s_waitcnt lgkmcnt(0)" ::: "memory");
    __builtin_amdgcn_s_barrier();

    // ---- phase C: y[t] = LN(g_t) from regs; g_{t+1} = gelu(inv*raw - invmu*s1 + c1 + P[t+1])
    float4 h4 = *(const float4*)&h_lds[b2 * 256 + o2];
    float4 y;
    y.x = wv.x * (inv * gr[0] - invmu) + bv.x;
    y.y = wv.y * (inv * gr[1] - invmu) + bv.y;
    y.z = wv.z * (inv * gr[2] - invmu) + bv.z;
    y.w = wv.w * (inv * gr[3] - invmu) + bv.w;
    *(float4*)(x + ((size_t)b2 * SEQ + t) * CDIM + o2) = y;

    gr[0] = gelu_f(inv * h4.x - invmu * s1v[0] + c1v[0] + pf.x);
    gr[1] = gelu_f(inv * h4.y - invmu * s1v[1] + c1v[1] + pf.y);
    gr[2] = gelu_f(inv * h4.z - invmu * s1v[2] + c1v[2] + pf.z);
    gr[3] = gelu_f(inv * h4.w - invmu * s1v[3] + c1v[3] + pf.w);
    ushort4 u; u.x = f2bf(gr[0]); u.y = f2bf(gr[1]); u.z = f2bf(gr[2]); u.w = f2bf(gr[3]);
    *(ushort4*)&g_lds[b2 * 288 + o2] = u;
    lsm = gr[0] + gr[1] + gr[2] + gr[3];
    lsq = gr[0]*gr[0] + gr[1]*gr[1] + gr[2]*gr[2] + gr[3]*gr[3];
    pf = pn;
    asm volatile("s_waitcnt lgkmcnt(0)" ::: "memory");
    __builtin_amdgcn_s_barrier();
  }
}

// ---------------------------------------------------------------- qkv rearrange + RoPE (ROT=8)
__global__ __launch_bounds__(256) void rope_k(const ushort* __restrict__ qkv,
                                              ushort* __restrict__ Qo,
                                              ushort* __restrict__ Ko,
                                              ushort* __restrict__ Vt) {
  int m = blockIdx.x;                      // b*S + s
  int b = m >> 10, s = m & 1023;
  int t = threadIdx.x;
  int h = t >> 5, d = t & 31;
  const ushort* row = qkv + (size_t)m * 768;
  float q = bf2f(row[h * 32 + d]);
  float k = bf2f(row[256 + h * 32 + d]);
  float v = bf2f(row[512 + h * 32 + d]);
  if (d < 8) {
    int prt = (d < 4) ? d + 4 : d - 4;
    float sgn = (d < 4) ? -1.f : 1.f;
    float qp = sgn * bf2f(row[h * 32 + prt]);
    float kp = sgn * bf2f(row[256 + h * 32 + prt]);
    int j = d & 3;
    const float invs[4] = {1.f, 0.1f, 0.01f, 0.001f};   // 10000^(-j/4) = 10^-j
    float ang = (float)s * invs[j];
    float c, sn;
    __sincosf(ang, &sn, &c);
    q = q * c + qp * sn;
    k = k * c + kp * sn;
  }
  size_t bh = (size_t)(b * NHEAD + h);
  Qo[(bh * SEQ + s) * HDIM + d] = f2bf(q);
  Ko[(bh * SEQ + s) * HDIM + d] = f2bf(k);
  Vt[bh * HDIM * SEQ + (size_t)d * SEQ + s] = f2bf(v);   // V transposed: [bh][d][s]
}

// ---------------------------------------------------------------- causal flash attention, D=32, MFMA
__global__ __launch_bounds__(256) void attn_k(const ushort* __restrict__ Q,
                                              const ushort* __restrict__ K,
                                              const ushort* __restrict__ VT,
                                              ushort* __restrict__ O) {
  __shared__ __attribute__((aligned(16))) ushort Plds[4 * 16 * 32];  // per-wave 16x32 P tile
  const int tid = threadIdx.x, lane = tid & 63, wave = tid >> 6;
  const int bh = blockIdx.y;
  const int qtile = blockIdx.x * 4 + wave;
  const int q0 = qtile * 16;
  const int l15 = lane & 15, lhi = lane >> 4;
  const float scale = 0.17677669529663689f;   // 1/sqrt(32)

  bf16x8 qa = __builtin_bit_cast(bf16x8,
      *(const uint4*)(Q + ((size_t)bh * SEQ + q0 + l15) * HDIM + lhi * 8));
  const ushort* Kb = K + (size_t)bh * SEQ * HDIM;
  const ushort* Vb = VT + (size_t)bh * HDIM * SEQ;
  ushort* Pw = &Plds[wave * 512];

  f32x4 o0 = {}, o1 = {};
  float mrow[4] = {-1e30f, -1e30f, -1e30f, -1e30f};
  float lrow[4] = {};

  for (int kt = 0; kt <= qtile; kt += 2) {
    const bool t2 = (kt + 1 <= qtile);
    f32x4 z = {};
    bf16x8 kf0 = __builtin_bit_cast(bf16x8, *(const uint4*)(Kb + (size_t)(kt * 16 + l15) * HDIM + lhi * 8));
    f32x4 s0 = mfma16(qa, kf0, z);
    f32x4 s1 = {};
    if (t2) {
      bf16x8 kf1 = __builtin_bit_cast(bf16x8, *(const uint4*)(Kb + (size_t)((kt + 1) * 16 + l15) * HDIM + lhi * 8));
      s1 = mfma16(qa, kf1, z);
    }
    float p0[4], p1[4], mx[4];
#pragma unroll
    for (int r = 0; r < 4; ++r) {
      int qr = q0 + lhi * 4 + r;
      int kc0 = kt * 16 + l15;
      p0[r] = (kc0 <= qr) ? s0[r] * scale : -1e30f;
      p1[r] = (t2 && kc0 + 16 <= qr) ? s1[r] * scale : -1e30f;
      mx[r] = fmaxf(p0[r], p1[r]);
    }
#pragma unroll
    for (int msk = 1; msk <= 8; msk <<= 1)
#pragma unroll
      for (int r = 0; r < 4; ++r) mx[r] = fmaxf(mx[r], __shfl_xor(mx[r], msk));
    float rs[4];
#pragma unroll
    for (int r = 0; r < 4; ++r) {
      float mn = fmaxf(mrow[r], mx[r]);
      float alpha = __expf(mrow[r] - mn);
      mrow[r] = mn;
      p0[r] = __expf(p0[r] - mn);
      p1[r] = __expf(p1[r] - mn);
      rs[r] = p0[r] + p1[r];
      lrow[r] = lrow[r] * alpha;
      o0[r] *= alpha; o1[r] *= alpha;
    }
#pragma unroll
    for (int msk = 1; msk <= 8; msk <<= 1)
#pragma unroll
      for (int r = 0; r < 4; ++r) rs[r] += __shfl_xor(rs[r], msk);
#pragma unroll
    for (int r = 0; r < 4; ++r) lrow[r] += rs[r];
#pragma unroll
    for (int r = 0; r < 4; ++r) {
      Pw[(lhi * 4 + r) * 32 + l15]      = f2bf(p0[r]);
      Pw[(lhi * 4 + r) * 32 + 16 + l15] = f2bf(p1[r]);
    }
    bf16x8 pa  = __builtin_bit_cast(bf16x8, *(const uint4*)(&Pw[l15 * 32 + lhi * 8]));
    bf16x8 v0f = __builtin_bit_cast(bf16x8, *(const uint4*)(Vb + (size_t)l15 * SEQ + kt * 16 + lhi * 8));
    bf16x8 v1f = __builtin_bit_cast(bf16x8, *(const uint4*)(Vb + (size_t)(16 + l15) * SEQ + kt * 16 + lhi * 8));
    o0 = mfma16(pa, v0f, o0);
    o1 = mfma16(pa, v1f, o1);
  }
  const int b = bh >> 3, h = bh & 7;
#pragma unroll
  for (int r = 0; r < 4; ++r) {
    float inv = 1.f / lrow[r];
    int qr = q0 + lhi * 4 + r;
    size_t base = ((size_t)(b * SEQ + qr)) * CDIM + h * HDIM;
    O[base + l15]      = f2bf(o0[r] * inv);
    O[base + 16 + l15] = f2bf(o1[r] * inv);
  }
}

// ---------------------------------------------------------------- launcher
static size_t ws_take(size_t& o, size_t bytes) {
  size_t r = o;
  o += (bytes + 255) & ~(size_t)255;
  return r;
}

extern "C" void kernel_launch(void* const* d_in, const int* in_sizes, int n_in,
                              void* d_out, int out_size, void* d_ws, size_t ws_size,
                              hipStream_t stream) {
  (void)in_sizes; (void)n_in; (void)out_size; (void)ws_size;
  const int*   input_ids = (const int*)  d_in[0];
  const float* prev_ctx  = (const float*)d_in[1];
  const float* embed_w   = (const float*)d_in[2];
  const float* en_w      = (const float*)d_in[3];
  const float* en_b      = (const float*)d_in[4];
  const float* ctx_w     = (const float*)d_in[5];
  const float* ctx_b     = (const float*)d_in[6];
  const float* cn_w      = (const float*)d_in[7];
  const float* cn_b      = (const float*)d_in[8];
  const float* ln1_w     = (const float*)d_in[9];
  const float* ln1_b     = (const float*)d_in[10];
  const float* ln2_w     = (const float*)d_in[11];
  const float* ln2_b     = (const float*)d_in[12];
  const float* qkv_w     = (const float*)d_in[13];
  const float* qkv_b     = (const float*)d_in[14];
  const float* ao_w      = (const float*)d_in[15];
  const float* ao_b      = (const float*)d_in[16];
  const float* fc1_w     = (const float*)d_in[17];
  const float* fc1_b     = (const float*)d_in[18];
  const float* fc2_w     = (const float*)d_in[19];
  const float* fc2_b     = (const float*)d_in[20];
  const float* fln_w     = (const float*)d_in[21];
  const float* fln_b     = (const float*)d_in[22];
  const float* out_w     = (const float*)d_in[23];
  float* logits = (float*)d_out;

  char* ws = (char*)d_ws;
  size_t o = 0;
  ushort* WB_OUT = (ushort*)(ws + ws_take(o, (size_t)NVOC * CDIM * 2));
  ushort* TOK    = (ushort*)(ws + ws_take(o, (size_t)NROWS * EDIM * 2));
  float*  PBUF   = (float*) (ws + ws_take(o, (size_t)NROWS * CDIM * 4));
  float*  XBUF   = (float*) (ws + ws_take(o, (size_t)NROWS * CDIM * 4));
  ushort* AIN    = (ushort*)(ws + ws_take(o, (size_t)NROWS * CDIM * 2));
  ushort* MIN    = (ushort*)(ws + ws_take(o, (size_t)NROWS * CDIM * 2));
  ushort* QKVB   = (ushort*)(ws + ws_take(o, (size_t)NROWS * 768 * 2));
  ushort* QB     = (ushort*)(ws + ws_take(o, (size_t)NROWS * CDIM * 2));
  ushort* KB     = (ushort*)(ws + ws_take(o, (size_t)NROWS * CDIM * 2));
  ushort* VTB    = (ushort*)(ws + ws_take(o, (size_t)NROWS * CDIM * 2));
  ushort* OB     = (ushort*)(ws + ws_take(o, (size_t)NROWS * CDIM * 2));
  ushort* TBUF   = (ushort*)(ws + ws_take(o, (size_t)NROWS * IDIM * 2));
  ushort* XLN    = (ushort*)(ws + ws_take(o, (size_t)NROWS * CDIM * 2));

  cvt_k<<<dim3(2048), dim3(256), 0, stream>>>(out_w, WB_OUT, NVOC * CDIM / 4);
  embed_ln_k<<<dim3(NROWS), dim3(64), 0, stream>>>(input_ids, embed_w, en_w, en_b, TOK);
  gemm_k<GF_BIAS | GF_WF32><<<dim3(32, 2), dim3(256), 0, stream>>>(
      TOK, EDIM, (const void*)(ctx_w + 256), 768, ctx_b, (void*)PBUF, CDIM, EDIM);
  scan_k<<<dim3(1), dim3(256), 0, stream>>>(ctx_w, prev_ctx, PBUF, cn_w, cn_b, XBUF);

  for (int l = 0; l < NLAY; ++l) {
    ln_k<true><<<dim3(NROWS / 4), dim3(256), 0, stream>>>(
        XBUF, ln1_w + l * CDIM, ln1_b + l * CDIM, ln2_w + l * CDIM, ln2_b + l * CDIM, AIN, MIN);
    gemm_k<GF_BIAS | GF_BF16O | GF_WF32><<<dim3(32, 6), dim3(256), 0, stream>>>(
        AIN, CDIM, (const void*)(qkv_w + (size_t)l * 768 * CDIM), CDIM,
        qkv_b + l * 768, (void*)QKVB, 768, CDIM);
    rope_k<<<dim3(NROWS), dim3(256), 0, stream>>>(QKVB, QB, KB, VTB);
    attn_k<<<dim3(16, 32), dim3(256), 0, stream>>>(QB, KB, VTB, OB);
    gemm_k<GF_BIAS | GF_ACC | GF_WF32><<<dim3(32, 2), dim3(256), 0, stream>>>(
        OB, CDIM, (const void*)(ao_w + (size_t)l * CDIM * CDIM), CDIM,
        ao_b + l * CDIM, (void*)XBUF, CDIM, CDIM);
    gemm_k<GF_BIAS | GF_GELU | GF_BF16O | GF_WF32><<<dim3(32, 8), dim3(256), 0, stream>>>(
        MIN, CDIM, (const void*)(fc1_w + (size_t)l * IDIM * CDIM), CDIM,
        fc1_b + l * IDIM, (void*)TBUF, IDIM, CDIM);
    gemm_k<GF_BIAS | GF_ACC | GF_WF32><<<dim3(32, 2), dim3(256), 0, stream>>>(
        TBUF, IDIM, (const void*)(fc2_w + (size_t)l * CDIM * IDIM), IDIM,
        fc2_b + l * CDIM, (void*)XBUF, CDIM, IDIM);
  }

  ln_k<false><<<dim3(NROWS / 4), dim3(256), 0, stream>>>(
      XBUF, fln_w, fln_b, nullptr, nullptr, XLN, nullptr);
  gemm_k<0><<<dim3(32, 393), dim3(256), 0, stream>>>(
      XLN, CDIM, (const void*)WB_OUT, CDIM, nullptr, (void*)logits, NVOC, CDIM);
}

// Round 5
// 2228.151 us; speedup vs baseline: 1.5098x; 1.0458x over previous
//
#include <hip/hip_runtime.h>

// ---------------------------------------------------------------- types/helpers
typedef __bf16 bf16x8 __attribute__((ext_vector_type(8)));
typedef float  f32x4  __attribute__((ext_vector_type(4)));
typedef unsigned uint32x4 __attribute__((ext_vector_type(4)));

#define DEV __device__ __forceinline__

DEV ushort f2bf(float f) {                       // fp32 -> bf16 RNE
  unsigned u = __builtin_bit_cast(unsigned, f);
  u += 0x7FFFu + ((u >> 16) & 1u);
  return (ushort)(u >> 16);
}
DEV float bf2f(ushort u) { return __builtin_bit_cast(float, ((unsigned)u) << 16); }
DEV unsigned pk2(ushort a, ushort b) { return (unsigned)a | ((unsigned)b << 16); }

DEV f32x4 mfma16(bf16x8 a, bf16x8 b, f32x4 c) {
  return __builtin_amdgcn_mfma_f32_16x16x32_bf16(a, b, c, 0, 0, 0);
}

// jax.nn.gelu approximate=True: 0.5x(1+tanh(u)) == x*sigmoid(2u), one v_exp + rcp
DEV float gelu_f(float x) {
  float u = 0.7978845608028654f * (x + 0.044715f * x * x * x);
  return x / (1.f + __expf(-2.f * u));
}

#define SEQ  1024
#define NBAT 4
#define CDIM 256
#define EDIM 512
#define NLAY 6
#define NHEAD 8
#define HDIM 32
#define IDIM 1024
#define NVOC 50304
#define NROWS (NBAT * SEQ)   // 4096

// ---------------------------------------------------------------- fp32 -> bf16 convert
__global__ __launch_bounds__(256) void cvt_k(const float* __restrict__ src,
                                             ushort* __restrict__ dst, int n4) {
  int i = blockIdx.x * blockDim.x + threadIdx.x;
  int stride = gridDim.x * blockDim.x;
  for (; i < n4; i += stride) {
    float4 f = ((const float4*)src)[i];
    ushort4 u; u.x = f2bf(f.x); u.y = f2bf(f.y); u.z = f2bf(f.z); u.w = f2bf(f.w);
    ((ushort4*)dst)[i] = u;
  }
}

// ---------------------------------------------------------------- embed gather + LN (E=512)
__global__ __launch_bounds__(64) void embed_ln_k(const int* __restrict__ ids,
                                                 const float* __restrict__ ew,
                                                 const float* __restrict__ w,
                                                 const float* __restrict__ b,
                                                 ushort* __restrict__ tok) {
  int m = blockIdx.x, t = threadIdx.x;
  const float* row = ew + (size_t)ids[m] * EDIM;
  float4 v0 = *(const float4*)(row + t * 8);
  float4 v1 = *(const float4*)(row + t * 8 + 4);
  float sm = v0.x + v0.y + v0.z + v0.w + v1.x + v1.y + v1.z + v1.w;
  float sq = v0.x*v0.x + v0.y*v0.y + v0.z*v0.z + v0.w*v0.w
           + v1.x*v1.x + v1.y*v1.y + v1.z*v1.z + v1.w*v1.w;
#pragma unroll
  for (int msk = 1; msk <= 32; msk <<= 1) { sm += __shfl_xor(sm, msk); sq += __shfl_xor(sq, msk); }
  float mean = sm * (1.f / EDIM);
  float var  = sq * (1.f / EDIM) - mean * mean;
  float inv  = rsqrtf(var + 1e-5f);
  float4 w0 = *(const float4*)(w + t * 8), w1 = *(const float4*)(w + t * 8 + 4);
  float4 b0 = *(const float4*)(b + t * 8), b1 = *(const float4*)(b + t * 8 + 4);
  ushort4 u0, u1;
  u0.x = f2bf((v0.x - mean) * inv * w0.x + b0.x);
  u0.y = f2bf((v0.y - mean) * inv * w0.y + b0.y);
  u0.z = f2bf((v0.z - mean) * inv * w0.z + b0.z);
  u0.w = f2bf((v0.w - mean) * inv * w0.w + b0.w);
  u1.x = f2bf((v1.x - mean) * inv * w1.x + b1.x);
  u1.y = f2bf((v1.y - mean) * inv * w1.y + b1.y);
  u1.z = f2bf((v1.z - mean) * inv * w1.z + b1.z);
  u1.w = f2bf((v1.w - mean) * inv * w1.w + b1.w);
  *(ushort4*)(tok + (size_t)m * EDIM + t * 8)     = u0;
  *(ushort4*)(tok + (size_t)m * EDIM + t * 8 + 4) = u1;
}

// ---------------------------------------------------------------- LayerNorm (C=256) -> bf16, wave-per-row
template <bool DUAL>
__global__ __launch_bounds__(256) void ln_k(const float* __restrict__ x,
                                            const float* __restrict__ w1, const float* __restrict__ b1,
                                            const float* __restrict__ w2, const float* __restrict__ b2,
                                            ushort* __restrict__ o1, ushort* __restrict__ o2) {
  int wave = threadIdx.x >> 6, t = threadIdx.x & 63;
  int m = blockIdx.x * 4 + wave;
  const float* row = x + (size_t)m * CDIM;
  float4 v = *(const float4*)(row + t * 4);
  float sm = v.x + v.y + v.z + v.w;
  float sq = v.x*v.x + v.y*v.y + v.z*v.z + v.w*v.w;
#pragma unroll
  for (int msk = 1; msk <= 32; msk <<= 1) { sm += __shfl_xor(sm, msk); sq += __shfl_xor(sq, msk); }
  float mean = sm * (1.f / CDIM);
  float var  = sq * (1.f / CDIM) - mean * mean;
  float inv  = rsqrtf(var + 1e-5f);
  float n0 = (v.x - mean) * inv, n1 = (v.y - mean) * inv, n2 = (v.z - mean) * inv, n3 = (v.w - mean) * inv;
  {
    float4 wv = *(const float4*)(w1 + t * 4), bv = *(const float4*)(b1 + t * 4);
    ushort4 u; u.x = f2bf(n0*wv.x+bv.x); u.y = f2bf(n1*wv.y+bv.y); u.z = f2bf(n2*wv.z+bv.z); u.w = f2bf(n3*wv.w+bv.w);
    *(ushort4*)(o1 + (size_t)m * CDIM + t * 4) = u;
  }
  if constexpr (DUAL) {
    float4 wv = *(const float4*)(w2 + t * 4), bv = *(const float4*)(b2 + t * 4);
    ushort4 u; u.x = f2bf(n0*wv.x+bv.x); u.y = f2bf(n1*wv.y+bv.y); u.z = f2bf(n2*wv.z+bv.z); u.w = f2bf(n3*wv.w+bv.w);
    *(ushort4*)(o2 + (size_t)m * CDIM + t * 4) = u;
  }
}

// ---------------------------------------------------------------- generic 128x128 MFMA GEMM
enum { GF_BIAS = 1, GF_GELU = 2, GF_ACC = 4, GF_BF16O = 8, GF_WF32 = 16 };

template <int FLAGS>
__global__ __launch_bounds__(256) void gemm_k(const ushort* __restrict__ A, int lda,
                                              const void* __restrict__ Wv, int ldw,
                                              const float* __restrict__ bias,
                                              void* __restrict__ C, int ldc, int K) {
  __shared__ __attribute__((aligned(16))) ushort lsA[128 * 32];
  __shared__ __attribute__((aligned(16))) ushort lsB[128 * 32];
  const int tid = threadIdx.x, lane = tid & 63, wave = tid >> 6;
  const int wm = wave >> 1, wn = wave & 1;
  const int row0 = blockIdx.x * 128, col0 = blockIdx.y * 128;
  const int l15 = lane & 15, koff = (lane >> 4) * 8;

  f32x4 acc[4][4] = {};
  for (int k0 = 0; k0 < K; k0 += 32) {
    __syncthreads();
#pragma unroll
    for (int p = 0; p < 2; ++p) {
      int c = tid + p * 256;          // 512 chunks of 8 bf16
      int r = c >> 2, k8 = (c & 3) * 8;
      *(uint4*)(&lsA[c * 8]) = *(const uint4*)(A + (size_t)(row0 + r) * lda + k0 + k8);
      if constexpr (FLAGS & GF_WF32) {
        const float* gw = (const float*)Wv + (size_t)(col0 + r) * ldw + k0 + k8;
        float4 f0 = *(const float4*)gw, f1 = *(const float4*)(gw + 4);
        uint4 vw;
        vw.x = pk2(f2bf(f0.x), f2bf(f0.y)); vw.y = pk2(f2bf(f0.z), f2bf(f0.w));
        vw.z = pk2(f2bf(f1.x), f2bf(f1.y)); vw.w = pk2(f2bf(f1.z), f2bf(f1.w));
        *(uint4*)(&lsB[c * 8]) = vw;
      } else {
        *(uint4*)(&lsB[c * 8]) = *(const uint4*)((const ushort*)Wv + (size_t)(col0 + r) * ldw + k0 + k8);
      }
    }
    __syncthreads();
    bf16x8 af[4], bfr[4];
#pragma unroll
    for (int mt = 0; mt < 4; ++mt)
      af[mt] = __builtin_bit_cast(bf16x8, *(const uint4*)(&lsA[(wm * 64 + mt * 16 + l15) * 32 + koff]));
#pragma unroll
    for (int nt = 0; nt < 4; ++nt)
      bfr[nt] = __builtin_bit_cast(bf16x8, *(const uint4*)(&lsB[(wn * 64 + nt * 16 + l15) * 32 + koff]));
#pragma unroll
    for (int mt = 0; mt < 4; ++mt)
#pragma unroll
      for (int nt = 0; nt < 4; ++nt)
        acc[mt][nt] = mfma16(af[mt], bfr[nt], acc[mt][nt]);
  }
#pragma unroll
  for (int mt = 0; mt < 4; ++mt) {
#pragma unroll
    for (int nt = 0; nt < 4; ++nt) {
      int col = col0 + wn * 64 + nt * 16 + l15;
      float bv = (FLAGS & GF_BIAS) ? bias[col] : 0.f;
      int rowb = row0 + wm * 64 + mt * 16 + (lane >> 4) * 4;
#pragma unroll
      for (int r = 0; r < 4; ++r) {
        float v = acc[mt][nt][r] + bv;
        if constexpr (FLAGS & GF_GELU) v = gelu_f(v);
        size_t off = (size_t)(rowb + r) * ldc + col;
        if constexpr (FLAGS & GF_ACC)        ((float*)C)[off] += v;
        else if constexpr (FLAGS & GF_BF16O) ((ushort*)C)[off] = f2bf(v);
        else                                 ((float*)C)[off] = v;
      }
    }
  }
}

// ---------------------------------------------------------------- sequential context scan (1 block)
// One barrier per step. MFMA computes h = W'·g with B-slots replicated
// (slot l15 holds batch l15&3), so lane (l15,lhi) consumes acc tile mt=l15>>2
// and owns (batch=l15&3, cols ccol..ccol+3). LN folded into W' as in R3/R4:
//   u_{t+1} = inv_t*(W'@g_t) - inv_t*mu_t*s1 + c1 + P[t+1],  g = gelu(u).
// P prefetched 3 iterations deep; y-store never drained (raw lgkm-only barrier).
__global__ __launch_bounds__(256, 1) void scan_k(const float* __restrict__ ctx_w,
                                                 const float* __restrict__ prev_ctx,
                                                 const float* __restrict__ P,
                                                 const float* __restrict__ cn_w,
                                                 const float* __restrict__ cn_b,
                                                 float* __restrict__ x) {
  __shared__ __attribute__((aligned(16))) ushort g_lds[2][4 * 288];     // [buf][batch][col] stride 288
  __shared__ __attribute__((aligned(16))) float  part_lds[2][4][16][2]; // [buf][batch][slot]{s,q}
  const int tid = threadIdx.x, lane = tid & 63, wave = tid >> 6;
  const int l15 = lane & 15, lhi = lane >> 4;
  const int bb = l15 & 3;                 // batch this lane epilogues
  const int ss = l15 >> 2;                // acc tile this lane consumes
  const int ccol = wave * 64 + ss * 16 + lhi * 4;   // 4 output cols this lane owns

  // ---- per-lane epilogue constants for own 4 cols
  float4 wv  = *(const float4*)(cn_w + ccol);
  float4 bvv = *(const float4*)(cn_b + ccol);
  float s1v[4] = {}, c1v[4] = {};
#pragma unroll 1
  for (int kk = 0; kk < CDIM; kk += 4) {
    float4 wk = *(const float4*)(cn_w + kk);
    float4 bk = *(const float4*)(cn_b + kk);
#pragma unroll
    for (int j = 0; j < 4; ++j) {
      float4 Wr = *(const float4*)(ctx_w + (size_t)(ccol + j) * 768 + kk);
      s1v[j] += Wr.x * wk.x + Wr.y * wk.y + Wr.z * wk.z + Wr.w * wk.w;
      c1v[j] += Wr.x * bk.x + Wr.y * bk.y + Wr.z * bk.z + Wr.w * bk.w;
    }
  }

  // ---- stage bf16(prev_ctx) into g_lds[0]
  {
    float4 c4 = *(const float4*)(prev_ctx + bb * CDIM + ccol);
    ushort4 u; u.x = f2bf(c4.x); u.y = f2bf(c4.y); u.z = f2bf(c4.z); u.w = f2bf(c4.w);
    *(ushort4*)&g_lds[0][bb * 288 + ccol] = u;
  }

  // ---- plain-W fragments for step 0 (A-frag: row = out_col, k-slice by lhi)
  uint32x4 wfu[4][8];
#pragma unroll
  for (int mt = 0; mt < 4; ++mt)
#pragma unroll
    for (int kt = 0; kt < 8; ++kt) {
      const float* s = ctx_w + (size_t)(wave * 64 + mt * 16 + l15) * 768 + kt * 32 + lhi * 8;
      float4 f0 = *(const float4*)s, f1 = *(const float4*)(s + 4);
      uint32x4 vw;
      vw.x = pk2(f2bf(f0.x), f2bf(f0.y)); vw.y = pk2(f2bf(f0.z), f2bf(f0.w));
      vw.z = pk2(f2bf(f1.x), f2bf(f1.y)); vw.w = pk2(f2bf(f1.z), f2bf(f1.w));
      wfu[mt][kt] = vw;
    }
  float4 pf  = *(const float4*)(P + ((size_t)bb * SEQ + 0) * CDIM + ccol);
  float4 pn1 = *(const float4*)(P + ((size_t)bb * SEQ + 1) * CDIM + ccol);
  float4 pn2 = *(const float4*)(P + ((size_t)bb * SEQ + 2) * CDIM + ccol);
  __syncthreads();

  // ---- step 0: raw0 = W @ bf16(prev_ctx); g_0 = gelu(raw0 + P[0])
  float gr[4];
  {
    uint32x4 bfr[8];
#pragma unroll
    for (int kt = 0; kt < 8; ++kt)
      bfr[kt] = *(const uint32x4*)(&g_lds[0][bb * 288 + kt * 32 + lhi * 8]);
    f32x4 acc[4] = {};
#pragma unroll
    for (int mt = 0; mt < 4; ++mt)
#pragma unroll
      for (int kt = 0; kt < 8; ++kt)
        acc[mt] = mfma16(__builtin_bit_cast(bf16x8, wfu[mt][kt]),
                         __builtin_bit_cast(bf16x8, bfr[kt]), acc[mt]);
    f32x4 av = (ss == 0) ? acc[0] : (ss == 1) ? acc[1] : (ss == 2) ? acc[2] : acc[3];
    gr[0] = gelu_f(av[0] + pf.x); gr[1] = gelu_f(av[1] + pf.y);
    gr[2] = gelu_f(av[2] + pf.z); gr[3] = gelu_f(av[3] + pf.w);
  }

  // ---- swap fragments to W' = W_c * diag(cn_w)
#pragma unroll
  for (int mt = 0; mt < 4; ++mt)
#pragma unroll
    for (int kt = 0; kt < 8; ++kt) {
      int k = kt * 32 + lhi * 8;
      const float* s = ctx_w + (size_t)(wave * 64 + mt * 16 + l15) * 768 + k;
      float4 f0 = *(const float4*)s, f1 = *(const float4*)(s + 4);
      float4 w0 = *(const float4*)(cn_w + k), w1 = *(const float4*)(cn_w + k + 4);
      uint32x4 vw;
      vw.x = pk2(f2bf(f0.x * w0.x), f2bf(f0.y * w0.y));
      vw.y = pk2(f2bf(f0.z * w0.z), f2bf(f0.w * w0.w));
      vw.z = pk2(f2bf(f1.x * w1.x), f2bf(f1.y * w1.y));
      vw.w = pk2(f2bf(f1.z * w1.z), f2bf(f1.w * w1.w));
      wfu[mt][kt] = vw;
    }
#pragma unroll
  for (int mt = 0; mt < 4; ++mt)
#pragma unroll
    for (int kt = 0; kt < 8; ++kt)
      asm volatile("" : "+v"(wfu[mt][kt]));
  pf = pn1; pn1 = pn2;
  pn2 = *(const float4*)(P + ((size_t)bb * SEQ + 3) * CDIM + ccol);
  __syncthreads();                         // everyone done reading g_lds[0]

  // ---- write g_0 (overwrites staging) + partials into buffer 0
  {
    ushort4 u; u.x = f2bf(gr[0]); u.y = f2bf(gr[1]); u.z = f2bf(gr[2]); u.w = f2bf(gr[3]);
    *(ushort4*)&g_lds[0][bb * 288 + ccol] = u;
    float lsm = gr[0] + gr[1] + gr[2] + gr[3];
    float lsq = gr[0]*gr[0] + gr[1]*gr[1] + gr[2]*gr[2] + gr[3]*gr[3];
    lsm += __shfl_xor(lsm, 4);  lsq += __shfl_xor(lsq, 4);
    lsm += __shfl_xor(lsm, 8);  lsq += __shfl_xor(lsq, 8);
    if (ss == 0) {
      part_lds[0][bb][wave * 4 + lhi][0] = lsm;
      part_lds[0][bb][wave * 4 + lhi][1] = lsq;
    }
  }
  __syncthreads();

  // ---- main loop: one raw barrier per step
  for (int t = 0; t < SEQ; ++t) {
    const int cur = t & 1, nxt = cur ^ 1;
    // issue P[t+4] (3 iterations ahead of use)
    int tp = (t + 4 < SEQ) ? t + 4 : SEQ - 1;
    float4 pl = *(const float4*)(P + ((size_t)bb * SEQ + tp) * CDIM + ccol);

    // B-frags of g_t (replicated by batch) + stats partials
    uint32x4 bfr[8];
#pragma unroll
    for (int kt = 0; kt < 8; ++kt)
      bfr[kt] = *(const uint32x4*)(&g_lds[cur][bb * 288 + kt * 32 + lhi * 8]);
    const float4* pp = (const float4*)&part_lds[cur][bb][0][0];
    float4 q0 = pp[0], q1 = pp[1], q2 = pp[2], q3 = pp[3];
    float4 q4 = pp[4], q5 = pp[5], q6 = pp[6], q7 = pp[7];

    f32x4 acc[4] = {};
#pragma unroll
    for (int mt = 0; mt < 4; ++mt)
#pragma unroll
      for (int kt = 0; kt < 8; ++kt)
        acc[mt] = mfma16(__builtin_bit_cast(bf16x8, wfu[mt][kt]),
                         __builtin_bit_cast(bf16x8, bfr[kt]), acc[mt]);

    float sm = q0.x+q0.z + q1.x+q1.z + q2.x+q2.z + q3.x+q3.z
             + q4.x+q4.z + q5.x+q5.z + q6.x+q6.z + q7.x+q7.z;
    float sq = q0.y+q0.w + q1.y+q1.w + q2.y+q2.w + q3.y+q3.w
             + q4.y+q4.w + q5.y+q5.w + q6.y+q6.w + q7.y+q7.w;
    float mu  = sm * (1.f / CDIM);
    float inv = rsqrtf(sq * (1.f / CDIM) - mu * mu + 1e-5f);
    float invmu = inv * mu;

    // y_t = LN(g_t) from regs -> global (fire-and-forget)
    float4 y;
    y.x = wv.x * (inv * gr[0] - invmu) + bvv.x;
    y.y = wv.y * (inv * gr[1] - invmu) + bvv.y;
    y.z = wv.z * (inv * gr[2] - invmu) + bvv.z;
    y.w = wv.w * (inv * gr[3] - invmu) + bvv.w;
    *(float4*)(x + ((size_t)bb * SEQ + t) * CDIM + ccol) = y;

    // g_{t+1} = gelu(inv*raw - invmu*s1 + c1 + P[t+1])
    f32x4 av = (ss == 0) ? acc[0] : (ss == 1) ? acc[1] : (ss == 2) ? acc[2] : acc[3];
    gr[0] = gelu_f(inv * av[0] - invmu * s1v[0] + c1v[0] + pf.x);
    gr[1] = gelu_f(inv * av[1] - invmu * s1v[1] + c1v[1] + pf.y);
    gr[2] = gelu_f(inv * av[2] - invmu * s1v[2] + c1v[2] + pf.z);
    gr[3] = gelu_f(inv * av[3] - invmu * s1v[3] + c1v[3] + pf.w);
    {
      ushort4 u; u.x = f2bf(gr[0]); u.y = f2bf(gr[1]); u.z = f2bf(gr[2]); u.w = f2bf(gr[3]);
      *(ushort4*)&g_lds[nxt][bb * 288 + ccol] = u;
    }
    float lsm = gr[0] + gr[1] + gr[2] + gr[3];
    float lsq = gr[0]*gr[0] + gr[1]*gr[1] + gr[2]*gr[2] + gr[3]*gr[3];
    lsm += __shfl_xor(lsm, 4);  lsq += __shfl_xor(lsq, 4);
    lsm += __shfl_xor(lsm, 8);  lsq += __shfl_xor(lsq, 8);
    if (ss == 0) {
      part_lds[nxt][bb][wave * 4 + lhi][0] = lsm;
      part_lds[nxt][bb][wave * 4 + lhi][1] = lsq;
    }
    pf = pn1; pn1 = pn2; pn2 = pl;
    asm volatile("s_waitcnt lgkmcnt(0)" ::: "memory");
    __builtin_amdgcn_s_barrier();
    __builtin_amdgcn_sched_barrier(0);
  }
}

// ---------------------------------------------------------------- qkv rearrange + RoPE (ROT=8)
__global__ __launch_bounds__(256) void rope_k(const ushort* __restrict__ qkv,
                                              ushort* __restrict__ Qo,
                                              ushort* __restrict__ Ko,
                                              ushort* __restrict__ Vt) {
  int m = blockIdx.x;                      // b*S + s
  int b = m >> 10, s = m & 1023;
  int t = threadIdx.x;
  int h = t >> 5, d = t & 31;
  const ushort* row = qkv + (size_t)m * 768;
  float q = bf2f(row[h * 32 + d]);
  float k = bf2f(row[256 + h * 32 + d]);
  float v = bf2f(row[512 + h * 32 + d]);
  if (d < 8) {
    int prt = (d < 4) ? d + 4 : d - 4;
    float sgn = (d < 4) ? -1.f : 1.f;
    float qp = sgn * bf2f(row[h * 32 + prt]);
    float kp = sgn * bf2f(row[256 + h * 32 + prt]);
    int j = d & 3;
    const float invs[4] = {1.f, 0.1f, 0.01f, 0.001f};   // 10000^(-j/4) = 10^-j
    float ang = (float)s * invs[j];
    float c, sn;
    __sincosf(ang, &sn, &c);
    q = q * c + qp * sn;
    k = k * c + kp * sn;
  }
  size_t bh = (size_t)(b * NHEAD + h);
  Qo[(bh * SEQ + s) * HDIM + d] = f2bf(q);
  Ko[(bh * SEQ + s) * HDIM + d] = f2bf(k);
  Vt[bh * HDIM * SEQ + (size_t)d * SEQ + s] = f2bf(v);   // V transposed: [bh][d][s]
}

// ---------------------------------------------------------------- causal flash attention, D=32, MFMA
__global__ __launch_bounds__(256) void attn_k(const ushort* __restrict__ Q,
                                              const ushort* __restrict__ K,
                                              const ushort* __restrict__ VT,
                                              ushort* __restrict__ O) {
  __shared__ __attribute__((aligned(16))) ushort Plds[4 * 16 * 32];  // per-wave 16x32 P tile
  const int tid = threadIdx.x, lane = tid & 63, wave = tid >> 6;
  const int bh = blockIdx.y;
  const int qtile = blockIdx.x * 4 + wave;
  const int q0 = qtile * 16;
  const int l15 = lane & 15, lhi = lane >> 4;
  const float scale = 0.17677669529663689f;   // 1/sqrt(32)

  bf16x8 qa = __builtin_bit_cast(bf16x8,
      *(const uint4*)(Q + ((size_t)bh * SEQ + q0 + l15) * HDIM + lhi * 8));
  const ushort* Kb = K + (size_t)bh * SEQ * HDIM;
  const ushort* Vb = VT + (size_t)bh * HDIM * SEQ;
  ushort* Pw = &Plds[wave * 512];

  f32x4 o0 = {}, o1 = {};
  float mrow[4] = {-1e30f, -1e30f, -1e30f, -1e30f};
  float lrow[4] = {};

  for (int kt = 0; kt <= qtile; kt += 2) {
    const bool t2 = (kt + 1 <= qtile);
    f32x4 z = {};
    bf16x8 kf0 = __builtin_bit_cast(bf16x8, *(const uint4*)(Kb + (size_t)(kt * 16 + l15) * HDIM + lhi * 8));
    f32x4 s0 = mfma16(qa, kf0, z);
    f32x4 s1 = {};
    if (t2) {
      bf16x8 kf1 = __builtin_bit_cast(bf16x8, *(const uint4*)(Kb + (size_t)((kt + 1) * 16 + l15) * HDIM + lhi * 8));
      s1 = mfma16(qa, kf1, z);
    }
    float p0[4], p1[4], mx[4];
#pragma unroll
    for (int r = 0; r < 4; ++r) {
      int qr = q0 + lhi * 4 + r;
      int kc0 = kt * 16 + l15;
      p0[r] = (kc0 <= qr) ? s0[r] * scale : -1e30f;
      p1[r] = (t2 && kc0 + 16 <= qr) ? s1[r] * scale : -1e30f;
      mx[r] = fmaxf(p0[r], p1[r]);
    }
#pragma unroll
    for (int msk = 1; msk <= 8; msk <<= 1)
#pragma unroll
      for (int r = 0; r < 4; ++r) mx[r] = fmaxf(mx[r], __shfl_xor(mx[r], msk));
    float rs[4];
#pragma unroll
    for (int r = 0; r < 4; ++r) {
      float mn = fmaxf(mrow[r], mx[r]);
      float alpha = __expf(mrow[r] - mn);
      mrow[r] = mn;
      p0[r] = __expf(p0[r] - mn);
      p1[r] = __expf(p1[r] - mn);
      rs[r] = p0[r] + p1[r];
      lrow[r] = lrow[r] * alpha;
      o0[r] *= alpha; o1[r] *= alpha;
    }
#pragma unroll
    for (int msk = 1; msk <= 8; msk <<= 1)
#pragma unroll
      for (int r = 0; r < 4; ++r) rs[r] += __shfl_xor(rs[r], msk);
#pragma unroll
    for (int r = 0; r < 4; ++r) lrow[r] += rs[r];
#pragma unroll
    for (int r = 0; r < 4; ++r) {
      Pw[(lhi * 4 + r) * 32 + l15]      = f2bf(p0[r]);
      Pw[(lhi * 4 + r) * 32 + 16 + l15] = f2bf(p1[r]);
    }
    bf16x8 pa  = __builtin_bit_cast(bf16x8, *(const uint4*)(&Pw[l15 * 32 + lhi * 8]));
    bf16x8 v0f = __builtin_bit_cast(bf16x8, *(const uint4*)(Vb + (size_t)l15 * SEQ + kt * 16 + lhi * 8));
    bf16x8 v1f = __builtin_bit_cast(bf16x8, *(const uint4*)(Vb + (size_t)(16 + l15) * SEQ + kt * 16 + lhi * 8));
    o0 = mfma16(pa, v0f, o0);
    o1 = mfma16(pa, v1f, o1);
  }
  const int b = bh >> 3, h = bh & 7;
#pragma unroll
  for (int r = 0; r < 4; ++r) {
    float inv = 1.f / lrow[r];
    int qr = q0 + lhi * 4 + r;
    size_t base = ((size_t)(b * SEQ + qr)) * CDIM + h * HDIM;
    O[base + l15]      = f2bf(o0[r] * inv);
    O[base + 16 + l15] = f2bf(o1[r] * inv);
  }
}

// ---------------------------------------------------------------- launcher
static size_t ws_take(size_t& o, size_t bytes) {
  size_t r = o;
  o += (bytes + 255) & ~(size_t)255;
  return r;
}

extern "C" void kernel_launch(void* const* d_in, const int* in_sizes, int n_in,
                              void* d_out, int out_size, void* d_ws, size_t ws_size,
                              hipStream_t stream) {
  (void)in_sizes; (void)n_in; (void)out_size; (void)ws_size;
  const int*   input_ids = (const int*)  d_in[0];
  const float* prev_ctx  = (const float*)d_in[1];
  const float* embed_w   = (const float*)d_in[2];
  const float* en_w      = (const float*)d_in[3];
  const float* en_b      = (const float*)d_in[4];
  const float* ctx_w     = (const float*)d_in[5];
  const float* ctx_b     = (const float*)d_in[6];
  const float* cn_w      = (const float*)d_in[7];
  const float* cn_b      = (const float*)d_in[8];
  const float* ln1_w     = (const float*)d_in[9];
  const float* ln1_b     = (const float*)d_in[10];
  const float* ln2_w     = (const float*)d_in[11];
  const float* ln2_b     = (const float*)d_in[12];
  const float* qkv_w     = (const float*)d_in[13];
  const float* qkv_b     = (const float*)d_in[14];
  const float* ao_w      = (const float*)d_in[15];
  const float* ao_b      = (const float*)d_in[16];
  const float* fc1_w     = (const float*)d_in[17];
  const float* fc1_b     = (const float*)d_in[18];
  const float* fc2_w     = (const float*)d_in[19];
  const float* fc2_b     = (const float*)d_in[20];
  const float* fln_w     = (const float*)d_in[21];
  const float* fln_b     = (const float*)d_in[22];
  const float* out_w     = (const float*)d_in[23];
  float* logits = (float*)d_out;

  char* ws = (char*)d_ws;
  size_t o = 0;
  ushort* WB_OUT = (ushort*)(ws + ws_take(o, (size_t)NVOC * CDIM * 2));
  ushort* TOK    = (ushort*)(ws + ws_take(o, (size_t)NROWS * EDIM * 2));
  float*  PBUF   = (float*) (ws + ws_take(o, (size_t)NROWS * CDIM * 4));
  float*  XBUF   = (float*) (ws + ws_take(o, (size_t)NROWS * CDIM * 4));
  ushort* AIN    = (ushort*)(ws + ws_take(o, (size_t)NROWS * CDIM * 2));
  ushort* MIN    = (ushort*)(ws + ws_take(o, (size_t)NROWS * CDIM * 2));
  ushort* QKVB   = (ushort*)(ws + ws_take(o, (size_t)NROWS * 768 * 2));
  ushort* QB     = (ushort*)(ws + ws_take(o, (size_t)NROWS * CDIM * 2));
  ushort* KB     = (ushort*)(ws + ws_take(o, (size_t)NROWS * CDIM * 2));
  ushort* VTB    = (ushort*)(ws + ws_take(o, (size_t)NROWS * CDIM * 2));
  ushort* OB     = (ushort*)(ws + ws_take(o, (size_t)NROWS * CDIM * 2));
  ushort* TBUF   = (ushort*)(ws + ws_take(o, (size_t)NROWS * IDIM * 2));
  ushort* XLN    = (ushort*)(ws + ws_take(o, (size_t)NROWS * CDIM * 2));

  cvt_k<<<dim3(2048), dim3(256), 0, stream>>>(out_w, WB_OUT, NVOC * CDIM / 4);
  embed_ln_k<<<dim3(NROWS), dim3(64), 0, stream>>>(input_ids, embed_w, en_w, en_b, TOK);
  gemm_k<GF_BIAS | GF_WF32><<<dim3(32, 2), dim3(256), 0, stream>>>(
      TOK, EDIM, (const void*)(ctx_w + 256), 768, ctx_b, (void*)PBUF, CDIM, EDIM);
  scan_k<<<dim3(1), dim3(256), 0, stream>>>(ctx_w, prev_ctx, PBUF, cn_w, cn_b, XBUF);

  for (int l = 0; l < NLAY; ++l) {
    ln_k<true><<<dim3(NROWS / 4), dim3(256), 0, stream>>>(
        XBUF, ln1_w + l * CDIM, ln1_b + l * CDIM, ln2_w + l * CDIM, ln2_b + l * CDIM, AIN, MIN);
    gemm_k<GF_BIAS | GF_BF16O | GF_WF32><<<dim3(32, 6), dim3(256), 0, stream>>>(
        AIN, CDIM, (const void*)(qkv_w + (size_t)l * 768 * CDIM), CDIM,
        qkv_b + l * 768, (void*)QKVB, 768, CDIM);
    rope_k<<<dim3(NROWS), dim3(256), 0, stream>>>(QKVB, QB, KB, VTB);
    attn_k<<<dim3(16, 32), dim3(256), 0, stream>>>(QB, KB, VTB, OB);
    gemm_k<GF_BIAS | GF_ACC | GF_WF32><<<dim3(32, 2), dim3(256), 0, stream>>>(
        OB, CDIM, (const void*)(ao_w + (size_t)l * CDIM * CDIM), CDIM,
        ao_b + l * CDIM, (void*)XBUF, CDIM, CDIM);
    gemm_k<GF_BIAS | GF_GELU | GF_BF16O | GF_WF32><<<dim3(32, 8), dim3(256), 0, stream>>>(
        MIN, CDIM, (const void*)(fc1_w + (size_t)l * IDIM * CDIM), CDIM,
        fc1_b + l * IDIM, (void*)TBUF, IDIM, CDIM);
    gemm_k<GF_BIAS | GF_ACC | GF_WF32><<<dim3(32, 2), dim3(256), 0, stream>>>(
        TBUF, IDIM, (const void*)(fc2_w + (size_t)l * CDIM * IDIM), IDIM,
        fc2_b + l * CDIM, (void*)XBUF, CDIM, IDIM);
  }

  ln_k<false><<<dim3(NROWS / 4), dim3(256), 0, stream>>>(
      XBUF, fln_w, fln_b, nullptr, nullptr, XLN, nullptr);
  gemm_k<0><<<dim3(32, 393), dim3(256), 0, stream>>>(
      XLN, CDIM, (const void*)WB_OUT, CDIM, nullptr, (void*)logits, NVOC, CDIM);
}

// Round 6
// 2186.347 us; speedup vs baseline: 1.5386x; 1.0191x over previous
//
#include <hip/hip_runtime.h>

// ---------------------------------------------------------------- types/helpers
typedef __bf16 bf16x8 __attribute__((ext_vector_type(8)));
typedef float  f32x4  __attribute__((ext_vector_type(4)));
typedef unsigned uint32x4 __attribute__((ext_vector_type(4)));

#define DEV __device__ __forceinline__

DEV ushort f2bf(float f) {                       // fp32 -> bf16 RNE
  unsigned u = __builtin_bit_cast(unsigned, f);
  u += 0x7FFFu + ((u >> 16) & 1u);
  return (ushort)(u >> 16);
}
DEV float bf2f(ushort u) { return __builtin_bit_cast(float, ((unsigned)u) << 16); }
DEV unsigned pk2(ushort a, ushort b) { return (unsigned)a | ((unsigned)b << 16); }

DEV f32x4 mfma16(bf16x8 a, bf16x8 b, f32x4 c) {
  return __builtin_amdgcn_mfma_f32_16x16x32_bf16(a, b, c, 0, 0, 0);
}

// jax.nn.gelu approximate=True: 0.5x(1+tanh(u)) == x*sigmoid(2u), one v_exp + rcp
DEV float gelu_f(float x) {
  float u = 0.7978845608028654f * (x + 0.044715f * x * x * x);
  return x / (1.f + __expf(-2.f * u));
}

#define SEQ  1024
#define NBAT 4
#define CDIM 256
#define EDIM 512
#define NLAY 6
#define NHEAD 8
#define HDIM 32
#define IDIM 1024
#define NVOC 50304
#define NROWS (NBAT * SEQ)   // 4096

// ---------------------------------------------------------------- fp32 -> bf16 convert
__global__ __launch_bounds__(256) void cvt_k(const float* __restrict__ src,
                                             ushort* __restrict__ dst, int n4) {
  int i = blockIdx.x * blockDim.x + threadIdx.x;
  int stride = gridDim.x * blockDim.x;
  for (; i < n4; i += stride) {
    float4 f = ((const float4*)src)[i];
    ushort4 u; u.x = f2bf(f.x); u.y = f2bf(f.y); u.z = f2bf(f.z); u.w = f2bf(f.w);
    ((ushort4*)dst)[i] = u;
  }
}

// ---------------------------------------------------------------- embed gather + LN (E=512)
__global__ __launch_bounds__(64) void embed_ln_k(const int* __restrict__ ids,
                                                 const float* __restrict__ ew,
                                                 const float* __restrict__ w,
                                                 const float* __restrict__ b,
                                                 ushort* __restrict__ tok) {
  int m = blockIdx.x, t = threadIdx.x;
  const float* row = ew + (size_t)ids[m] * EDIM;
  float4 v0 = *(const float4*)(row + t * 8);
  float4 v1 = *(const float4*)(row + t * 8 + 4);
  float sm = v0.x + v0.y + v0.z + v0.w + v1.x + v1.y + v1.z + v1.w;
  float sq = v0.x*v0.x + v0.y*v0.y + v0.z*v0.z + v0.w*v0.w
           + v1.x*v1.x + v1.y*v1.y + v1.z*v1.z + v1.w*v1.w;
#pragma unroll
  for (int msk = 1; msk <= 32; msk <<= 1) { sm += __shfl_xor(sm, msk); sq += __shfl_xor(sq, msk); }
  float mean = sm * (1.f / EDIM);
  float var  = sq * (1.f / EDIM) - mean * mean;
  float inv  = rsqrtf(var + 1e-5f);
  float4 w0 = *(const float4*)(w + t * 8), w1 = *(const float4*)(w + t * 8 + 4);
  float4 b0 = *(const float4*)(b + t * 8), b1 = *(const float4*)(b + t * 8 + 4);
  ushort4 u0, u1;
  u0.x = f2bf((v0.x - mean) * inv * w0.x + b0.x);
  u0.y = f2bf((v0.y - mean) * inv * w0.y + b0.y);
  u0.z = f2bf((v0.z - mean) * inv * w0.z + b0.z);
  u0.w = f2bf((v0.w - mean) * inv * w0.w + b0.w);
  u1.x = f2bf((v1.x - mean) * inv * w1.x + b1.x);
  u1.y = f2bf((v1.y - mean) * inv * w1.y + b1.y);
  u1.z = f2bf((v1.z - mean) * inv * w1.z + b1.z);
  u1.w = f2bf((v1.w - mean) * inv * w1.w + b1.w);
  *(ushort4*)(tok + (size_t)m * EDIM + t * 8)     = u0;
  *(ushort4*)(tok + (size_t)m * EDIM + t * 8 + 4) = u1;
}

// ---------------------------------------------------------------- LayerNorm (C=256) -> bf16, wave-per-row
template <bool DUAL>
__global__ __launch_bounds__(256) void ln_k(const float* __restrict__ x,
                                            const float* __restrict__ w1, const float* __restrict__ b1,
                                            const float* __restrict__ w2, const float* __restrict__ b2,
                                            ushort* __restrict__ o1, ushort* __restrict__ o2) {
  int wave = threadIdx.x >> 6, t = threadIdx.x & 63;
  int m = blockIdx.x * 4 + wave;
  const float* row = x + (size_t)m * CDIM;
  float4 v = *(const float4*)(row + t * 4);
  float sm = v.x + v.y + v.z + v.w;
  float sq = v.x*v.x + v.y*v.y + v.z*v.z + v.w*v.w;
#pragma unroll
  for (int msk = 1; msk <= 32; msk <<= 1) { sm += __shfl_xor(sm, msk); sq += __shfl_xor(sq, msk); }
  float mean = sm * (1.f / CDIM);
  float var  = sq * (1.f / CDIM) - mean * mean;
  float inv  = rsqrtf(var + 1e-5f);
  float n0 = (v.x - mean) * inv, n1 = (v.y - mean) * inv, n2 = (v.z - mean) * inv, n3 = (v.w - mean) * inv;
  {
    float4 wv = *(const float4*)(w1 + t * 4), bv = *(const float4*)(b1 + t * 4);
    ushort4 u; u.x = f2bf(n0*wv.x+bv.x); u.y = f2bf(n1*wv.y+bv.y); u.z = f2bf(n2*wv.z+bv.z); u.w = f2bf(n3*wv.w+bv.w);
    *(ushort4*)(o1 + (size_t)m * CDIM + t * 4) = u;
  }
  if constexpr (DUAL) {
    float4 wv = *(const float4*)(w2 + t * 4), bv = *(const float4*)(b2 + t * 4);
    ushort4 u; u.x = f2bf(n0*wv.x+bv.x); u.y = f2bf(n1*wv.y+bv.y); u.z = f2bf(n2*wv.z+bv.z); u.w = f2bf(n3*wv.w+bv.w);
    *(ushort4*)(o2 + (size_t)m * CDIM + t * 4) = u;
  }
}

// ---------------------------------------------------------------- generic 128x128 MFMA GEMM
enum { GF_BIAS = 1, GF_GELU = 2, GF_ACC = 4, GF_BF16O = 8, GF_WF32 = 16 };

template <int FLAGS>
__global__ __launch_bounds__(256) void gemm_k(const ushort* __restrict__ A, int lda,
                                              const void* __restrict__ Wv, int ldw,
                                              const float* __restrict__ bias,
                                              void* __restrict__ C, int ldc, int K) {
  __shared__ __attribute__((aligned(16))) ushort lsA[128 * 32];
  __shared__ __attribute__((aligned(16))) ushort lsB[128 * 32];
  const int tid = threadIdx.x, lane = tid & 63, wave = tid >> 6;
  const int wm = wave >> 1, wn = wave & 1;
  const int row0 = blockIdx.x * 128, col0 = blockIdx.y * 128;
  const int l15 = lane & 15, koff = (lane >> 4) * 8;

  f32x4 acc[4][4] = {};
  for (int k0 = 0; k0 < K; k0 += 32) {
    __syncthreads();
#pragma unroll
    for (int p = 0; p < 2; ++p) {
      int c = tid + p * 256;          // 512 chunks of 8 bf16
      int r = c >> 2, k8 = (c & 3) * 8;
      *(uint4*)(&lsA[c * 8]) = *(const uint4*)(A + (size_t)(row0 + r) * lda + k0 + k8);
      if constexpr (FLAGS & GF_WF32) {
        const float* gw = (const float*)Wv + (size_t)(col0 + r) * ldw + k0 + k8;
        float4 f0 = *(const float4*)gw, f1 = *(const float4*)(gw + 4);
        uint4 vw;
        vw.x = pk2(f2bf(f0.x), f2bf(f0.y)); vw.y = pk2(f2bf(f0.z), f2bf(f0.w));
        vw.z = pk2(f2bf(f1.x), f2bf(f1.y)); vw.w = pk2(f2bf(f1.z), f2bf(f1.w));
        *(uint4*)(&lsB[c * 8]) = vw;
      } else {
        *(uint4*)(&lsB[c * 8]) = *(const uint4*)((const ushort*)Wv + (size_t)(col0 + r) * ldw + k0 + k8);
      }
    }
    __syncthreads();
    bf16x8 af[4], bfr[4];
#pragma unroll
    for (int mt = 0; mt < 4; ++mt)
      af[mt] = __builtin_bit_cast(bf16x8, *(const uint4*)(&lsA[(wm * 64 + mt * 16 + l15) * 32 + koff]));
#pragma unroll
    for (int nt = 0; nt < 4; ++nt)
      bfr[nt] = __builtin_bit_cast(bf16x8, *(const uint4*)(&lsB[(wn * 64 + nt * 16 + l15) * 32 + koff]));
#pragma unroll
    for (int mt = 0; mt < 4; ++mt)
#pragma unroll
      for (int nt = 0; nt < 4; ++nt)
        acc[mt][nt] = mfma16(af[mt], bfr[nt], acc[mt][nt]);
  }
#pragma unroll
  for (int mt = 0; mt < 4; ++mt) {
#pragma unroll
    for (int nt = 0; nt < 4; ++nt) {
      int col = col0 + wn * 64 + nt * 16 + l15;
      float bv = (FLAGS & GF_BIAS) ? bias[col] : 0.f;
      int rowb = row0 + wm * 64 + mt * 16 + (lane >> 4) * 4;
#pragma unroll
      for (int r = 0; r < 4; ++r) {
        float v = acc[mt][nt][r] + bv;
        if constexpr (FLAGS & GF_GELU) v = gelu_f(v);
        size_t off = (size_t)(rowb + r) * ldc + col;
        if constexpr (FLAGS & GF_ACC)        ((float*)C)[off] += v;
        else if constexpr (FLAGS & GF_BF16O) ((ushort*)C)[off] = f2bf(v);
        else                                 ((float*)C)[off] = v;
      }
    }
  }
}

// ---------------------------------------------------------------- sequential context scan (1 block)
// One barrier per step; h = W'·g via MFMA with replicated B-slots (slot l15
// holds batch l15&3; lane consumes acc tile ss=l15>>2). LN folded into W'.
// Stats: full intra-wave shfl_xor{4,8,16,32} at the producer -> 4 wave-partials
// per batch in LDS; consumer combines 4 values + rsqrt, hidden under the MFMA.
__global__ __launch_bounds__(256, 1) void scan_k(const float* __restrict__ ctx_w,
                                                 const float* __restrict__ prev_ctx,
                                                 const float* __restrict__ P,
                                                 const float* __restrict__ cn_w,
                                                 const float* __restrict__ cn_b,
                                                 float* __restrict__ x) {
  __shared__ __attribute__((aligned(16))) ushort g_lds[2][4 * 288];   // [buf][batch][col] stride 288
  __shared__ __attribute__((aligned(16))) float  part_lds[2][4][4][2]; // [buf][batch][wave]{s,q}
  const int tid = threadIdx.x, lane = tid & 63, wave = tid >> 6;
  const int l15 = lane & 15, lhi = lane >> 4;
  const int bb = l15 & 3;                 // batch this lane epilogues
  const int ss = l15 >> 2;                // acc tile this lane consumes
  const int ccol = wave * 64 + ss * 16 + lhi * 4;   // 4 output cols this lane owns

  // ---- per-lane epilogue constants for own 4 cols
  float4 wv  = *(const float4*)(cn_w + ccol);
  float4 bvv = *(const float4*)(cn_b + ccol);
  float s1v[4] = {}, c1v[4] = {};
#pragma unroll 1
  for (int kk = 0; kk < CDIM; kk += 4) {
    float4 wk = *(const float4*)(cn_w + kk);
    float4 bk = *(const float4*)(cn_b + kk);
#pragma unroll
    for (int j = 0; j < 4; ++j) {
      float4 Wr = *(const float4*)(ctx_w + (size_t)(ccol + j) * 768 + kk);
      s1v[j] += Wr.x * wk.x + Wr.y * wk.y + Wr.z * wk.z + Wr.w * wk.w;
      c1v[j] += Wr.x * bk.x + Wr.y * bk.y + Wr.z * bk.z + Wr.w * bk.w;
    }
  }

  // ---- stage bf16(prev_ctx) into g_lds[0]
  {
    float4 c4 = *(const float4*)(prev_ctx + bb * CDIM + ccol);
    ushort4 u; u.x = f2bf(c4.x); u.y = f2bf(c4.y); u.z = f2bf(c4.z); u.w = f2bf(c4.w);
    *(ushort4*)&g_lds[0][bb * 288 + ccol] = u;
  }

  // ---- plain-W fragments for step 0
  uint32x4 wfu[4][8];
#pragma unroll
  for (int mt = 0; mt < 4; ++mt)
#pragma unroll
    for (int kt = 0; kt < 8; ++kt) {
      const float* s = ctx_w + (size_t)(wave * 64 + mt * 16 + l15) * 768 + kt * 32 + lhi * 8;
      float4 f0 = *(const float4*)s, f1 = *(const float4*)(s + 4);
      uint32x4 vw;
      vw.x = pk2(f2bf(f0.x), f2bf(f0.y)); vw.y = pk2(f2bf(f0.z), f2bf(f0.w));
      vw.z = pk2(f2bf(f1.x), f2bf(f1.y)); vw.w = pk2(f2bf(f1.z), f2bf(f1.w));
      wfu[mt][kt] = vw;
    }
  float4 pf  = *(const float4*)(P + ((size_t)bb * SEQ + 0) * CDIM + ccol);
  float4 pn1 = *(const float4*)(P + ((size_t)bb * SEQ + 1) * CDIM + ccol);
  float4 pn2 = *(const float4*)(P + ((size_t)bb * SEQ + 2) * CDIM + ccol);
  __syncthreads();

  // ---- step 0: raw0 = W @ bf16(prev_ctx); g_0 = gelu(raw0 + P[0])
  float gr[4];
  {
    uint32x4 bfr[8];
#pragma unroll
    for (int kt = 0; kt < 8; ++kt)
      bfr[kt] = *(const uint32x4*)(&g_lds[0][bb * 288 + kt * 32 + lhi * 8]);
    f32x4 acc[4] = {};
#pragma unroll
    for (int mt = 0; mt < 4; ++mt)
#pragma unroll
      for (int kt = 0; kt < 8; ++kt)
        acc[mt] = mfma16(__builtin_bit_cast(bf16x8, wfu[mt][kt]),
                         __builtin_bit_cast(bf16x8, bfr[kt]), acc[mt]);
    f32x4 av = (ss == 0) ? acc[0] : (ss == 1) ? acc[1] : (ss == 2) ? acc[2] : acc[3];
    gr[0] = gelu_f(av[0] + pf.x); gr[1] = gelu_f(av[1] + pf.y);
    gr[2] = gelu_f(av[2] + pf.z); gr[3] = gelu_f(av[3] + pf.w);
  }

  // ---- swap fragments to W' = W_c * diag(cn_w)
#pragma unroll
  for (int mt = 0; mt < 4; ++mt)
#pragma unroll
    for (int kt = 0; kt < 8; ++kt) {
      int k = kt * 32 + lhi * 8;
      const float* s = ctx_w + (size_t)(wave * 64 + mt * 16 + l15) * 768 + k;
      float4 f0 = *(const float4*)s, f1 = *(const float4*)(s + 4);
      float4 w0 = *(const float4*)(cn_w + k), w1 = *(const float4*)(cn_w + k + 4);
      uint32x4 vw;
      vw.x = pk2(f2bf(f0.x * w0.x), f2bf(f0.y * w0.y));
      vw.y = pk2(f2bf(f0.z * w0.z), f2bf(f0.w * w0.w));
      vw.z = pk2(f2bf(f1.x * w1.x), f2bf(f1.y * w1.y));
      vw.w = pk2(f2bf(f1.z * w1.z), f2bf(f1.w * w1.w));
      wfu[mt][kt] = vw;
    }
#pragma unroll
  for (int mt = 0; mt < 4; ++mt)
#pragma unroll
    for (int kt = 0; kt < 8; ++kt)
      asm volatile("" : "+v"(wfu[mt][kt]));
  pf = pn1; pn1 = pn2;
  pn2 = *(const float4*)(P + ((size_t)bb * SEQ + 3) * CDIM + ccol);
  __syncthreads();                         // everyone done reading g_lds[0] staging

  // ---- write g_0 (overwrites staging) + wave partials into buffer 0
  {
    ushort4 u; u.x = f2bf(gr[0]); u.y = f2bf(gr[1]); u.z = f2bf(gr[2]); u.w = f2bf(gr[3]);
    *(ushort4*)&g_lds[0][bb * 288 + ccol] = u;
    float lsm = gr[0] + gr[1] + gr[2] + gr[3];
    float lsq = gr[0]*gr[0] + gr[1]*gr[1] + gr[2]*gr[2] + gr[3]*gr[3];
    lsm += __shfl_xor(lsm, 4);  lsq += __shfl_xor(lsq, 4);
    lsm += __shfl_xor(lsm, 8);  lsq += __shfl_xor(lsq, 8);
    lsm += __shfl_xor(lsm, 16); lsq += __shfl_xor(lsq, 16);
    lsm += __shfl_xor(lsm, 32); lsq += __shfl_xor(lsq, 32);
    if (ss == 0 && lhi == 0) {
      part_lds[0][bb][wave][0] = lsm;
      part_lds[0][bb][wave][1] = lsq;
    }
  }
  __syncthreads();

  // ---- main loop: one raw barrier per step
  for (int t = 0; t < SEQ; ++t) {
    const int cur = t & 1, nxt = cur ^ 1;
    // issue P[t+4] (3 iterations ahead of use)
    int tp = (t + 4 < SEQ) ? t + 4 : SEQ - 1;
    float4 pl = *(const float4*)(P + ((size_t)bb * SEQ + tp) * CDIM + ccol);

    // B-frags of g_t (replicated by batch) + 4 wave-partials for this batch
    uint32x4 bfr[8];
#pragma unroll
    for (int kt = 0; kt < 8; ++kt)
      bfr[kt] = *(const uint32x4*)(&g_lds[cur][bb * 288 + kt * 32 + lhi * 8]);
    float4 pa = ((const float4*)&part_lds[cur][bb][0][0])[0];
    float4 pb = ((const float4*)&part_lds[cur][bb][0][0])[1];

    // MFMA: two independent 4-deep chains per tile (latency), combine after
    f32x4 accA[4] = {}, accB[4] = {};
#pragma unroll
    for (int mt = 0; mt < 4; ++mt) {
      accA[mt] = mfma16(__builtin_bit_cast(bf16x8, wfu[mt][0]), __builtin_bit_cast(bf16x8, bfr[0]), accA[mt]);
      accB[mt] = mfma16(__builtin_bit_cast(bf16x8, wfu[mt][4]), __builtin_bit_cast(bf16x8, bfr[4]), accB[mt]);
      accA[mt] = mfma16(__builtin_bit_cast(bf16x8, wfu[mt][1]), __builtin_bit_cast(bf16x8, bfr[1]), accA[mt]);
      accB[mt] = mfma16(__builtin_bit_cast(bf16x8, wfu[mt][5]), __builtin_bit_cast(bf16x8, bfr[5]), accB[mt]);
      accA[mt] = mfma16(__builtin_bit_cast(bf16x8, wfu[mt][2]), __builtin_bit_cast(bf16x8, bfr[2]), accA[mt]);
      accB[mt] = mfma16(__builtin_bit_cast(bf16x8, wfu[mt][6]), __builtin_bit_cast(bf16x8, bfr[6]), accB[mt]);
      accA[mt] = mfma16(__builtin_bit_cast(bf16x8, wfu[mt][3]), __builtin_bit_cast(bf16x8, bfr[3]), accA[mt]);
      accB[mt] = mfma16(__builtin_bit_cast(bf16x8, wfu[mt][7]), __builtin_bit_cast(bf16x8, bfr[7]), accB[mt]);
    }

    // stats(g_t): 3 adds + rsqrt, hidden under the MFMA block
    float sm = (pa.x + pa.z) + (pb.x + pb.z);
    float sq = (pa.y + pa.w) + (pb.y + pb.w);
    float mu  = sm * (1.f / CDIM);
    float inv = rsqrtf(sq * (1.f / CDIM) - mu * mu + 1e-5f);
    float invmu = inv * mu;

    // y_t = LN(g_t) from regs -> global (fire-and-forget)
    float4 y;
    y.x = wv.x * (inv * gr[0] - invmu) + bvv.x;
    y.y = wv.y * (inv * gr[1] - invmu) + bvv.y;
    y.z = wv.z * (inv * gr[2] - invmu) + bvv.z;
    y.w = wv.w * (inv * gr[3] - invmu) + bvv.w;
    *(float4*)(x + ((size_t)bb * SEQ + t) * CDIM + ccol) = y;

    // g_{t+1} = gelu(inv*raw - invmu*s1 + c1 + P[t+1])
    f32x4 avA = (ss == 0) ? accA[0] : (ss == 1) ? accA[1] : (ss == 2) ? accA[2] : accA[3];
    f32x4 avB = (ss == 0) ? accB[0] : (ss == 1) ? accB[1] : (ss == 2) ? accB[2] : accB[3];
    f32x4 av = avA + avB;
    gr[0] = gelu_f(inv * av[0] - invmu * s1v[0] + c1v[0] + pf.x);
    gr[1] = gelu_f(inv * av[1] - invmu * s1v[1] + c1v[1] + pf.y);
    gr[2] = gelu_f(inv * av[2] - invmu * s1v[2] + c1v[2] + pf.z);
    gr[3] = gelu_f(inv * av[3] - invmu * s1v[3] + c1v[3] + pf.w);
    {
      ushort4 u; u.x = f2bf(gr[0]); u.y = f2bf(gr[1]); u.z = f2bf(gr[2]); u.w = f2bf(gr[3]);
      *(ushort4*)&g_lds[nxt][bb * 288 + ccol] = u;
    }
    // full intra-wave stats for this batch (masks 4..32 preserve bb)
    float lsm = gr[0] + gr[1] + gr[2] + gr[3];
    float lsq = gr[0]*gr[0] + gr[1]*gr[1] + gr[2]*gr[2] + gr[3]*gr[3];
    lsm += __shfl_xor(lsm, 4);  lsq += __shfl_xor(lsq, 4);
    lsm += __shfl_xor(lsm, 8);  lsq += __shfl_xor(lsq, 8);
    lsm += __shfl_xor(lsm, 16); lsq += __shfl_xor(lsq, 16);
    lsm += __shfl_xor(lsm, 32); lsq += __shfl_xor(lsq, 32);
    if (ss == 0 && lhi == 0) {
      part_lds[nxt][bb][wave][0] = lsm;
      part_lds[nxt][bb][wave][1] = lsq;
    }
    pf = pn1; pn1 = pn2; pn2 = pl;
    asm volatile("s_waitcnt lgkmcnt(0)" ::: "memory");
    __builtin_amdgcn_s_barrier();
    __builtin_amdgcn_sched_barrier(0);
  }
}

// ---------------------------------------------------------------- qkv rearrange + RoPE (ROT=8)
__global__ __launch_bounds__(256) void rope_k(const ushort* __restrict__ qkv,
                                              ushort* __restrict__ Qo,
                                              ushort* __restrict__ Ko,
                                              ushort* __restrict__ Vt) {
  int m = blockIdx.x;                      // b*S + s
  int b = m >> 10, s = m & 1023;
  int t = threadIdx.x;
  int h = t >> 5, d = t & 31;
  const ushort* row = qkv + (size_t)m * 768;
  float q = bf2f(row[h * 32 + d]);
  float k = bf2f(row[256 + h * 32 + d]);
  float v = bf2f(row[512 + h * 32 + d]);
  if (d < 8) {
    int prt = (d < 4) ? d + 4 : d - 4;
    float sgn = (d < 4) ? -1.f : 1.f;
    float qp = sgn * bf2f(row[h * 32 + prt]);
    float kp = sgn * bf2f(row[256 + h * 32 + prt]);
    int j = d & 3;
    const float invs[4] = {1.f, 0.1f, 0.01f, 0.001f};   // 10000^(-j/4) = 10^-j
    float ang = (float)s * invs[j];
    float c, sn;
    __sincosf(ang, &sn, &c);
    q = q * c + qp * sn;
    k = k * c + kp * sn;
  }
  size_t bh = (size_t)(b * NHEAD + h);
  Qo[(bh * SEQ + s) * HDIM + d] = f2bf(q);
  Ko[(bh * SEQ + s) * HDIM + d] = f2bf(k);
  Vt[bh * HDIM * SEQ + (size_t)d * SEQ + s] = f2bf(v);   // V transposed: [bh][d][s]
}

// ---------------------------------------------------------------- causal flash attention, D=32, MFMA
__global__ __launch_bounds__(256) void attn_k(const ushort* __restrict__ Q,
                                              const ushort* __restrict__ K,
                                              const ushort* __restrict__ VT,
                                              ushort* __restrict__ O) {
  __shared__ __attribute__((aligned(16))) ushort Plds[4 * 16 * 32];  // per-wave 16x32 P tile
  const int tid = threadIdx.x, lane = tid & 63, wave = tid >> 6;
  const int bh = blockIdx.y;
  const int qtile = blockIdx.x * 4 + wave;
  const int q0 = qtile * 16;
  const int l15 = lane & 15, lhi = lane >> 4;
  const float scale = 0.17677669529663689f;   // 1/sqrt(32)

  bf16x8 qa = __builtin_bit_cast(bf16x8,
      *(const uint4*)(Q + ((size_t)bh * SEQ + q0 + l15) * HDIM + lhi * 8));
  const ushort* Kb = K + (size_t)bh * SEQ * HDIM;
  const ushort* Vb = VT + (size_t)bh * HDIM * SEQ;
  ushort* Pw = &Plds[wave * 512];

  f32x4 o0 = {}, o1 = {};
  float mrow[4] = {-1e30f, -1e30f, -1e30f, -1e30f};
  float lrow[4] = {};

  for (int kt = 0; kt <= qtile; kt += 2) {
    const bool t2 = (kt + 1 <= qtile);
    f32x4 z = {};
    bf16x8 kf0 = __builtin_bit_cast(bf16x8, *(const uint4*)(Kb + (size_t)(kt * 16 + l15) * HDIM + lhi * 8));
    f32x4 s0 = mfma16(qa, kf0, z);
    f32x4 s1 = {};
    if (t2) {
      bf16x8 kf1 = __builtin_bit_cast(bf16x8, *(const uint4*)(Kb + (size_t)((kt + 1) * 16 + l15) * HDIM + lhi * 8));
      s1 = mfma16(qa, kf1, z);
    }
    float p0[4], p1[4], mx[4];
#pragma unroll
    for (int r = 0; r < 4; ++r) {
      int qr = q0 + lhi * 4 + r;
      int kc0 = kt * 16 + l15;
      p0[r] = (kc0 <= qr) ? s0[r] * scale : -1e30f;
      p1[r] = (t2 && kc0 + 16 <= qr) ? s1[r] * scale : -1e30f;
      mx[r] = fmaxf(p0[r], p1[r]);
    }
#pragma unroll
    for (int msk = 1; msk <= 8; msk <<= 1)
#pragma unroll
      for (int r = 0; r < 4; ++r) mx[r] = fmaxf(mx[r], __shfl_xor(mx[r], msk));
    float rs[4];
#pragma unroll
    for (int r = 0; r < 4; ++r) {
      float mn = fmaxf(mrow[r], mx[r]);
      float alpha = __expf(mrow[r] - mn);
      mrow[r] = mn;
      p0[r] = __expf(p0[r] - mn);
      p1[r] = __expf(p1[r] - mn);
      rs[r] = p0[r] + p1[r];
      lrow[r] = lrow[r] * alpha;
      o0[r] *= alpha; o1[r] *= alpha;
    }
#pragma unroll
    for (int msk = 1; msk <= 8; msk <<= 1)
#pragma unroll
      for (int r = 0; r < 4; ++r) rs[r] += __shfl_xor(rs[r], msk);
#pragma unroll
    for (int r = 0; r < 4; ++r) lrow[r] += rs[r];
#pragma unroll
    for (int r = 0; r < 4; ++r) {
      Pw[(lhi * 4 + r) * 32 + l15]      = f2bf(p0[r]);
      Pw[(lhi * 4 + r) * 32 + 16 + l15] = f2bf(p1[r]);
    }
    bf16x8 pa  = __builtin_bit_cast(bf16x8, *(const uint4*)(&Pw[l15 * 32 + lhi * 8]));
    bf16x8 v0f = __builtin_bit_cast(bf16x8, *(const uint4*)(Vb + (size_t)l15 * SEQ + kt * 16 + lhi * 8));
    bf16x8 v1f = __builtin_bit_cast(bf16x8, *(const uint4*)(Vb + (size_t)(16 + l15) * SEQ + kt * 16 + lhi * 8));
    o0 = mfma16(pa, v0f, o0);
    o1 = mfma16(pa, v1f, o1);
  }
  const int b = bh >> 3, h = bh & 7;
#pragma unroll
  for (int r = 0; r < 4; ++r) {
    float inv = 1.f / lrow[r];
    int qr = q0 + lhi * 4 + r;
    size_t base = ((size_t)(b * SEQ + qr)) * CDIM + h * HDIM;
    O[base + l15]      = f2bf(o0[r] * inv);
    O[base + 16 + l15] = f2bf(o1[r] * inv);
  }
}

// ---------------------------------------------------------------- launcher
static size_t ws_take(size_t& o, size_t bytes) {
  size_t r = o;
  o += (bytes + 255) & ~(size_t)255;
  return r;
}

extern "C" void kernel_launch(void* const* d_in, const int* in_sizes, int n_in,
                              void* d_out, int out_size, void* d_ws, size_t ws_size,
                              hipStream_t stream) {
  (void)in_sizes; (void)n_in; (void)out_size; (void)ws_size;
  const int*   input_ids = (const int*)  d_in[0];
  const float* prev_ctx  = (const float*)d_in[1];
  const float* embed_w   = (const float*)d_in[2];
  const float* en_w      = (const float*)d_in[3];
  const float* en_b      = (const float*)d_in[4];
  const float* ctx_w     = (const float*)d_in[5];
  const float* ctx_b     = (const float*)d_in[6];
  const float* cn_w      = (const float*)d_in[7];
  const float* cn_b      = (const float*)d_in[8];
  const float* ln1_w     = (const float*)d_in[9];
  const float* ln1_b     = (const float*)d_in[10];
  const float* ln2_w     = (const float*)d_in[11];
  const float* ln2_b     = (const float*)d_in[12];
  const float* qkv_w     = (const float*)d_in[13];
  const float* qkv_b     = (const float*)d_in[14];
  const float* ao_w      = (const float*)d_in[15];
  const float* ao_b      = (const float*)d_in[16];
  const float* fc1_w     = (const float*)d_in[17];
  const float* fc1_b     = (const float*)d_in[18];
  const float* fc2_w     = (const float*)d_in[19];
  const float* fc2_b     = (const float*)d_in[20];
  const float* fln_w     = (const float*)d_in[21];
  const float* fln_b     = (const float*)d_in[22];
  const float* out_w     = (const float*)d_in[23];
  float* logits = (float*)d_out;

  char* ws = (char*)d_ws;
  size_t o = 0;
  ushort* WB_OUT = (ushort*)(ws + ws_take(o, (size_t)NVOC * CDIM * 2));
  ushort* TOK    = (ushort*)(ws + ws_take(o, (size_t)NROWS * EDIM * 2));
  float*  PBUF   = (float*) (ws + ws_take(o, (size_t)NROWS * CDIM * 4));
  float*  XBUF   = (float*) (ws + ws_take(o, (size_t)NROWS * CDIM * 4));
  ushort* AIN    = (ushort*)(ws + ws_take(o, (size_t)NROWS * CDIM * 2));
  ushort* MIN    = (ushort*)(ws + ws_take(o, (size_t)NROWS * CDIM * 2));
  ushort* QKVB   = (ushort*)(ws + ws_take(o, (size_t)NROWS * 768 * 2));
  ushort* QB     = (ushort*)(ws + ws_take(o, (size_t)NROWS * CDIM * 2));
  ushort* KB     = (ushort*)(ws + ws_take(o, (size_t)NROWS * CDIM * 2));
  ushort* VTB    = (ushort*)(ws + ws_take(o, (size_t)NROWS * CDIM * 2));
  ushort* OB     = (ushort*)(ws + ws_take(o, (size_t)NROWS * CDIM * 2));
  ushort* TBUF   = (ushort*)(ws + ws_take(o, (size_t)NROWS * IDIM * 2));
  ushort* XLN    = (ushort*)(ws + ws_take(o, (size_t)NROWS * CDIM * 2));

  cvt_k<<<dim3(2048), dim3(256), 0, stream>>>(out_w, WB_OUT, NVOC * CDIM / 4);
  embed_ln_k<<<dim3(NROWS), dim3(64), 0, stream>>>(input_ids, embed_w, en_w, en_b, TOK);
  gemm_k<GF_BIAS | GF_WF32><<<dim3(32, 2), dim3(256), 0, stream>>>(
      TOK, EDIM, (const void*)(ctx_w + 256), 768, ctx_b, (void*)PBUF, CDIM, EDIM);
  scan_k<<<dim3(1), dim3(256), 0, stream>>>(ctx_w, prev_ctx, PBUF, cn_w, cn_b, XBUF);

  for (int l = 0; l < NLAY; ++l) {
    ln_k<true><<<dim3(NROWS / 4), dim3(256), 0, stream>>>(
        XBUF, ln1_w + l * CDIM, ln1_b + l * CDIM, ln2_w + l * CDIM, ln2_b + l * CDIM, AIN, MIN);
    gemm_k<GF_BIAS | GF_BF16O | GF_WF32><<<dim3(32, 6), dim3(256), 0, stream>>>(
        AIN, CDIM, (const void*)(qkv_w + (size_t)l * 768 * CDIM), CDIM,
        qkv_b + l * 768, (void*)QKVB, 768, CDIM);
    rope_k<<<dim3(NROWS), dim3(256), 0, stream>>>(QKVB, QB, KB, VTB);
    attn_k<<<dim3(16, 32), dim3(256), 0, stream>>>(QB, KB, VTB, OB);
    gemm_k<GF_BIAS | GF_ACC | GF_WF32><<<dim3(32, 2), dim3(256), 0, stream>>>(
        OB, CDIM, (const void*)(ao_w + (size_t)l * CDIM * CDIM), CDIM,
        ao_b + l * CDIM, (void*)XBUF, CDIM, CDIM);
    gemm_k<GF_BIAS | GF_GELU | GF_BF16O | GF_WF32><<<dim3(32, 8), dim3(256), 0, stream>>>(
        MIN, CDIM, (const void*)(fc1_w + (size_t)l * IDIM * CDIM), CDIM,
        fc1_b + l * IDIM, (void*)TBUF, IDIM, CDIM);
    gemm_k<GF_BIAS | GF_ACC | GF_WF32><<<dim3(32, 2), dim3(256), 0, stream>>>(
        TBUF, IDIM, (const void*)(fc2_w + (size_t)l * CDIM * IDIM), IDIM,
        fc2_b + l * CDIM, (void*)XBUF, CDIM, IDIM);
  }

  ln_k<false><<<dim3(NROWS / 4), dim3(256), 0, stream>>>(
      XBUF, fln_w, fln_b, nullptr, nullptr, XLN, nullptr);
  gemm_k<0><<<dim3(32, 393), dim3(256), 0, stream>>>(
      XLN, CDIM, (const void*)WB_OUT, CDIM, nullptr, (void*)logits, NVOC, CDIM);
}

// Round 7
// 2019.737 us; speedup vs baseline: 1.6656x; 1.0825x over previous
//
#include <hip/hip_runtime.h>

// ---------------------------------------------------------------- types/helpers
typedef __bf16 bf16x8 __attribute__((ext_vector_type(8)));
typedef float  f32x4  __attribute__((ext_vector_type(4)));
typedef unsigned uint32x4 __attribute__((ext_vector_type(4)));

#define DEV __device__ __forceinline__

DEV ushort f2bf(float f) {                       // fp32 -> bf16 RNE
  unsigned u = __builtin_bit_cast(unsigned, f);
  u += 0x7FFFu + ((u >> 16) & 1u);
  return (ushort)(u >> 16);
}
DEV float bf2f(ushort u) { return __builtin_bit_cast(float, ((unsigned)u) << 16); }
DEV unsigned pk2(ushort a, ushort b) { return (unsigned)a | ((unsigned)b << 16); }

DEV f32x4 mfma16(bf16x8 a, bf16x8 b, f32x4 c) {
  return __builtin_amdgcn_mfma_f32_16x16x32_bf16(a, b, c, 0, 0, 0);
}

// jax.nn.gelu approximate=True: 0.5x(1+tanh(u)) == x*sigmoid(2u), one v_exp + rcp
DEV float gelu_f(float x) {
  float u = 0.7978845608028654f * (x + 0.044715f * x * x * x);
  return x / (1.f + __expf(-2.f * u));
}

#define SEQ  1024
#define NBAT 4
#define CDIM 256
#define EDIM 512
#define NLAY 6
#define NHEAD 8
#define HDIM 32
#define IDIM 1024
#define NVOC 50304
#define NROWS (NBAT * SEQ)   // 4096

// ---------------------------------------------------------------- fp32 -> bf16 convert
__global__ __launch_bounds__(256) void cvt_k(const float* __restrict__ src,
                                             ushort* __restrict__ dst, int n4) {
  int i = blockIdx.x * blockDim.x + threadIdx.x;
  int stride = gridDim.x * blockDim.x;
  for (; i < n4; i += stride) {
    float4 f = ((const float4*)src)[i];
    ushort4 u; u.x = f2bf(f.x); u.y = f2bf(f.y); u.z = f2bf(f.z); u.w = f2bf(f.w);
    ((ushort4*)dst)[i] = u;
  }
}

// ---------------------------------------------------------------- embed gather + LN (E=512)
__global__ __launch_bounds__(64) void embed_ln_k(const int* __restrict__ ids,
                                                 const float* __restrict__ ew,
                                                 const float* __restrict__ w,
                                                 const float* __restrict__ b,
                                                 ushort* __restrict__ tok) {
  int m = blockIdx.x, t = threadIdx.x;
  const float* row = ew + (size_t)ids[m] * EDIM;
  float4 v0 = *(const float4*)(row + t * 8);
  float4 v1 = *(const float4*)(row + t * 8 + 4);
  float sm = v0.x + v0.y + v0.z + v0.w + v1.x + v1.y + v1.z + v1.w;
  float sq = v0.x*v0.x + v0.y*v0.y + v0.z*v0.z + v0.w*v0.w
           + v1.x*v1.x + v1.y*v1.y + v1.z*v1.z + v1.w*v1.w;
#pragma unroll
  for (int msk = 1; msk <= 32; msk <<= 1) { sm += __shfl_xor(sm, msk); sq += __shfl_xor(sq, msk); }
  float mean = sm * (1.f / EDIM);
  float var  = sq * (1.f / EDIM) - mean * mean;
  float inv  = rsqrtf(var + 1e-5f);
  float4 w0 = *(const float4*)(w + t * 8), w1 = *(const float4*)(w + t * 8 + 4);
  float4 b0 = *(const float4*)(b + t * 8), b1 = *(const float4*)(b + t * 8 + 4);
  ushort4 u0, u1;
  u0.x = f2bf((v0.x - mean) * inv * w0.x + b0.x);
  u0.y = f2bf((v0.y - mean) * inv * w0.y + b0.y);
  u0.z = f2bf((v0.z - mean) * inv * w0.z + b0.z);
  u0.w = f2bf((v0.w - mean) * inv * w0.w + b0.w);
  u1.x = f2bf((v1.x - mean) * inv * w1.x + b1.x);
  u1.y = f2bf((v1.y - mean) * inv * w1.y + b1.y);
  u1.z = f2bf((v1.z - mean) * inv * w1.z + b1.z);
  u1.w = f2bf((v1.w - mean) * inv * w1.w + b1.w);
  *(ushort4*)(tok + (size_t)m * EDIM + t * 8)     = u0;
  *(ushort4*)(tok + (size_t)m * EDIM + t * 8 + 4) = u1;
}

// ---------------------------------------------------------------- LayerNorm (C=256) -> bf16, wave-per-row
template <bool DUAL>
__global__ __launch_bounds__(256) void ln_k(const float* __restrict__ x,
                                            const float* __restrict__ w1, const float* __restrict__ b1,
                                            const float* __restrict__ w2, const float* __restrict__ b2,
                                            ushort* __restrict__ o1, ushort* __restrict__ o2) {
  int wave = threadIdx.x >> 6, t = threadIdx.x & 63;
  int m = blockIdx.x * 4 + wave;
  const float* row = x + (size_t)m * CDIM;
  float4 v = *(const float4*)(row + t * 4);
  float sm = v.x + v.y + v.z + v.w;
  float sq = v.x*v.x + v.y*v.y + v.z*v.z + v.w*v.w;
#pragma unroll
  for (int msk = 1; msk <= 32; msk <<= 1) { sm += __shfl_xor(sm, msk); sq += __shfl_xor(sq, msk); }
  float mean = sm * (1.f / CDIM);
  float var  = sq * (1.f / CDIM) - mean * mean;
  float inv  = rsqrtf(var + 1e-5f);
  float n0 = (v.x - mean) * inv, n1 = (v.y - mean) * inv, n2 = (v.z - mean) * inv, n3 = (v.w - mean) * inv;
  {
    float4 wv = *(const float4*)(w1 + t * 4), bv = *(const float4*)(b1 + t * 4);
    ushort4 u; u.x = f2bf(n0*wv.x+bv.x); u.y = f2bf(n1*wv.y+bv.y); u.z = f2bf(n2*wv.z+bv.z); u.w = f2bf(n3*wv.w+bv.w);
    *(ushort4*)(o1 + (size_t)m * CDIM + t * 4) = u;
  }
  if constexpr (DUAL) {
    float4 wv = *(const float4*)(w2 + t * 4), bv = *(const float4*)(b2 + t * 4);
    ushort4 u; u.x = f2bf(n0*wv.x+bv.x); u.y = f2bf(n1*wv.y+bv.y); u.z = f2bf(n2*wv.z+bv.z); u.w = f2bf(n3*wv.w+bv.w);
    *(ushort4*)(o2 + (size_t)m * CDIM + t * 4) = u;
  }
}

// ---------------------------------------------------------------- MFMA GEMM, 128x128 tile (logits)
enum { GF_BIAS = 1, GF_GELU = 2, GF_ACC = 4, GF_BF16O = 8, GF_WF32 = 16 };

template <int FLAGS>
__global__ __launch_bounds__(256) void gemm_k(const ushort* __restrict__ A, int lda,
                                              const void* __restrict__ Wv, int ldw,
                                              const float* __restrict__ bias,
                                              void* __restrict__ C, int ldc, int K) {
  __shared__ __attribute__((aligned(16))) ushort lsA[128 * 32];
  __shared__ __attribute__((aligned(16))) ushort lsB[128 * 32];
  const int tid = threadIdx.x, lane = tid & 63, wave = tid >> 6;
  const int wm = wave >> 1, wn = wave & 1;
  const int row0 = blockIdx.x * 128, col0 = blockIdx.y * 128;
  const int l15 = lane & 15, koff = (lane >> 4) * 8;

  f32x4 acc[4][4] = {};
  for (int k0 = 0; k0 < K; k0 += 32) {
    __syncthreads();
#pragma unroll
    for (int p = 0; p < 2; ++p) {
      int c = tid + p * 256;          // 512 chunks of 8 bf16
      int r = c >> 2, k8 = (c & 3) * 8;
      *(uint4*)(&lsA[c * 8]) = *(const uint4*)(A + (size_t)(row0 + r) * lda + k0 + k8);
      if constexpr (FLAGS & GF_WF32) {
        const float* gw = (const float*)Wv + (size_t)(col0 + r) * ldw + k0 + k8;
        float4 f0 = *(const float4*)gw, f1 = *(const float4*)(gw + 4);
        uint4 vw;
        vw.x = pk2(f2bf(f0.x), f2bf(f0.y)); vw.y = pk2(f2bf(f0.z), f2bf(f0.w));
        vw.z = pk2(f2bf(f1.x), f2bf(f1.y)); vw.w = pk2(f2bf(f1.z), f2bf(f1.w));
        *(uint4*)(&lsB[c * 8]) = vw;
      } else {
        *(uint4*)(&lsB[c * 8]) = *(const uint4*)((const ushort*)Wv + (size_t)(col0 + r) * ldw + k0 + k8);
      }
    }
    __syncthreads();
    bf16x8 af[4], bfr[4];
#pragma unroll
    for (int mt = 0; mt < 4; ++mt)
      af[mt] = __builtin_bit_cast(bf16x8, *(const uint4*)(&lsA[(wm * 64 + mt * 16 + l15) * 32 + koff]));
#pragma unroll
    for (int nt = 0; nt < 4; ++nt)
      bfr[nt] = __builtin_bit_cast(bf16x8, *(const uint4*)(&lsB[(wn * 64 + nt * 16 + l15) * 32 + koff]));
#pragma unroll
    for (int mt = 0; mt < 4; ++mt)
#pragma unroll
      for (int nt = 0; nt < 4; ++nt)
        acc[mt][nt] = mfma16(af[mt], bfr[nt], acc[mt][nt]);
  }
#pragma unroll
  for (int mt = 0; mt < 4; ++mt) {
#pragma unroll
    for (int nt = 0; nt < 4; ++nt) {
      int col = col0 + wn * 64 + nt * 16 + l15;
      float bv = (FLAGS & GF_BIAS) ? bias[col] : 0.f;
      int rowb = row0 + wm * 64 + mt * 16 + (lane >> 4) * 4;
#pragma unroll
      for (int r = 0; r < 4; ++r) {
        float v = acc[mt][nt][r] + bv;
        if constexpr (FLAGS & GF_GELU) v = gelu_f(v);
        size_t off = (size_t)(rowb + r) * ldc + col;
        if constexpr (FLAGS & GF_ACC)        ((float*)C)[off] += v;
        else if constexpr (FLAGS & GF_BF16O) ((ushort*)C)[off] = f2bf(v);
        else                                 ((float*)C)[off] = v;
      }
    }
  }
}

// ---------------------------------------------------------------- MFMA GEMM, 64x64 tile (per-layer: better CU utilization)
template <int FLAGS>
__global__ __launch_bounds__(256) void gemm64_k(const ushort* __restrict__ A, int lda,
                                                const void* __restrict__ Wv, int ldw,
                                                const float* __restrict__ bias,
                                                void* __restrict__ C, int ldc, int K) {
  __shared__ __attribute__((aligned(16))) ushort lsA[64 * 32];
  __shared__ __attribute__((aligned(16))) ushort lsB[64 * 32];
  const int tid = threadIdx.x, lane = tid & 63, wave = tid >> 6;
  const int row0 = blockIdx.x * 64, col0 = blockIdx.y * 64;
  const int l15 = lane & 15, lhi = lane >> 4, koff = lhi * 8;

  f32x4 acc[4] = {};
  for (int k0 = 0; k0 < K; k0 += 32) {
    __syncthreads();
    {
      int r = tid >> 2, k8 = (tid & 3) * 8;
      *(uint4*)(&lsA[tid * 8]) = *(const uint4*)(A + (size_t)(row0 + r) * lda + k0 + k8);
      if constexpr (FLAGS & GF_WF32) {
        const float* gw = (const float*)Wv + (size_t)(col0 + r) * ldw + k0 + k8;
        float4 f0 = *(const float4*)gw, f1 = *(const float4*)(gw + 4);
        uint4 vw;
        vw.x = pk2(f2bf(f0.x), f2bf(f0.y)); vw.y = pk2(f2bf(f0.z), f2bf(f0.w));
        vw.z = pk2(f2bf(f1.x), f2bf(f1.y)); vw.w = pk2(f2bf(f1.z), f2bf(f1.w));
        *(uint4*)(&lsB[tid * 8]) = vw;
      } else {
        *(uint4*)(&lsB[tid * 8]) = *(const uint4*)((const ushort*)Wv + (size_t)(col0 + r) * ldw + k0 + k8);
      }
    }
    __syncthreads();
    bf16x8 af = __builtin_bit_cast(bf16x8, *(const uint4*)(&lsA[(wave * 16 + l15) * 32 + koff]));
#pragma unroll
    for (int nt = 0; nt < 4; ++nt) {
      bf16x8 bfr = __builtin_bit_cast(bf16x8, *(const uint4*)(&lsB[(nt * 16 + l15) * 32 + koff]));
      acc[nt] = mfma16(af, bfr, acc[nt]);
    }
  }
#pragma unroll
  for (int nt = 0; nt < 4; ++nt) {
    int col = col0 + nt * 16 + l15;
    float bv = (FLAGS & GF_BIAS) ? bias[col] : 0.f;
    int rowb = row0 + wave * 16 + lhi * 4;
#pragma unroll
    for (int r = 0; r < 4; ++r) {
      float v = acc[nt][r] + bv;
      if constexpr (FLAGS & GF_GELU) v = gelu_f(v);
      size_t off = (size_t)(rowb + r) * ldc + col;
      if constexpr (FLAGS & GF_ACC)        ((float*)C)[off] += v;
      else if constexpr (FLAGS & GF_BF16O) ((ushort*)C)[off] = f2bf(v);
      else                                 ((float*)C)[off] = v;
    }
  }
}

// ---------------------------------------------------------------- sequential context scan (1 block, 8 waves)
// 512 threads = 8 waves = 2 waves/SIMD (cross-wave latency hiding; 16 MFMA/wave).
// h = W'·g via MFMA with replicated B-slots (slot l15 holds batch l15&3).
// Wave w owns output cols [w*32, w*32+32) (2 M-tiles). Lane epilogues 2 cols:
//   mt = (l15>>2)&1, rp = l15>>3, c0 = w*32 + mt*16 + lhi*4 + rp*2.
// LN folded into W' (as R4-R6). One lgkm-only barrier per step.
__global__ __launch_bounds__(512, 2) void scan_k(const float* __restrict__ ctx_w,
                                                 const float* __restrict__ prev_ctx,
                                                 const float* __restrict__ P,
                                                 const float* __restrict__ cn_w,
                                                 const float* __restrict__ cn_b,
                                                 float* __restrict__ x) {
  __shared__ __attribute__((aligned(16))) ushort g_lds[2][4 * 288];    // [buf][batch][col] stride 288
  __shared__ __attribute__((aligned(16))) float  part_lds[2][4][8][2]; // [buf][batch][wave]{s,q}
  const int tid = threadIdx.x, lane = tid & 63, wave = tid >> 6;
  const int l15 = lane & 15, lhi = lane >> 4;
  const int bb = l15 & 3;                  // batch this lane epilogues
  const int ss = l15 >> 2;                 // 0..3
  const int mt = ss & 1, rp = ss >> 1;     // tile + r-pair select
  const int c0 = wave * 32 + mt * 16 + lhi * 4 + rp * 2;  // first of lane's 2 cols

  // ---- per-lane epilogue constants for own 2 cols
  float2 wv  = *(const float2*)(cn_w + c0);
  float2 bv2 = *(const float2*)(cn_b + c0);
  float s1v0 = 0.f, s1v1 = 0.f, c1v0 = 0.f, c1v1 = 0.f;
#pragma unroll 1
  for (int kk = 0; kk < CDIM; kk += 4) {
    float4 wk = *(const float4*)(cn_w + kk);
    float4 bk = *(const float4*)(cn_b + kk);
    float4 W0 = *(const float4*)(ctx_w + (size_t)c0 * 768 + kk);
    float4 W1 = *(const float4*)(ctx_w + (size_t)(c0 + 1) * 768 + kk);
    s1v0 += W0.x*wk.x + W0.y*wk.y + W0.z*wk.z + W0.w*wk.w;
    c1v0 += W0.x*bk.x + W0.y*bk.y + W0.z*bk.z + W0.w*bk.w;
    s1v1 += W1.x*wk.x + W1.y*wk.y + W1.z*wk.z + W1.w*wk.w;
    c1v1 += W1.x*bk.x + W1.y*bk.y + W1.z*bk.z + W1.w*bk.w;
  }

  // ---- stage bf16(prev_ctx) into g_lds[0]
  {
    float2 c2 = *(const float2*)(prev_ctx + bb * CDIM + c0);
    ushort2 u; u.x = f2bf(c2.x); u.y = f2bf(c2.y);
    *(ushort2*)&g_lds[0][bb * 288 + c0] = u;
  }

  // ---- plain-W fragments for step 0 (A-frag row = output col)
  uint32x4 wfu[2][8];
#pragma unroll
  for (int m2 = 0; m2 < 2; ++m2)
#pragma unroll
    for (int kt = 0; kt < 8; ++kt) {
      const float* s = ctx_w + (size_t)(wave * 32 + m2 * 16 + l15) * 768 + kt * 32 + lhi * 8;
      float4 f0 = *(const float4*)s, f1 = *(const float4*)(s + 4);
      uint32x4 vw;
      vw.x = pk2(f2bf(f0.x), f2bf(f0.y)); vw.y = pk2(f2bf(f0.z), f2bf(f0.w));
      vw.z = pk2(f2bf(f1.x), f2bf(f1.y)); vw.w = pk2(f2bf(f1.z), f2bf(f1.w));
      wfu[m2][kt] = vw;
    }
  float2 pf  = *(const float2*)(P + ((size_t)bb * SEQ + 0) * CDIM + c0);
  float2 pn1 = *(const float2*)(P + ((size_t)bb * SEQ + 1) * CDIM + c0);
  float2 pn2 = *(const float2*)(P + ((size_t)bb * SEQ + 2) * CDIM + c0);
  __syncthreads();

  // ---- step 0: raw0 = W @ bf16(prev_ctx); g_0 = gelu(raw0 + P[0])
  float gr[2];
  {
    uint32x4 bfr[8];
#pragma unroll
    for (int kt = 0; kt < 8; ++kt)
      bfr[kt] = *(const uint32x4*)(&g_lds[0][bb * 288 + kt * 32 + lhi * 8]);
    f32x4 acc[2] = {};
#pragma unroll
    for (int m2 = 0; m2 < 2; ++m2)
#pragma unroll
      for (int kt = 0; kt < 8; ++kt)
        acc[m2] = mfma16(__builtin_bit_cast(bf16x8, wfu[m2][kt]),
                         __builtin_bit_cast(bf16x8, bfr[kt]), acc[m2]);
    f32x4 av = (mt == 0) ? acc[0] : acc[1];
    gr[0] = gelu_f(av[rp * 2]     + pf.x);
    gr[1] = gelu_f(av[rp * 2 + 1] + pf.y);
  }

  // ---- swap fragments to W' = W_c * diag(cn_w)
#pragma unroll
  for (int m2 = 0; m2 < 2; ++m2)
#pragma unroll
    for (int kt = 0; kt < 8; ++kt) {
      int k = kt * 32 + lhi * 8;
      const float* s = ctx_w + (size_t)(wave * 32 + m2 * 16 + l15) * 768 + k;
      float4 f0 = *(const float4*)s, f1 = *(const float4*)(s + 4);
      float4 w0 = *(const float4*)(cn_w + k), w1 = *(const float4*)(cn_w + k + 4);
      uint32x4 vw;
      vw.x = pk2(f2bf(f0.x * w0.x), f2bf(f0.y * w0.y));
      vw.y = pk2(f2bf(f0.z * w0.z), f2bf(f0.w * w0.w));
      vw.z = pk2(f2bf(f1.x * w1.x), f2bf(f1.y * w1.y));
      vw.w = pk2(f2bf(f1.z * w1.z), f2bf(f1.w * w1.w));
      wfu[m2][kt] = vw;
    }
#pragma unroll
  for (int m2 = 0; m2 < 2; ++m2)
#pragma unroll
    for (int kt = 0; kt < 8; ++kt)
      asm volatile("" : "+v"(wfu[m2][kt]));
  pf = pn1; pn1 = pn2;
  pn2 = *(const float2*)(P + ((size_t)bb * SEQ + 3) * CDIM + c0);
  __syncthreads();                          // everyone done reading g_lds[0] staging

  // ---- write g_0 (overwrites staging) + wave partials into buffer 0
  {
    ushort2 u; u.x = f2bf(gr[0]); u.y = f2bf(gr[1]);
    *(ushort2*)&g_lds[0][bb * 288 + c0] = u;
    float lsm = gr[0] + gr[1];
    float lsq = gr[0]*gr[0] + gr[1]*gr[1];
    lsm += __shfl_xor(lsm, 4);  lsq += __shfl_xor(lsq, 4);
    lsm += __shfl_xor(lsm, 8);  lsq += __shfl_xor(lsq, 8);
    lsm += __shfl_xor(lsm, 16); lsq += __shfl_xor(lsq, 16);
    lsm += __shfl_xor(lsm, 32); lsq += __shfl_xor(lsq, 32);
    if (ss == 0 && lhi == 0) {
      float2 pq; pq.x = lsm; pq.y = lsq;
      *(float2*)&part_lds[0][l15][wave][0] = pq;
    }
  }
  __syncthreads();

  // ---- main loop: one raw barrier per step
  for (int t = 0; t < SEQ; ++t) {
    const int cur = t & 1, nxt = cur ^ 1;
    int tp = (t + 4 < SEQ) ? t + 4 : SEQ - 1;
    float2 pl = *(const float2*)(P + ((size_t)bb * SEQ + tp) * CDIM + c0);

    // B-frags of g_t (replicated by batch) + 8 wave-partials for this batch
    uint32x4 bfr[8];
#pragma unroll
    for (int kt = 0; kt < 8; ++kt)
      bfr[kt] = *(const uint32x4*)(&g_lds[cur][bb * 288 + kt * 32 + lhi * 8]);
    const float4* pp = (const float4*)&part_lds[cur][bb][0][0];
    float4 qa = pp[0], qb = pp[1], qc = pp[2], qd = pp[3];

    // MFMA: 4 independent 4-deep chains
    f32x4 accA[2] = {}, accB[2] = {};
#pragma unroll
    for (int m2 = 0; m2 < 2; ++m2) {
      accA[m2] = mfma16(__builtin_bit_cast(bf16x8, wfu[m2][0]), __builtin_bit_cast(bf16x8, bfr[0]), accA[m2]);
      accB[m2] = mfma16(__builtin_bit_cast(bf16x8, wfu[m2][4]), __builtin_bit_cast(bf16x8, bfr[4]), accB[m2]);
      accA[m2] = mfma16(__builtin_bit_cast(bf16x8, wfu[m2][1]), __builtin_bit_cast(bf16x8, bfr[1]), accA[m2]);
      accB[m2] = mfma16(__builtin_bit_cast(bf16x8, wfu[m2][5]), __builtin_bit_cast(bf16x8, bfr[5]), accB[m2]);
      accA[m2] = mfma16(__builtin_bit_cast(bf16x8, wfu[m2][2]), __builtin_bit_cast(bf16x8, bfr[2]), accA[m2]);
      accB[m2] = mfma16(__builtin_bit_cast(bf16x8, wfu[m2][6]), __builtin_bit_cast(bf16x8, bfr[6]), accB[m2]);
      accA[m2] = mfma16(__builtin_bit_cast(bf16x8, wfu[m2][3]), __builtin_bit_cast(bf16x8, bfr[3]), accA[m2]);
      accB[m2] = mfma16(__builtin_bit_cast(bf16x8, wfu[m2][7]), __builtin_bit_cast(bf16x8, bfr[7]), accB[m2]);
    }

    // stats(g_t) combine: hidden under the MFMA block
    float sm = (qa.x + qa.z) + (qb.x + qb.z) + (qc.x + qc.z) + (qd.x + qd.z);
    float sq = (qa.y + qa.w) + (qb.y + qb.w) + (qc.y + qc.w) + (qd.y + qd.w);
    float mu  = sm * (1.f / CDIM);
    float inv = rsqrtf(sq * (1.f / CDIM) - mu * mu + 1e-5f);
    float invmu = inv * mu;

    // y_t = LN(g_t) from regs -> global (fire-and-forget)
    float2 y;
    y.x = wv.x * (inv * gr[0] - invmu) + bv2.x;
    y.y = wv.y * (inv * gr[1] - invmu) + bv2.y;
    *(float2*)(x + ((size_t)bb * SEQ + t) * CDIM + c0) = y;

    // g_{t+1} = gelu(inv*raw - invmu*s1 + c1 + P[t+1])
    f32x4 avA = (mt == 0) ? accA[0] : accA[1];
    f32x4 avB = (mt == 0) ? accB[0] : accB[1];
    float a0 = avA[rp * 2]     + avB[rp * 2];
    float a1 = avA[rp * 2 + 1] + avB[rp * 2 + 1];
    gr[0] = gelu_f(inv * a0 - invmu * s1v0 + c1v0 + pf.x);
    gr[1] = gelu_f(inv * a1 - invmu * s1v1 + c1v1 + pf.y);
    {
      ushort2 u; u.x = f2bf(gr[0]); u.y = f2bf(gr[1]);
      *(ushort2*)&g_lds[nxt][bb * 288 + c0] = u;
    }
    float lsm = gr[0] + gr[1];
    float lsq = gr[0]*gr[0] + gr[1]*gr[1];
    lsm += __shfl_xor(lsm, 4);  lsq += __shfl_xor(lsq, 4);
    lsm += __shfl_xor(lsm, 8);  lsq += __shfl_xor(lsq, 8);
    lsm += __shfl_xor(lsm, 16); lsq += __shfl_xor(lsq, 16);
    lsm += __shfl_xor(lsm, 32); lsq += __shfl_xor(lsq, 32);
    if (ss == 0 && lhi == 0) {
      float2 pq; pq.x = lsm; pq.y = lsq;
      *(float2*)&part_lds[nxt][l15][wave][0] = pq;
    }
    pf = pn1; pn1 = pn2; pn2 = pl;
    asm volatile("s_waitcnt lgkmcnt(0)" ::: "memory");
    __builtin_amdgcn_s_barrier();
    __builtin_amdgcn_sched_barrier(0);
  }
}

// ---------------------------------------------------------------- qkv rearrange + RoPE (ROT=8)
__global__ __launch_bounds__(256) void rope_k(const ushort* __restrict__ qkv,
                                              ushort* __restrict__ Qo,
                                              ushort* __restrict__ Ko,
                                              ushort* __restrict__ Vt) {
  int m = blockIdx.x;                      // b*S + s
  int b = m >> 10, s = m & 1023;
  int t = threadIdx.x;
  int h = t >> 5, d = t & 31;
  const ushort* row = qkv + (size_t)m * 768;
  float q = bf2f(row[h * 32 + d]);
  float k = bf2f(row[256 + h * 32 + d]);
  float v = bf2f(row[512 + h * 32 + d]);
  if (d < 8) {
    int prt = (d < 4) ? d + 4 : d - 4;
    float sgn = (d < 4) ? -1.f : 1.f;
    float qp = sgn * bf2f(row[h * 32 + prt]);
    float kp = sgn * bf2f(row[256 + h * 32 + prt]);
    int j = d & 3;
    const float invs[4] = {1.f, 0.1f, 0.01f, 0.001f};   // 10000^(-j/4) = 10^-j
    float ang = (float)s * invs[j];
    float c, sn;
    __sincosf(ang, &sn, &c);
    q = q * c + qp * sn;
    k = k * c + kp * sn;
  }
  size_t bh = (size_t)(b * NHEAD + h);
  Qo[(bh * SEQ + s) * HDIM + d] = f2bf(q);
  Ko[(bh * SEQ + s) * HDIM + d] = f2bf(k);
  Vt[bh * HDIM * SEQ + (size_t)d * SEQ + s] = f2bf(v);   // V transposed: [bh][d][s]
}

// ---------------------------------------------------------------- causal flash attention, D=32, MFMA
// No online max (|scores| ~ O(1) << 80: exp cannot overflow) and the softmax
// denominator reduce is deferred out of the k-loop (one shfl tree at the end).
__global__ __launch_bounds__(256) void attn_k(const ushort* __restrict__ Q,
                                              const ushort* __restrict__ K,
                                              const ushort* __restrict__ VT,
                                              ushort* __restrict__ O) {
  __shared__ __attribute__((aligned(16))) ushort Plds[4 * 16 * 32];  // per-wave 16x32 P tile
  const int tid = threadIdx.x, lane = tid & 63, wave = tid >> 6;
  const int bh = blockIdx.y;
  const int qtile = blockIdx.x * 4 + wave;
  const int q0 = qtile * 16;
  const int l15 = lane & 15, lhi = lane >> 4;
  const float scale = 0.17677669529663689f;   // 1/sqrt(32)

  bf16x8 qa = __builtin_bit_cast(bf16x8,
      *(const uint4*)(Q + ((size_t)bh * SEQ + q0 + l15) * HDIM + lhi * 8));
  const ushort* Kb = K + (size_t)bh * SEQ * HDIM;
  const ushort* Vb = VT + (size_t)bh * HDIM * SEQ;
  ushort* Pw = &Plds[wave * 512];

  f32x4 o0 = {}, o1 = {};
  float lacc[4] = {};

  for (int kt = 0; kt <= qtile; kt += 2) {
    const bool t2 = (kt + 1 <= qtile);
    f32x4 z = {};
    bf16x8 kf0 = __builtin_bit_cast(bf16x8, *(const uint4*)(Kb + (size_t)(kt * 16 + l15) * HDIM + lhi * 8));
    f32x4 s0 = mfma16(qa, kf0, z);
    f32x4 s1 = {};
    if (t2) {
      bf16x8 kf1 = __builtin_bit_cast(bf16x8, *(const uint4*)(Kb + (size_t)((kt + 1) * 16 + l15) * HDIM + lhi * 8));
      s1 = mfma16(qa, kf1, z);
    }
    float p0[4], p1[4];
#pragma unroll
    for (int r = 0; r < 4; ++r) {
      int qr = q0 + lhi * 4 + r;
      int kc0 = kt * 16 + l15;
      p0[r] = (kc0 <= qr) ? __expf(s0[r] * scale) : 0.f;
      p1[r] = (t2 && kc0 + 16 <= qr) ? __expf(s1[r] * scale) : 0.f;
      lacc[r] += p0[r] + p1[r];
    }
#pragma unroll
    for (int r = 0; r < 4; ++r) {
      Pw[(lhi * 4 + r) * 32 + l15]      = f2bf(p0[r]);
      Pw[(lhi * 4 + r) * 32 + 16 + l15] = f2bf(p1[r]);
    }
    bf16x8 pa  = __builtin_bit_cast(bf16x8, *(const uint4*)(&Pw[l15 * 32 + lhi * 8]));
    bf16x8 v0f = __builtin_bit_cast(bf16x8, *(const uint4*)(Vb + (size_t)l15 * SEQ + kt * 16 + lhi * 8));
    bf16x8 v1f = __builtin_bit_cast(bf16x8, *(const uint4*)(Vb + (size_t)(16 + l15) * SEQ + kt * 16 + lhi * 8));
    o0 = mfma16(pa, v0f, o0);
    o1 = mfma16(pa, v1f, o1);
  }
  // deferred denominator: sum over the 16 k-lanes once
#pragma unroll
  for (int msk = 1; msk <= 8; msk <<= 1)
#pragma unroll
    for (int r = 0; r < 4; ++r) lacc[r] += __shfl_xor(lacc[r], msk);

  const int b = bh >> 3, h = bh & 7;
#pragma unroll
  for (int r = 0; r < 4; ++r) {
    float inv = 1.f / lacc[r];
    int qr = q0 + lhi * 4 + r;
    size_t base = ((size_t)(b * SEQ + qr)) * CDIM + h * HDIM;
    O[base + l15]      = f2bf(o0[r] * inv);
    O[base + 16 + l15] = f2bf(o1[r] * inv);
  }
}

// ---------------------------------------------------------------- launcher
static size_t ws_take(size_t& o, size_t bytes) {
  size_t r = o;
  o += (bytes + 255) & ~(size_t)255;
  return r;
}

extern "C" void kernel_launch(void* const* d_in, const int* in_sizes, int n_in,
                              void* d_out, int out_size, void* d_ws, size_t ws_size,
                              hipStream_t stream) {
  (void)in_sizes; (void)n_in; (void)out_size; (void)ws_size;
  const int*   input_ids = (const int*)  d_in[0];
  const float* prev_ctx  = (const float*)d_in[1];
  const float* embed_w   = (const float*)d_in[2];
  const float* en_w      = (const float*)d_in[3];
  const float* en_b      = (const float*)d_in[4];
  const float* ctx_w     = (const float*)d_in[5];
  const float* ctx_b     = (const float*)d_in[6];
  const float* cn_w      = (const float*)d_in[7];
  const float* cn_b      = (const float*)d_in[8];
  const float* ln1_w     = (const float*)d_in[9];
  const float* ln1_b     = (const float*)d_in[10];
  const float* ln2_w     = (const float*)d_in[11];
  const float* ln2_b     = (const float*)d_in[12];
  const float* qkv_w     = (const float*)d_in[13];
  const float* qkv_b     = (const float*)d_in[14];
  const float* ao_w      = (const float*)d_in[15];
  const float* ao_b      = (const float*)d_in[16];
  const float* fc1_w     = (const float*)d_in[17];
  const float* fc1_b     = (const float*)d_in[18];
  const float* fc2_w     = (const float*)d_in[19];
  const float* fc2_b     = (const float*)d_in[20];
  const float* fln_w     = (const float*)d_in[21];
  const float* fln_b     = (const float*)d_in[22];
  const float* out_w     = (const float*)d_in[23];
  float* logits = (float*)d_out;

  char* ws = (char*)d_ws;
  size_t o = 0;
  ushort* WB_OUT = (ushort*)(ws + ws_take(o, (size_t)NVOC * CDIM * 2));
  ushort* TOK    = (ushort*)(ws + ws_take(o, (size_t)NROWS * EDIM * 2));
  float*  PBUF   = (float*) (ws + ws_take(o, (size_t)NROWS * CDIM * 4));
  float*  XBUF   = (float*) (ws + ws_take(o, (size_t)NROWS * CDIM * 4));
  ushort* AIN    = (ushort*)(ws + ws_take(o, (size_t)NROWS * CDIM * 2));
  ushort* MIN    = (ushort*)(ws + ws_take(o, (size_t)NROWS * CDIM * 2));
  ushort* QKVB   = (ushort*)(ws + ws_take(o, (size_t)NROWS * 768 * 2));
  ushort* QB     = (ushort*)(ws + ws_take(o, (size_t)NROWS * CDIM * 2));
  ushort* KB     = (ushort*)(ws + ws_take(o, (size_t)NROWS * CDIM * 2));
  ushort* VTB    = (ushort*)(ws + ws_take(o, (size_t)NROWS * CDIM * 2));
  ushort* OB     = (ushort*)(ws + ws_take(o, (size_t)NROWS * CDIM * 2));
  ushort* TBUF   = (ushort*)(ws + ws_take(o, (size_t)NROWS * IDIM * 2));
  ushort* XLN    = (ushort*)(ws + ws_take(o, (size_t)NROWS * CDIM * 2));

  cvt_k<<<dim3(2048), dim3(256), 0, stream>>>(out_w, WB_OUT, NVOC * CDIM / 4);
  embed_ln_k<<<dim3(NROWS), dim3(64), 0, stream>>>(input_ids, embed_w, en_w, en_b, TOK);
  gemm64_k<GF_BIAS | GF_WF32><<<dim3(64, 4), dim3(256), 0, stream>>>(
      TOK, EDIM, (const void*)(ctx_w + 256), 768, ctx_b, (void*)PBUF, CDIM, EDIM);
  scan_k<<<dim3(1), dim3(512), 0, stream>>>(ctx_w, prev_ctx, PBUF, cn_w, cn_b, XBUF);

  for (int l = 0; l < NLAY; ++l) {
    ln_k<true><<<dim3(NROWS / 4), dim3(256), 0, stream>>>(
        XBUF, ln1_w + l * CDIM, ln1_b + l * CDIM, ln2_w + l * CDIM, ln2_b + l * CDIM, AIN, MIN);
    gemm64_k<GF_BIAS | GF_BF16O | GF_WF32><<<dim3(64, 12), dim3(256), 0, stream>>>(
        AIN, CDIM, (const void*)(qkv_w + (size_t)l * 768 * CDIM), CDIM,
        qkv_b + l * 768, (void*)QKVB, 768, CDIM);
    rope_k<<<dim3(NROWS), dim3(256), 0, stream>>>(QKVB, QB, KB, VTB);
    attn_k<<<dim3(16, 32), dim3(256), 0, stream>>>(QB, KB, VTB, OB);
    gemm64_k<GF_BIAS | GF_ACC | GF_WF32><<<dim3(64, 4), dim3(256), 0, stream>>>(
        OB, CDIM, (const void*)(ao_w + (size_t)l * CDIM * CDIM), CDIM,
        ao_b + l * CDIM, (void*)XBUF, CDIM, CDIM);
    gemm64_k<GF_BIAS | GF_GELU | GF_BF16O | GF_WF32><<<dim3(64, 16), dim3(256), 0, stream>>>(
        MIN, CDIM, (const void*)(fc1_w + (size_t)l * IDIM * CDIM), CDIM,
        fc1_b + l * IDIM, (void*)TBUF, IDIM, CDIM);
    gemm64_k<GF_BIAS | GF_ACC | GF_WF32><<<dim3(64, 4), dim3(256), 0, stream>>>(
        TBUF, IDIM, (const void*)(fc2_w + (size_t)l * CDIM * IDIM), IDIM,
        fc2_b + l * CDIM, (void*)XBUF, CDIM, IDIM);
  }

  ln_k<false><<<dim3(NROWS / 4), dim3(256), 0, stream>>>(
      XBUF, fln_w, fln_b, nullptr, nullptr, XLN, nullptr);
  gemm_k<0><<<dim3(32, 393), dim3(256), 0, stream>>>(
      XLN, CDIM, (const void*)WB_OUT, CDIM, nullptr, (void*)logits, NVOC, CDIM);
}

// Round 8
// 1805.444 us; speedup vs baseline: 1.8632x; 1.1187x over previous
//
#include <hip/hip_runtime.h>

// ---------------------------------------------------------------- types/helpers
typedef __bf16 bf16x8 __attribute__((ext_vector_type(8)));
typedef float  f32x4  __attribute__((ext_vector_type(4)));
typedef unsigned uint32x4 __attribute__((ext_vector_type(4)));

#define DEV __device__ __forceinline__

DEV ushort f2bf(float f) {                       // fp32 -> bf16 RNE
  unsigned u = __builtin_bit_cast(unsigned, f);
  u += 0x7FFFu + ((u >> 16) & 1u);
  return (ushort)(u >> 16);
}
DEV float bf2f(ushort u) { return __builtin_bit_cast(float, ((unsigned)u) << 16); }
DEV unsigned pk2(ushort a, ushort b) { return (unsigned)a | ((unsigned)b << 16); }

DEV f32x4 mfma16(bf16x8 a, bf16x8 b, f32x4 c) {
  return __builtin_amdgcn_mfma_f32_16x16x32_bf16(a, b, c, 0, 0, 0);
}

// jax.nn.gelu approximate=True: 0.5x(1+tanh(u)) == x*sigmoid(2u), one v_exp + rcp
DEV float gelu_f(float x) {
  float u = 0.7978845608028654f * (x + 0.044715f * x * x * x);
  return x / (1.f + __expf(-2.f * u));
}

#define SEQ  1024
#define NBAT 4
#define CDIM 256
#define EDIM 512
#define NLAY 6
#define NHEAD 8
#define HDIM 32
#define IDIM 1024
#define NVOC 50304
#define NROWS (NBAT * SEQ)   // 4096

// ---------------------------------------------------------------- fp32 -> bf16 convert
__global__ __launch_bounds__(256) void cvt_k(const float* __restrict__ src,
                                             ushort* __restrict__ dst, int n4) {
  int i = blockIdx.x * blockDim.x + threadIdx.x;
  int stride = gridDim.x * blockDim.x;
  for (; i < n4; i += stride) {
    float4 f = ((const float4*)src)[i];
    ushort4 u; u.x = f2bf(f.x); u.y = f2bf(f.y); u.z = f2bf(f.z); u.w = f2bf(f.w);
    ((ushort4*)dst)[i] = u;
  }
}

// ---------------------------------------------------------------- embed gather + LN (E=512)
__global__ __launch_bounds__(64) void embed_ln_k(const int* __restrict__ ids,
                                                 const float* __restrict__ ew,
                                                 const float* __restrict__ w,
                                                 const float* __restrict__ b,
                                                 ushort* __restrict__ tok) {
  int m = blockIdx.x, t = threadIdx.x;
  const float* row = ew + (size_t)ids[m] * EDIM;
  float4 v0 = *(const float4*)(row + t * 8);
  float4 v1 = *(const float4*)(row + t * 8 + 4);
  float sm = v0.x + v0.y + v0.z + v0.w + v1.x + v1.y + v1.z + v1.w;
  float sq = v0.x*v0.x + v0.y*v0.y + v0.z*v0.z + v0.w*v0.w
           + v1.x*v1.x + v1.y*v1.y + v1.z*v1.z + v1.w*v1.w;
#pragma unroll
  for (int msk = 1; msk <= 32; msk <<= 1) { sm += __shfl_xor(sm, msk); sq += __shfl_xor(sq, msk); }
  float mean = sm * (1.f / EDIM);
  float var  = sq * (1.f / EDIM) - mean * mean;
  float inv  = rsqrtf(var + 1e-5f);
  float4 w0 = *(const float4*)(w + t * 8), w1 = *(const float4*)(w + t * 8 + 4);
  float4 b0 = *(const float4*)(b + t * 8), b1 = *(const float4*)(b + t * 8 + 4);
  ushort4 u0, u1;
  u0.x = f2bf((v0.x - mean) * inv * w0.x + b0.x);
  u0.y = f2bf((v0.y - mean) * inv * w0.y + b0.y);
  u0.z = f2bf((v0.z - mean) * inv * w0.z + b0.z);
  u0.w = f2bf((v0.w - mean) * inv * w0.w + b0.w);
  u1.x = f2bf((v1.x - mean) * inv * w1.x + b1.x);
  u1.y = f2bf((v1.y - mean) * inv * w1.y + b1.y);
  u1.z = f2bf((v1.z - mean) * inv * w1.z + b1.z);
  u1.w = f2bf((v1.w - mean) * inv * w1.w + b1.w);
  *(ushort4*)(tok + (size_t)m * EDIM + t * 8)     = u0;
  *(ushort4*)(tok + (size_t)m * EDIM + t * 8 + 4) = u1;
}

// ---------------------------------------------------------------- LayerNorm (C=256) -> bf16, wave-per-row
template <bool DUAL>
__global__ __launch_bounds__(256) void ln_k(const float* __restrict__ x,
                                            const float* __restrict__ w1, const float* __restrict__ b1,
                                            const float* __restrict__ w2, const float* __restrict__ b2,
                                            ushort* __restrict__ o1, ushort* __restrict__ o2) {
  int wave = threadIdx.x >> 6, t = threadIdx.x & 63;
  int m = blockIdx.x * 4 + wave;
  const float* row = x + (size_t)m * CDIM;
  float4 v = *(const float4*)(row + t * 4);
  float sm = v.x + v.y + v.z + v.w;
  float sq = v.x*v.x + v.y*v.y + v.z*v.z + v.w*v.w;
#pragma unroll
  for (int msk = 1; msk <= 32; msk <<= 1) { sm += __shfl_xor(sm, msk); sq += __shfl_xor(sq, msk); }
  float mean = sm * (1.f / CDIM);
  float var  = sq * (1.f / CDIM) - mean * mean;
  float inv  = rsqrtf(var + 1e-5f);
  float n0 = (v.x - mean) * inv, n1 = (v.y - mean) * inv, n2 = (v.z - mean) * inv, n3 = (v.w - mean) * inv;
  {
    float4 wv = *(const float4*)(w1 + t * 4), bv = *(const float4*)(b1 + t * 4);
    ushort4 u; u.x = f2bf(n0*wv.x+bv.x); u.y = f2bf(n1*wv.y+bv.y); u.z = f2bf(n2*wv.z+bv.z); u.w = f2bf(n3*wv.w+bv.w);
    *(ushort4*)(o1 + (size_t)m * CDIM + t * 4) = u;
  }
  if constexpr (DUAL) {
    float4 wv = *(const float4*)(w2 + t * 4), bv = *(const float4*)(b2 + t * 4);
    ushort4 u; u.x = f2bf(n0*wv.x+bv.x); u.y = f2bf(n1*wv.y+bv.y); u.z = f2bf(n2*wv.z+bv.z); u.w = f2bf(n3*wv.w+bv.w);
    *(ushort4*)(o2 + (size_t)m * CDIM + t * 4) = u;
  }
}

// ---------------------------------------------------------------- MFMA GEMM, 128x128 tile (logits)
enum { GF_BIAS = 1, GF_GELU = 2, GF_ACC = 4, GF_BF16O = 8, GF_WF32 = 16 };

template <int FLAGS>
__global__ __launch_bounds__(256) void gemm_k(const ushort* __restrict__ A, int lda,
                                              const void* __restrict__ Wv, int ldw,
                                              const float* __restrict__ bias,
                                              void* __restrict__ C, int ldc, int K) {
  __shared__ __attribute__((aligned(16))) ushort lsA[128 * 32];
  __shared__ __attribute__((aligned(16))) ushort lsB[128 * 32];
  const int tid = threadIdx.x, lane = tid & 63, wave = tid >> 6;
  const int wm = wave >> 1, wn = wave & 1;
  const int row0 = blockIdx.x * 128, col0 = blockIdx.y * 128;
  const int l15 = lane & 15, koff = (lane >> 4) * 8;

  f32x4 acc[4][4] = {};
  for (int k0 = 0; k0 < K; k0 += 32) {
    __syncthreads();
#pragma unroll
    for (int p = 0; p < 2; ++p) {
      int c = tid + p * 256;          // 512 chunks of 8 bf16
      int r = c >> 2, k8 = (c & 3) * 8;
      *(uint4*)(&lsA[c * 8]) = *(const uint4*)(A + (size_t)(row0 + r) * lda + k0 + k8);
      if constexpr (FLAGS & GF_WF32) {
        const float* gw = (const float*)Wv + (size_t)(col0 + r) * ldw + k0 + k8;
        float4 f0 = *(const float4*)gw, f1 = *(const float4*)(gw + 4);
        uint4 vw;
        vw.x = pk2(f2bf(f0.x), f2bf(f0.y)); vw.y = pk2(f2bf(f0.z), f2bf(f0.w));
        vw.z = pk2(f2bf(f1.x), f2bf(f1.y)); vw.w = pk2(f2bf(f1.z), f2bf(f1.w));
        *(uint4*)(&lsB[c * 8]) = vw;
      } else {
        *(uint4*)(&lsB[c * 8]) = *(const uint4*)((const ushort*)Wv + (size_t)(col0 + r) * ldw + k0 + k8);
      }
    }
    __syncthreads();
    bf16x8 af[4], bfr[4];
#pragma unroll
    for (int mt = 0; mt < 4; ++mt)
      af[mt] = __builtin_bit_cast(bf16x8, *(const uint4*)(&lsA[(wm * 64 + mt * 16 + l15) * 32 + koff]));
#pragma unroll
    for (int nt = 0; nt < 4; ++nt)
      bfr[nt] = __builtin_bit_cast(bf16x8, *(const uint4*)(&lsB[(wn * 64 + nt * 16 + l15) * 32 + koff]));
#pragma unroll
    for (int mt = 0; mt < 4; ++mt)
#pragma unroll
      for (int nt = 0; nt < 4; ++nt)
        acc[mt][nt] = mfma16(af[mt], bfr[nt], acc[mt][nt]);
  }
#pragma unroll
  for (int mt = 0; mt < 4; ++mt) {
#pragma unroll
    for (int nt = 0; nt < 4; ++nt) {
      int col = col0 + wn * 64 + nt * 16 + l15;
      float bv = (FLAGS & GF_BIAS) ? bias[col] : 0.f;
      int rowb = row0 + wm * 64 + mt * 16 + (lane >> 4) * 4;
#pragma unroll
      for (int r = 0; r < 4; ++r) {
        float v = acc[mt][nt][r] + bv;
        if constexpr (FLAGS & GF_GELU) v = gelu_f(v);
        size_t off = (size_t)(rowb + r) * ldc + col;
        if constexpr (FLAGS & GF_ACC)        ((float*)C)[off] += v;
        else if constexpr (FLAGS & GF_BF16O) ((ushort*)C)[off] = f2bf(v);
        else                                 ((float*)C)[off] = v;
      }
    }
  }
}

// ---------------------------------------------------------------- MFMA GEMM, 64x64 tile (per-layer)
template <int FLAGS>
__global__ __launch_bounds__(256) void gemm64_k(const ushort* __restrict__ A, int lda,
                                                const void* __restrict__ Wv, int ldw,
                                                const float* __restrict__ bias,
                                                void* __restrict__ C, int ldc, int K) {
  __shared__ __attribute__((aligned(16))) ushort lsA[64 * 32];
  __shared__ __attribute__((aligned(16))) ushort lsB[64 * 32];
  const int tid = threadIdx.x, lane = tid & 63, wave = tid >> 6;
  const int row0 = blockIdx.x * 64, col0 = blockIdx.y * 64;
  const int l15 = lane & 15, lhi = lane >> 4, koff = lhi * 8;

  f32x4 acc[4] = {};
  for (int k0 = 0; k0 < K; k0 += 32) {
    __syncthreads();
    {
      int r = tid >> 2, k8 = (tid & 3) * 8;
      *(uint4*)(&lsA[tid * 8]) = *(const uint4*)(A + (size_t)(row0 + r) * lda + k0 + k8);
      if constexpr (FLAGS & GF_WF32) {
        const float* gw = (const float*)Wv + (size_t)(col0 + r) * ldw + k0 + k8;
        float4 f0 = *(const float4*)gw, f1 = *(const float4*)(gw + 4);
        uint4 vw;
        vw.x = pk2(f2bf(f0.x), f2bf(f0.y)); vw.y = pk2(f2bf(f0.z), f2bf(f0.w));
        vw.z = pk2(f2bf(f1.x), f2bf(f1.y)); vw.w = pk2(f2bf(f1.z), f2bf(f1.w));
        *(uint4*)(&lsB[tid * 8]) = vw;
      } else {
        *(uint4*)(&lsB[tid * 8]) = *(const uint4*)((const ushort*)Wv + (size_t)(col0 + r) * ldw + k0 + k8);
      }
    }
    __syncthreads();
    bf16x8 af = __builtin_bit_cast(bf16x8, *(const uint4*)(&lsA[(wave * 16 + l15) * 32 + koff]));
#pragma unroll
    for (int nt = 0; nt < 4; ++nt) {
      bf16x8 bfr = __builtin_bit_cast(bf16x8, *(const uint4*)(&lsB[(nt * 16 + l15) * 32 + koff]));
      acc[nt] = mfma16(af, bfr, acc[nt]);
    }
  }
#pragma unroll
  for (int nt = 0; nt < 4; ++nt) {
    int col = col0 + nt * 16 + l15;
    float bv = (FLAGS & GF_BIAS) ? bias[col] : 0.f;
    int rowb = row0 + wave * 16 + lhi * 4;
#pragma unroll
    for (int r = 0; r < 4; ++r) {
      float v = acc[nt][r] + bv;
      if constexpr (FLAGS & GF_GELU) v = gelu_f(v);
      size_t off = (size_t)(rowb + r) * ldc + col;
      if constexpr (FLAGS & GF_ACC)        ((float*)C)[off] += v;
      else if constexpr (FLAGS & GF_BF16O) ((ushort*)C)[off] = f2bf(v);
      else                                 ((float*)C)[off] = v;
    }
  }
}

// ---------------------------------------------------------------- fused QKV GEMM + bias + RoPE + scatter
// A = LN(x) bf16 [4096][256]; W = qkv_w layer fp32 [768][256]; out: Q,K [bh][s][32], V^T [bh][32][s].
// RoPE partner of col c is col c^4 (d<8) -> one shfl_xor(4).
__global__ __launch_bounds__(256) void qkvrope_k(const ushort* __restrict__ A,
                                                 const float* __restrict__ W,
                                                 const float* __restrict__ bias,
                                                 ushort* __restrict__ Qo,
                                                 ushort* __restrict__ Ko,
                                                 ushort* __restrict__ Vt) {
  __shared__ __attribute__((aligned(16))) ushort lsA[64 * 32];
  __shared__ __attribute__((aligned(16))) ushort lsB[64 * 32];
  const int tid = threadIdx.x, lane = tid & 63, wave = tid >> 6;
  const int row0 = blockIdx.x * 64, col0 = blockIdx.y * 64;
  const int l15 = lane & 15, lhi = lane >> 4, koff = lhi * 8;

  f32x4 acc[4] = {};
  for (int k0 = 0; k0 < CDIM; k0 += 32) {
    __syncthreads();
    {
      int r = tid >> 2, k8 = (tid & 3) * 8;
      *(uint4*)(&lsA[tid * 8]) = *(const uint4*)(A + (size_t)(row0 + r) * CDIM + k0 + k8);
      const float* gw = W + (size_t)(col0 + r) * CDIM + k0 + k8;
      float4 f0 = *(const float4*)gw, f1 = *(const float4*)(gw + 4);
      uint4 vw;
      vw.x = pk2(f2bf(f0.x), f2bf(f0.y)); vw.y = pk2(f2bf(f0.z), f2bf(f0.w));
      vw.z = pk2(f2bf(f1.x), f2bf(f1.y)); vw.w = pk2(f2bf(f1.z), f2bf(f1.w));
      *(uint4*)(&lsB[tid * 8]) = vw;
    }
    __syncthreads();
    bf16x8 af = __builtin_bit_cast(bf16x8, *(const uint4*)(&lsA[(wave * 16 + l15) * 32 + koff]));
#pragma unroll
    for (int nt = 0; nt < 4; ++nt) {
      bf16x8 bfr = __builtin_bit_cast(bf16x8, *(const uint4*)(&lsB[(nt * 16 + l15) * 32 + koff]));
      acc[nt] = mfma16(af, bfr, acc[nt]);
    }
  }
  const int rowb = row0 + wave * 16 + lhi * 4;
  const int b = rowb >> 10, s0 = rowb & 1023;
#pragma unroll
  for (int nt = 0; nt < 4; ++nt) {
    int c = col0 + nt * 16 + l15;
    int which = c >> 8;                 // 0=q 1=k 2=v  (uniform per nt tile)
    int h = (c >> 5) & 7;
    int d = c & 31;
    size_t bh = (size_t)(b * NHEAD + h);
    float bv = bias[c];
    float val[4], part[4];
#pragma unroll
    for (int r = 0; r < 4; ++r) val[r] = acc[nt][r] + bv;
#pragma unroll
    for (int r = 0; r < 4; ++r) part[r] = __shfl_xor(val[r], 4);   // col c^4 (all lanes)
    if (d < 8 && which < 2) {
      float sgn = (d < 4) ? -1.f : 1.f;
      int j = d & 3;
      float invp = (j == 0) ? 1.f : (j == 1) ? 0.1f : (j == 2) ? 0.01f : 0.001f;
#pragma unroll
      for (int r = 0; r < 4; ++r) {
        float ang = (float)(s0 + r) * invp;
        float cs, sn;
        __sincosf(ang, &sn, &cs);
        val[r] = val[r] * cs + sgn * part[r] * sn;
      }
    }
    if (which == 2) {
      ushort4 u; u.x = f2bf(val[0]); u.y = f2bf(val[1]); u.z = f2bf(val[2]); u.w = f2bf(val[3]);
      *(ushort4*)(Vt + bh * HDIM * SEQ + (size_t)d * SEQ + s0) = u;
    } else {
      ushort* dst = (which == 0) ? Qo : Ko;
#pragma unroll
      for (int r = 0; r < 4; ++r)
        dst[(bh * SEQ + s0 + r) * HDIM + d] = f2bf(val[r]);
    }
  }
}

// ---------------------------------------------------------------- fused ao+fc2 accumulate GEMM (K = 256 + 1024)
// C[M,256] += A1@W1^T + b1 + A2@W2^T + b2
__global__ __launch_bounds__(256) void gemm64_dual_k(const ushort* __restrict__ A1, int lda1,
                                                     const float* __restrict__ W1, int ldw1, int K1,
                                                     const ushort* __restrict__ A2, int lda2,
                                                     const float* __restrict__ W2, int ldw2, int K2,
                                                     const float* __restrict__ b1,
                                                     const float* __restrict__ b2,
                                                     float* __restrict__ C, int ldc) {
  __shared__ __attribute__((aligned(16))) ushort lsA[64 * 32];
  __shared__ __attribute__((aligned(16))) ushort lsB[64 * 32];
  const int tid = threadIdx.x, lane = tid & 63, wave = tid >> 6;
  const int row0 = blockIdx.x * 64, col0 = blockIdx.y * 64;
  const int l15 = lane & 15, lhi = lane >> 4, koff = lhi * 8;

  f32x4 acc[4] = {};
  for (int k0 = 0; k0 < K1 + K2; k0 += 32) {
    __syncthreads();
    {
      int r = tid >> 2, k8 = (tid & 3) * 8;
      const ushort* Ap; const float* Wp; int kk;
      if (k0 < K1) { Ap = A1 + (size_t)(row0 + r) * lda1; Wp = W1 + (size_t)(col0 + r) * ldw1; kk = k0 + k8; }
      else         { Ap = A2 + (size_t)(row0 + r) * lda2; Wp = W2 + (size_t)(col0 + r) * ldw2; kk = k0 - K1 + k8; }
      *(uint4*)(&lsA[tid * 8]) = *(const uint4*)(Ap + kk);
      float4 f0 = *(const float4*)(Wp + kk), f1 = *(const float4*)(Wp + kk + 4);
      uint4 vw;
      vw.x = pk2(f2bf(f0.x), f2bf(f0.y)); vw.y = pk2(f2bf(f0.z), f2bf(f0.w));
      vw.z = pk2(f2bf(f1.x), f2bf(f1.y)); vw.w = pk2(f2bf(f1.z), f2bf(f1.w));
      *(uint4*)(&lsB[tid * 8]) = vw;
    }
    __syncthreads();
    bf16x8 af = __builtin_bit_cast(bf16x8, *(const uint4*)(&lsA[(wave * 16 + l15) * 32 + koff]));
#pragma unroll
    for (int nt = 0; nt < 4; ++nt) {
      bf16x8 bfr = __builtin_bit_cast(bf16x8, *(const uint4*)(&lsB[(nt * 16 + l15) * 32 + koff]));
      acc[nt] = mfma16(af, bfr, acc[nt]);
    }
  }
#pragma unroll
  for (int nt = 0; nt < 4; ++nt) {
    int col = col0 + nt * 16 + l15;
    float bv = b1[col] + b2[col];
    int rowb = row0 + wave * 16 + lhi * 4;
#pragma unroll
    for (int r = 0; r < 4; ++r)
      C[(size_t)(rowb + r) * ldc + col] += acc[nt][r] + bv;
  }
}

// ---------------------------------------------------------------- sequential context scan (1 block, 4 waves)
// R6 structure (best measured) + unroll-4 static P slots (true 3-iter prefetch distance).
__global__ __launch_bounds__(256, 1) void scan_k(const float* __restrict__ ctx_w,
                                                 const float* __restrict__ prev_ctx,
                                                 const float* __restrict__ P,
                                                 const float* __restrict__ cn_w,
                                                 const float* __restrict__ cn_b,
                                                 float* __restrict__ x) {
  __shared__ __attribute__((aligned(16))) ushort g_lds[2][4 * 288];    // [buf][batch][col] stride 288
  __shared__ __attribute__((aligned(16))) float  part_lds[2][4][4][2]; // [buf][batch][wave]{s,q}
  const int tid = threadIdx.x, lane = tid & 63, wave = tid >> 6;
  const int l15 = lane & 15, lhi = lane >> 4;
  const int bb = l15 & 3;                 // batch this lane epilogues
  const int ss = l15 >> 2;                // acc tile this lane consumes
  const int ccol = wave * 64 + ss * 16 + lhi * 4;   // 4 output cols this lane owns

  // ---- per-lane epilogue constants for own 4 cols
  float4 wv  = *(const float4*)(cn_w + ccol);
  float4 bvv = *(const float4*)(cn_b + ccol);
  float s1v[4] = {}, c1v[4] = {};
#pragma unroll 1
  for (int kk = 0; kk < CDIM; kk += 4) {
    float4 wk = *(const float4*)(cn_w + kk);
    float4 bk = *(const float4*)(cn_b + kk);
#pragma unroll
    for (int j = 0; j < 4; ++j) {
      float4 Wr = *(const float4*)(ctx_w + (size_t)(ccol + j) * 768 + kk);
      s1v[j] += Wr.x * wk.x + Wr.y * wk.y + Wr.z * wk.z + Wr.w * wk.w;
      c1v[j] += Wr.x * bk.x + Wr.y * bk.y + Wr.z * bk.z + Wr.w * bk.w;
    }
  }

  // ---- stage bf16(prev_ctx) into g_lds[0]
  {
    float4 c4 = *(const float4*)(prev_ctx + bb * CDIM + ccol);
    ushort4 u; u.x = f2bf(c4.x); u.y = f2bf(c4.y); u.z = f2bf(c4.z); u.w = f2bf(c4.w);
    *(ushort4*)&g_lds[0][bb * 288 + ccol] = u;
  }

  // ---- plain-W fragments for step 0
  uint32x4 wfu[4][8];
#pragma unroll
  for (int mt = 0; mt < 4; ++mt)
#pragma unroll
    for (int kt = 0; kt < 8; ++kt) {
      const float* s = ctx_w + (size_t)(wave * 64 + mt * 16 + l15) * 768 + kt * 32 + lhi * 8;
      float4 f0 = *(const float4*)s, f1 = *(const float4*)(s + 4);
      uint32x4 vw;
      vw.x = pk2(f2bf(f0.x), f2bf(f0.y)); vw.y = pk2(f2bf(f0.z), f2bf(f0.w));
      vw.z = pk2(f2bf(f1.x), f2bf(f1.y)); vw.w = pk2(f2bf(f1.z), f2bf(f1.w));
      wfu[mt][kt] = vw;
    }
  float4 pf = *(const float4*)(P + ((size_t)bb * SEQ + 0) * CDIM + ccol);
  __syncthreads();

  // ---- step 0: raw0 = W @ bf16(prev_ctx); g_0 = gelu(raw0 + P[0])
  float gr[4];
  {
    uint32x4 bfr[8];
#pragma unroll
    for (int kt = 0; kt < 8; ++kt)
      bfr[kt] = *(const uint32x4*)(&g_lds[0][bb * 288 + kt * 32 + lhi * 8]);
    f32x4 acc[4] = {};
#pragma unroll
    for (int mt = 0; mt < 4; ++mt)
#pragma unroll
      for (int kt = 0; kt < 8; ++kt)
        acc[mt] = mfma16(__builtin_bit_cast(bf16x8, wfu[mt][kt]),
                         __builtin_bit_cast(bf16x8, bfr[kt]), acc[mt]);
    f32x4 av = (ss == 0) ? acc[0] : (ss == 1) ? acc[1] : (ss == 2) ? acc[2] : acc[3];
    gr[0] = gelu_f(av[0] + pf.x); gr[1] = gelu_f(av[1] + pf.y);
    gr[2] = gelu_f(av[2] + pf.z); gr[3] = gelu_f(av[3] + pf.w);
  }

  // ---- swap fragments to W' = W_c * diag(cn_w)
#pragma unroll
  for (int mt = 0; mt < 4; ++mt)
#pragma unroll
    for (int kt = 0; kt < 8; ++kt) {
      int k = kt * 32 + lhi * 8;
      const float* s = ctx_w + (size_t)(wave * 64 + mt * 16 + l15) * 768 + k;
      float4 f0 = *(const float4*)s, f1 = *(const float4*)(s + 4);
      float4 w0 = *(const float4*)(cn_w + k), w1 = *(const float4*)(cn_w + k + 4);
      uint32x4 vw;
      vw.x = pk2(f2bf(f0.x * w0.x), f2bf(f0.y * w0.y));
      vw.y = pk2(f2bf(f0.z * w0.z), f2bf(f0.w * w0.w));
      vw.z = pk2(f2bf(f1.x * w1.x), f2bf(f1.y * w1.y));
      vw.w = pk2(f2bf(f1.z * w1.z), f2bf(f1.w * w1.w));
      wfu[mt][kt] = vw;
    }
#pragma unroll
  for (int mt = 0; mt < 4; ++mt)
#pragma unroll
    for (int kt = 0; kt < 8; ++kt)
      asm volatile("" : "+v"(wfu[mt][kt]));

  // ---- P prefetch slots: iter t uses slot (t+1)&3 (=P[t+1]), loads slot t&3 (=P[t+4])
  float4 ps0, ps1, ps2, ps3;
  ps1 = *(const float4*)(P + ((size_t)bb * SEQ + 1) * CDIM + ccol);
  ps2 = *(const float4*)(P + ((size_t)bb * SEQ + 2) * CDIM + ccol);
  ps3 = *(const float4*)(P + ((size_t)bb * SEQ + 3) * CDIM + ccol);
  ps0 = ps3;   // placeholder; overwritten at t=0
  __syncthreads();                         // everyone done reading g_lds[0] staging

  // ---- write g_0 (overwrites staging) + wave partials into buffer 0
  {
    ushort4 u; u.x = f2bf(gr[0]); u.y = f2bf(gr[1]); u.z = f2bf(gr[2]); u.w = f2bf(gr[3]);
    *(ushort4*)&g_lds[0][bb * 288 + ccol] = u;
    float lsm = gr[0] + gr[1] + gr[2] + gr[3];
    float lsq = gr[0]*gr[0] + gr[1]*gr[1] + gr[2]*gr[2] + gr[3]*gr[3];
    lsm += __shfl_xor(lsm, 4);  lsq += __shfl_xor(lsq, 4);
    lsm += __shfl_xor(lsm, 8);  lsq += __shfl_xor(lsq, 8);
    lsm += __shfl_xor(lsm, 16); lsq += __shfl_xor(lsq, 16);
    lsm += __shfl_xor(lsm, 32); lsq += __shfl_xor(lsq, 32);
    if (ss == 0 && lhi == 0) {
      part_lds[0][bb][wave][0] = lsm;
      part_lds[0][bb][wave][1] = lsq;
    }
  }
  __syncthreads();

#define SCAN_STEP(T, CUR, NXT, PUSE, PLOAD)                                          \
  {                                                                                  \
    int tp = ((T) + 4 < SEQ) ? (T) + 4 : SEQ - 1;                                    \
    PLOAD = *(const float4*)(P + ((size_t)bb * SEQ + tp) * CDIM + ccol);             \
    uint32x4 bfr[8];                                                                 \
    _Pragma("unroll")                                                                \
    for (int kt = 0; kt < 8; ++kt)                                                   \
      bfr[kt] = *(const uint32x4*)(&g_lds[CUR][bb * 288 + kt * 32 + lhi * 8]);       \
    const float4* pp = (const float4*)&part_lds[CUR][bb][0][0];                      \
    float4 qpa = pp[0], qpb = pp[1];                                                 \
    f32x4 accA[4] = {}, accB[4] = {};                                                \
    _Pragma("unroll")                                                                \
    for (int mt = 0; mt < 4; ++mt) {                                                 \
      accA[mt] = mfma16(__builtin_bit_cast(bf16x8, wfu[mt][0]), __builtin_bit_cast(bf16x8, bfr[0]), accA[mt]); \
      accB[mt] = mfma16(__builtin_bit_cast(bf16x8, wfu[mt][4]), __builtin_bit_cast(bf16x8, bfr[4]), accB[mt]); \
      accA[mt] = mfma16(__builtin_bit_cast(bf16x8, wfu[mt][1]), __builtin_bit_cast(bf16x8, bfr[1]), accA[mt]); \
      accB[mt] = mfma16(__builtin_bit_cast(bf16x8, wfu[mt][5]), __builtin_bit_cast(bf16x8, bfr[5]), accB[mt]); \
      accA[mt] = mfma16(__builtin_bit_cast(bf16x8, wfu[mt][2]), __builtin_bit_cast(bf16x8, bfr[2]), accA[mt]); \
      accB[mt] = mfma16(__builtin_bit_cast(bf16x8, wfu[mt][6]), __builtin_bit_cast(bf16x8, bfr[6]), accB[mt]); \
      accA[mt] = mfma16(__builtin_bit_cast(bf16x8, wfu[mt][3]), __builtin_bit_cast(bf16x8, bfr[3]), accA[mt]); \
      accB[mt] = mfma16(__builtin_bit_cast(bf16x8, wfu[mt][7]), __builtin_bit_cast(bf16x8, bfr[7]), accB[mt]); \
    }                                                                                \
    float sm = (qpa.x + qpa.z) + (qpb.x + qpb.z);                                    \
    float sq = (qpa.y + qpa.w) + (qpb.y + qpb.w);                                    \
    float mu  = sm * (1.f / CDIM);                                                   \
    float inv = rsqrtf(sq * (1.f / CDIM) - mu * mu + 1e-5f);                         \
    float invmu = inv * mu;                                                          \
    float4 y;                                                                        \
    y.x = wv.x * (inv * gr[0] - invmu) + bvv.x;                                      \
    y.y = wv.y * (inv * gr[1] - invmu) + bvv.y;                                      \
    y.z = wv.z * (inv * gr[2] - invmu) + bvv.z;                                      \
    y.w = wv.w * (inv * gr[3] - invmu) + bvv.w;                                      \
    *(float4*)(x + ((size_t)bb * SEQ + (T)) * CDIM + ccol) = y;                      \
    f32x4 avA = (ss == 0) ? accA[0] : (ss == 1) ? accA[1] : (ss == 2) ? accA[2] : accA[3]; \
    f32x4 avB = (ss == 0) ? accB[0] : (ss == 1) ? accB[1] : (ss == 2) ? accB[2] : accB[3]; \
    f32x4 av = avA + avB;                                                            \
    gr[0] = gelu_f(inv * av[0] - invmu * s1v[0] + c1v[0] + PUSE.x);                  \
    gr[1] = gelu_f(inv * av[1] - invmu * s1v[1] + c1v[1] + PUSE.y);                  \
    gr[2] = gelu_f(inv * av[2] - invmu * s1v[2] + c1v[2] + PUSE.z);                  \
    gr[3] = gelu_f(inv * av[3] - invmu * s1v[3] + c1v[3] + PUSE.w);                  \
    {                                                                                \
      ushort4 u; u.x = f2bf(gr[0]); u.y = f2bf(gr[1]); u.z = f2bf(gr[2]); u.w = f2bf(gr[3]); \
      *(ushort4*)&g_lds[NXT][bb * 288 + ccol] = u;                                   \
    }                                                                                \
    float lsm = gr[0] + gr[1] + gr[2] + gr[3];                                       \
    float lsq = gr[0]*gr[0] + gr[1]*gr[1] + gr[2]*gr[2] + gr[3]*gr[3];               \
    lsm += __shfl_xor(lsm, 4);  lsq += __shfl_xor(lsq, 4);                           \
    lsm += __shfl_xor(lsm, 8);  lsq += __shfl_xor(lsq, 8);                           \
    lsm += __shfl_xor(lsm, 16); lsq += __shfl_xor(lsq, 16);                          \
    lsm += __shfl_xor(lsm, 32); lsq += __shfl_xor(lsq, 32);                          \
    if (ss == 0 && lhi == 0) {                                                       \
      part_lds[NXT][bb][wave][0] = lsm;                                              \
      part_lds[NXT][bb][wave][1] = lsq;                                              \
    }                                                                                \
    asm volatile("s_waitcnt lgkmcnt(0)" ::: "memory");                               \
    __builtin_amdgcn_s_barrier();                                                    \
    __builtin_amdgcn_sched_barrier(0);                                               \
  }

  for (int t = 0; t < SEQ; t += 4) {
    SCAN_STEP(t,     0, 1, ps1, ps0)
    SCAN_STEP(t + 1, 1, 0, ps2, ps1)
    SCAN_STEP(t + 2, 0, 1, ps3, ps2)
    SCAN_STEP(t + 3, 1, 0, ps0, ps3)
  }
#undef SCAN_STEP
}

// ---------------------------------------------------------------- causal flash attention, D=32, MFMA
// No online max (|scores| << 80), deferred denominator reduce.
__global__ __launch_bounds__(256) void attn_k(const ushort* __restrict__ Q,
                                              const ushort* __restrict__ K,
                                              const ushort* __restrict__ VT,
                                              ushort* __restrict__ O) {
  __shared__ __attribute__((aligned(16))) ushort Plds[4 * 16 * 32];  // per-wave 16x32 P tile
  const int tid = threadIdx.x, lane = tid & 63, wave = tid >> 6;
  const int bh = blockIdx.y;
  const int qtile = blockIdx.x * 4 + wave;
  const int q0 = qtile * 16;
  const int l15 = lane & 15, lhi = lane >> 4;
  const float scale = 0.17677669529663689f;   // 1/sqrt(32)

  bf16x8 qa = __builtin_bit_cast(bf16x8,
      *(const uint4*)(Q + ((size_t)bh * SEQ + q0 + l15) * HDIM + lhi * 8));
  const ushort* Kb = K + (size_t)bh * SEQ * HDIM;
  const ushort* Vb = VT + (size_t)bh * HDIM * SEQ;
  ushort* Pw = &Plds[wave * 512];

  f32x4 o0 = {}, o1 = {};
  float lacc[4] = {};

  for (int kt = 0; kt <= qtile; kt += 2) {
    const bool t2 = (kt + 1 <= qtile);
    f32x4 z = {};
    bf16x8 kf0 = __builtin_bit_cast(bf16x8, *(const uint4*)(Kb + (size_t)(kt * 16 + l15) * HDIM + lhi * 8));
    f32x4 s0 = mfma16(qa, kf0, z);
    f32x4 s1 = {};
    if (t2) {
      bf16x8 kf1 = __builtin_bit_cast(bf16x8, *(const uint4*)(Kb + (size_t)((kt + 1) * 16 + l15) * HDIM + lhi * 8));
      s1 = mfma16(qa, kf1, z);
    }
    float p0[4], p1[4];
#pragma unroll
    for (int r = 0; r < 4; ++r) {
      int qr = q0 + lhi * 4 + r;
      int kc0 = kt * 16 + l15;
      p0[r] = (kc0 <= qr) ? __expf(s0[r] * scale) : 0.f;
      p1[r] = (t2 && kc0 + 16 <= qr) ? __expf(s1[r] * scale) : 0.f;
      lacc[r] += p0[r] + p1[r];
    }
#pragma unroll
    for (int r = 0; r < 4; ++r) {
      Pw[(lhi * 4 + r) * 32 + l15]      = f2bf(p0[r]);
      Pw[(lhi * 4 + r) * 32 + 16 + l15] = f2bf(p1[r]);
    }
    bf16x8 pa  = __builtin_bit_cast(bf16x8, *(const uint4*)(&Pw[l15 * 32 + lhi * 8]));
    bf16x8 v0f = __builtin_bit_cast(bf16x8, *(const uint4*)(Vb + (size_t)l15 * SEQ + kt * 16 + lhi * 8));
    bf16x8 v1f = __builtin_bit_cast(bf16x8, *(const uint4*)(Vb + (size_t)(16 + l15) * SEQ + kt * 16 + lhi * 8));
    o0 = mfma16(pa, v0f, o0);
    o1 = mfma16(pa, v1f, o1);
  }
#pragma unroll
  for (int msk = 1; msk <= 8; msk <<= 1)
#pragma unroll
    for (int r = 0; r < 4; ++r) lacc[r] += __shfl_xor(lacc[r], msk);

  const int b = bh >> 3, h = bh & 7;
#pragma unroll
  for (int r = 0; r < 4; ++r) {
    float inv = 1.f / lacc[r];
    int qr = q0 + lhi * 4 + r;
    size_t base = ((size_t)(b * SEQ + qr)) * CDIM + h * HDIM;
    O[base + l15]      = f2bf(o0[r] * inv);
    O[base + 16 + l15] = f2bf(o1[r] * inv);
  }
}

// ---------------------------------------------------------------- launcher
static size_t ws_take(size_t& o, size_t bytes) {
  size_t r = o;
  o += (bytes + 255) & ~(size_t)255;
  return r;
}

extern "C" void kernel_launch(void* const* d_in, const int* in_sizes, int n_in,
                              void* d_out, int out_size, void* d_ws, size_t ws_size,
                              hipStream_t stream) {
  (void)in_sizes; (void)n_in; (void)out_size; (void)ws_size;
  const int*   input_ids = (const int*)  d_in[0];
  const float* prev_ctx  = (const float*)d_in[1];
  const float* embed_w   = (const float*)d_in[2];
  const float* en_w      = (const float*)d_in[3];
  const float* en_b      = (const float*)d_in[4];
  const float* ctx_w     = (const float*)d_in[5];
  const float* ctx_b     = (const float*)d_in[6];
  const float* cn_w      = (const float*)d_in[7];
  const float* cn_b      = (const float*)d_in[8];
  const float* ln1_w     = (const float*)d_in[9];
  const float* ln1_b     = (const float*)d_in[10];
  const float* ln2_w     = (const float*)d_in[11];
  const float* ln2_b     = (const float*)d_in[12];
  const float* qkv_w     = (const float*)d_in[13];
  const float* qkv_b     = (const float*)d_in[14];
  const float* ao_w      = (const float*)d_in[15];
  const float* ao_b      = (const float*)d_in[16];
  const float* fc1_w     = (const float*)d_in[17];
  const float* fc1_b     = (const float*)d_in[18];
  const float* fc2_w     = (const float*)d_in[19];
  const float* fc2_b     = (const float*)d_in[20];
  const float* fln_w     = (const float*)d_in[21];
  const float* fln_b     = (const float*)d_in[22];
  const float* out_w     = (const float*)d_in[23];
  float* logits = (float*)d_out;

  char* ws = (char*)d_ws;
  size_t o = 0;
  ushort* WB_OUT = (ushort*)(ws + ws_take(o, (size_t)NVOC * CDIM * 2));
  ushort* TOK    = (ushort*)(ws + ws_take(o, (size_t)NROWS * EDIM * 2));
  float*  PBUF   = (float*) (ws + ws_take(o, (size_t)NROWS * CDIM * 4));
  float*  XBUF   = (float*) (ws + ws_take(o, (size_t)NROWS * CDIM * 4));
  ushort* AIN    = (ushort*)(ws + ws_take(o, (size_t)NROWS * CDIM * 2));
  ushort* MIN    = (ushort*)(ws + ws_take(o, (size_t)NROWS * CDIM * 2));
  ushort* QB     = (ushort*)(ws + ws_take(o, (size_t)NROWS * CDIM * 2));
  ushort* KB     = (ushort*)(ws + ws_take(o, (size_t)NROWS * CDIM * 2));
  ushort* VTB    = (ushort*)(ws + ws_take(o, (size_t)NROWS * CDIM * 2));
  ushort* OB     = (ushort*)(ws + ws_take(o, (size_t)NROWS * CDIM * 2));
  ushort* TBUF   = (ushort*)(ws + ws_take(o, (size_t)NROWS * IDIM * 2));
  ushort* XLN    = (ushort*)(ws + ws_take(o, (size_t)NROWS * CDIM * 2));

  cvt_k<<<dim3(2048), dim3(256), 0, stream>>>(out_w, WB_OUT, NVOC * CDIM / 4);
  embed_ln_k<<<dim3(NROWS), dim3(64), 0, stream>>>(input_ids, embed_w, en_w, en_b, TOK);
  gemm64_k<GF_BIAS | GF_WF32><<<dim3(64, 4), dim3(256), 0, stream>>>(
      TOK, EDIM, (const void*)(ctx_w + 256), 768, ctx_b, (void*)PBUF, CDIM, EDIM);
  scan_k<<<dim3(1), dim3(256), 0, stream>>>(ctx_w, prev_ctx, PBUF, cn_w, cn_b, XBUF);

  for (int l = 0; l < NLAY; ++l) {
    ln_k<true><<<dim3(NROWS / 4), dim3(256), 0, stream>>>(
        XBUF, ln1_w + l * CDIM, ln1_b + l * CDIM, ln2_w + l * CDIM, ln2_b + l * CDIM, AIN, MIN);
    qkvrope_k<<<dim3(64, 12), dim3(256), 0, stream>>>(
        AIN, qkv_w + (size_t)l * 768 * CDIM, qkv_b + l * 768, QB, KB, VTB);
    attn_k<<<dim3(16, 32), dim3(256), 0, stream>>>(QB, KB, VTB, OB);
    gemm64_k<GF_BIAS | GF_GELU | GF_BF16O | GF_WF32><<<dim3(64, 16), dim3(256), 0, stream>>>(
        MIN, CDIM, (const void*)(fc1_w + (size_t)l * IDIM * CDIM), CDIM,
        fc1_b + l * IDIM, (void*)TBUF, IDIM, CDIM);
    gemm64_dual_k<<<dim3(64, 4), dim3(256), 0, stream>>>(
        OB, CDIM, ao_w + (size_t)l * CDIM * CDIM, CDIM, CDIM,
        TBUF, IDIM, fc2_w + (size_t)l * CDIM * IDIM, IDIM, IDIM,
        ao_b + l * CDIM, fc2_b + l * CDIM, XBUF, CDIM);
  }

  ln_k<false><<<dim3(NROWS / 4), dim3(256), 0, stream>>>(
      XBUF, fln_w, fln_b, nullptr, nullptr, XLN, nullptr);
  gemm_k<0><<<dim3(32, 393), dim3(256), 0, stream>>>(
      XLN, CDIM, (const void*)WB_OUT, CDIM, nullptr, (void*)logits, NVOC, CDIM);
}